// Round 1
// baseline (1641.723 us; speedup 1.0000x reference)
//
#include <hip/hip_runtime.h>
#include <math.h>

#define D_MODEL 1024
#define D_STATE 16
#define D_CONVK 4
#define D_INNER 2048
#define DT_RANK 64
#define BB 2
#define LL 2048
#define NROWS (BB*LL)   // 4096

// ---------------- LayerNorm: one block per row of 1024 ----------------
__global__ __launch_bounds__(256)
void ln_kernel(const float* __restrict__ x, const float* __restrict__ w,
               const float* __restrict__ b, float* __restrict__ xn) {
    int row = blockIdx.x;
    const float* xr = x + (size_t)row * D_MODEL;
    float4 v = ((const float4*)xr)[threadIdx.x];
    float s  = v.x + v.y + v.z + v.w;
    float ss = v.x*v.x + v.y*v.y + v.z*v.z + v.w*v.w;
    for (int off = 32; off > 0; off >>= 1) {
        s  += __shfl_down(s, off);
        ss += __shfl_down(ss, off);
    }
    __shared__ float red[8];
    int lane = threadIdx.x & 63, wv = threadIdx.x >> 6;
    if (lane == 0) { red[wv] = s; red[wv + 4] = ss; }
    __syncthreads();
    if (threadIdx.x == 0) {
        float ts  = red[0] + red[1] + red[2] + red[3];
        float tss = red[4] + red[5] + red[6] + red[7];
        float mu  = ts / D_MODEL;
        float var = tss / D_MODEL - mu * mu;
        red[0] = mu; red[1] = rsqrtf(var + 1e-5f);
    }
    __syncthreads();
    float mu = red[0], rs = red[1];
    float4 w4 = ((const float4*)w)[threadIdx.x];
    float4 b4 = ((const float4*)b)[threadIdx.x];
    float4 o;
    o.x = (v.x - mu) * rs * w4.x + b4.x;
    o.y = (v.y - mu) * rs * w4.y + b4.y;
    o.z = (v.z - mu) * rs * w4.z + b4.z;
    o.w = (v.w - mu) * rs * w4.w + b4.w;
    ((float4*)(xn + (size_t)row * D_MODEL))[threadIdx.x] = o;
}

// ---------------- Generic fp32 tiled GEMM: C[M,N] = A[M,K] @ W[K,N] -------
// mode 0: plain   mode 1: softplus(acc + bias[c])   mode 2: scale*acc + resid
#define BM 64
#define BN 64
#define BK 16
__global__ __launch_bounds__(256)
void gemm_kernel(const float* __restrict__ A, int lda,
                 const float* __restrict__ W, int ldw,
                 float* __restrict__ C, int ldc,
                 int M, int N, int K,
                 int mode, const float* __restrict__ bias,
                 const float* __restrict__ resid,
                 const float* __restrict__ scale_ptr) {
    __shared__ float As[BK][BM];
    __shared__ float Ws[BK][BN];
    int tid = threadIdx.x;
    int row0 = blockIdx.y * BM, col0 = blockIdx.x * BN;
    int tx = tid & 15, ty = tid >> 4;
    int ar = tid >> 2;          // 0..63 (A row within tile)
    int ac = (tid & 3) * 4;     // 0,4,8,12
    int wr = tid >> 4;          // 0..15 (W row within k-tile)
    int wc = (tid & 15) * 4;    // 0..60
    float acc[4][4] = {{0,0,0,0},{0,0,0,0},{0,0,0,0},{0,0,0,0}};
    for (int k0 = 0; k0 < K; k0 += BK) {
        float4 av = *(const float4*)(A + (size_t)(row0 + ar) * lda + k0 + ac);
        float4 wv;
        if (col0 + wc < N)
            wv = *(const float4*)(W + (size_t)(k0 + wr) * ldw + col0 + wc);
        else
            wv = make_float4(0.f, 0.f, 0.f, 0.f);
        __syncthreads();
        As[ac + 0][ar] = av.x; As[ac + 1][ar] = av.y;
        As[ac + 2][ar] = av.z; As[ac + 3][ar] = av.w;
        *(float4*)&Ws[wr][wc] = wv;
        __syncthreads();
#pragma unroll
        for (int kk = 0; kk < BK; ++kk) {
            float4 a4 = *(const float4*)&As[kk][ty * 4];
            float4 w4 = *(const float4*)&Ws[kk][tx * 4];
            acc[0][0] = fmaf(a4.x, w4.x, acc[0][0]);
            acc[0][1] = fmaf(a4.x, w4.y, acc[0][1]);
            acc[0][2] = fmaf(a4.x, w4.z, acc[0][2]);
            acc[0][3] = fmaf(a4.x, w4.w, acc[0][3]);
            acc[1][0] = fmaf(a4.y, w4.x, acc[1][0]);
            acc[1][1] = fmaf(a4.y, w4.y, acc[1][1]);
            acc[1][2] = fmaf(a4.y, w4.z, acc[1][2]);
            acc[1][3] = fmaf(a4.y, w4.w, acc[1][3]);
            acc[2][0] = fmaf(a4.z, w4.x, acc[2][0]);
            acc[2][1] = fmaf(a4.z, w4.y, acc[2][1]);
            acc[2][2] = fmaf(a4.z, w4.z, acc[2][2]);
            acc[2][3] = fmaf(a4.z, w4.w, acc[2][3]);
            acc[3][0] = fmaf(a4.w, w4.x, acc[3][0]);
            acc[3][1] = fmaf(a4.w, w4.y, acc[3][1]);
            acc[3][2] = fmaf(a4.w, w4.z, acc[3][2]);
            acc[3][3] = fmaf(a4.w, w4.w, acc[3][3]);
        }
    }
    float scale = scale_ptr ? scale_ptr[0] : 1.0f;
#pragma unroll
    for (int i = 0; i < 4; ++i) {
        int r = row0 + ty * 4 + i;
#pragma unroll
        for (int j = 0; j < 4; ++j) {
            int c = col0 + tx * 4 + j;
            if (c >= N) continue;
            float v = acc[i][j];
            if (mode == 1) {
                v += bias[c];
                v = (v > 20.0f) ? v : log1pf(expf(v));   // softplus
            } else if (mode == 2) {
                v = scale * v + resid[(size_t)r * ldc + c];
            }
            C[(size_t)r * ldc + c] = v;
        }
    }
}

// ---------------- Causal depthwise conv (K=4) + bias + silu ----------------
// Also emits new_conv_state = pre-conv x_main at l in {L-3..L-1}, [B,Di,3]
__global__ __launch_bounds__(256)
void conv_kernel(const float* __restrict__ xm, const float* __restrict__ cw,
                 const float* __restrict__ cb, float* __restrict__ xs,
                 float* __restrict__ conv_state_out) {
    int idx = blockIdx.x * 256 + threadIdx.x;
    int d = idx & (D_INNER - 1);
    int l = (idx / D_INNER) & (LL - 1);
    int b = idx / (D_INNER * LL);
    const float* base = xm + (size_t)b * LL * D_INNER + d;
    float acc = cb[d];
#pragma unroll
    for (int k = 0; k < D_CONVK; ++k) {
        int li = l - (D_CONVK - 1) + k;
        if (li >= 0) acc += base[(size_t)li * D_INNER] * cw[d * D_CONVK + k];
    }
    xs[idx] = acc / (1.0f + expf(-acc));   // silu
    if (l >= LL - (D_CONVK - 1)) {
        float xv = base[(size_t)l * D_INNER];
        conv_state_out[((size_t)b * D_INNER + d) * (D_CONVK - 1) + (l - (LL - (D_CONVK - 1)))] = xv;
    }
}

// ---------------- Selective scan ----------------
// block = 256 threads = 16 d-channels x 16 states; grid = (Di/16, B)
#define LCH 32
__global__ __launch_bounds__(256)
void scan_kernel(const float* __restrict__ dt, const float* __restrict__ xdbl,
                 const float* __restrict__ xs, const float* __restrict__ z,
                 const float* __restrict__ A_log, const float* __restrict__ Dp,
                 float* __restrict__ y, float* __restrict__ ssm_out) {
    __shared__ float dt_t[LCH][16], x_t[LCH][16], z_t[LCH][16];
    __shared__ float Bt[LCH][16], Ct[LCH][16], y_t[LCH][16];
    int b = blockIdx.y;
    int d0 = blockIdx.x * 16;
    int tid = threadIdx.x;
    int n = tid & 15, dg = tid >> 4;        // state idx, channel-in-block idx
    int d = d0 + dg;
    float a = -expf(A_log[d * D_STATE + n]);
    float al2 = a * 1.44269504088896340736f;   // for exp2
    float Dv = Dp[d];
    float h = 0.0f;
    size_t rowbase = (size_t)b * LL;
    for (int l0 = 0; l0 < LL; l0 += LCH) {
        for (int e = tid; e < LCH * 16; e += 256) {
            int i = e >> 4, j = e & 15;
            size_t r = rowbase + l0 + i;
            dt_t[i][j] = dt[r * D_INNER + d0 + j];
            x_t[i][j]  = xs[r * D_INNER + d0 + j];
            z_t[i][j]  = z [r * D_INNER + d0 + j];
            Bt[i][j]   = xdbl[r * 96 + DT_RANK + j];
            Ct[i][j]   = xdbl[r * 96 + DT_RANK + D_STATE + j];
        }
        __syncthreads();
#pragma unroll 4
        for (int i = 0; i < LCH; ++i) {
            float dtv = dt_t[i][dg];
            float xv  = x_t[i][dg];
            float e = exp2f(al2 * dtv);
            h = fmaf(e, h, dtv * Bt[i][n] * xv);
            float p = h * Ct[i][n];
            p += __shfl_xor(p, 1);
            p += __shfl_xor(p, 2);
            p += __shfl_xor(p, 4);
            p += __shfl_xor(p, 8);
            if (n == 0) {
                float zv = z_t[i][dg];
                y_t[i][dg] = (p + xv * Dv) * (zv / (1.0f + expf(-zv)));
            }
        }
        __syncthreads();
        for (int e = tid; e < LCH * 16; e += 256) {
            int i = e >> 4, j = e & 15;
            y[(rowbase + l0 + i) * D_INNER + d0 + j] = y_t[i][j];
        }
    }
    ssm_out[((size_t)b * D_INNER + d) * D_STATE + n] = h;
}

// ---------------- launch ----------------
extern "C" void kernel_launch(void* const* d_in, const int* in_sizes, int n_in,
                              void* d_out, int out_size, void* d_ws, size_t ws_size,
                              hipStream_t stream) {
    (void)in_sizes; (void)n_in; (void)out_size; (void)ws_size;
    const float* x      = (const float*)d_in[0];
    const float* ln_w   = (const float*)d_in[1];
    const float* ln_b   = (const float*)d_in[2];
    const float* Win    = (const float*)d_in[3];   // [1024, 4096]
    const float* convw  = (const float*)d_in[4];   // [2048, 4]
    const float* convb  = (const float*)d_in[5];
    const float* Wx     = (const float*)d_in[6];   // [2048, 96]
    const float* Wdt    = (const float*)d_in[7];   // [64, 2048]
    const float* bdt    = (const float*)d_in[8];
    const float* A_log  = (const float*)d_in[9];   // [2048, 16]
    const float* Dp     = (const float*)d_in[10];
    const float* Wout   = (const float*)d_in[11];  // [2048, 1024]
    const float* rscale = (const float*)d_in[12];  // [1]

    float* out      = (float*)d_out;                          // [4096,1024]
    float* ssm_out  = out + (size_t)NROWS * D_MODEL;          // [2,2048,16]
    float* conv_out = ssm_out + (size_t)BB * D_INNER * D_STATE; // [2,2048,3]

    float* ws    = (float*)d_ws;
    float* xn    = ws;                                   // 4096*1024
    float* xmain = xn + (size_t)NROWS * D_MODEL;         // 4096*2048
    float* zbuf  = xmain + (size_t)NROWS * D_INNER;      // 4096*2048
    float* xsb   = zbuf + (size_t)NROWS * D_INNER;       // 4096*2048
    float* xdbl  = xsb + (size_t)NROWS * D_INNER;        // 4096*96
    float* dtb   = xdbl + (size_t)NROWS * 96;            // 4096*2048
    float* ybuf  = xmain;  // x_main dead after conv; reuse for y

    ln_kernel<<<NROWS, 256, 0, stream>>>(x, ln_w, ln_b, xn);

    // in_proj split into x_main and z halves
    gemm_kernel<<<dim3(D_INNER / BN, NROWS / BM), 256, 0, stream>>>(
        xn, D_MODEL, Win, 2 * D_INNER, xmain, D_INNER,
        NROWS, D_INNER, D_MODEL, 0, nullptr, nullptr, nullptr);
    gemm_kernel<<<dim3(D_INNER / BN, NROWS / BM), 256, 0, stream>>>(
        xn, D_MODEL, Win + D_INNER, 2 * D_INNER, zbuf, D_INNER,
        NROWS, D_INNER, D_MODEL, 0, nullptr, nullptr, nullptr);

    conv_kernel<<<(NROWS * D_INNER) / 256, 256, 0, stream>>>(
        xmain, convw, convb, xsb, conv_out);

    // x_dbl = x_s @ x_proj_w   [4096 x 96]
    gemm_kernel<<<dim3((96 + BN - 1) / BN, NROWS / BM), 256, 0, stream>>>(
        xsb, D_INNER, Wx, 96, xdbl, 96,
        NROWS, 96, D_INNER, 0, nullptr, nullptr, nullptr);

    // dt = softplus(x_dbl[:, :64] @ dt_proj_w + b)   [4096 x 2048]
    gemm_kernel<<<dim3(D_INNER / BN, NROWS / BM), 256, 0, stream>>>(
        xdbl, 96, Wdt, D_INNER, dtb, D_INNER,
        NROWS, D_INNER, DT_RANK, 1, bdt, nullptr, nullptr);

    scan_kernel<<<dim3(D_INNER / 16, BB), 256, 0, stream>>>(
        dtb, xdbl, xsb, zbuf, A_log, Dp, ybuf, ssm_out);

    // out = res_scale * (y @ out_proj_w) + residual
    gemm_kernel<<<dim3(D_MODEL / BN, NROWS / BM), 256, 0, stream>>>(
        ybuf, D_INNER, Wout, D_MODEL, out, D_MODEL,
        NROWS, D_MODEL, D_INNER, 2, nullptr, x, rscale);
}

// Round 2
// 1218.211 us; speedup vs baseline: 1.3477x; 1.3477x over previous
//
#include <hip/hip_runtime.h>
#include <math.h>

#define D_MODEL 1024
#define D_STATE 16
#define D_CONVK 4
#define D_INNER 2048
#define DT_RANK 64
#define BB 2
#define LL 2048
#define NROWS (BB*LL)   // 4096
#define NC 16           // scan chunks
#define CH (LL/NC)      // 128 steps per chunk
#define SC 32           // staging sub-chunk

// ---------------- LayerNorm: one block per row of 1024 ----------------
__global__ __launch_bounds__(256)
void ln_kernel(const float* __restrict__ x, const float* __restrict__ w,
               const float* __restrict__ b, float* __restrict__ xn) {
    int row = blockIdx.x;
    const float* xr = x + (size_t)row * D_MODEL;
    float4 v = ((const float4*)xr)[threadIdx.x];
    float s  = v.x + v.y + v.z + v.w;
    float ss = v.x*v.x + v.y*v.y + v.z*v.z + v.w*v.w;
    for (int off = 32; off > 0; off >>= 1) {
        s  += __shfl_down(s, off);
        ss += __shfl_down(ss, off);
    }
    __shared__ float red[8];
    int lane = threadIdx.x & 63, wv = threadIdx.x >> 6;
    if (lane == 0) { red[wv] = s; red[wv + 4] = ss; }
    __syncthreads();
    if (threadIdx.x == 0) {
        float ts  = red[0] + red[1] + red[2] + red[3];
        float tss = red[4] + red[5] + red[6] + red[7];
        float mu  = ts / D_MODEL;
        float var = tss / D_MODEL - mu * mu;
        red[0] = mu; red[1] = rsqrtf(var + 1e-5f);
    }
    __syncthreads();
    float mu = red[0], rs = red[1];
    float4 w4 = ((const float4*)w)[threadIdx.x];
    float4 b4 = ((const float4*)b)[threadIdx.x];
    float4 o;
    o.x = (v.x - mu) * rs * w4.x + b4.x;
    o.y = (v.y - mu) * rs * w4.y + b4.y;
    o.z = (v.z - mu) * rs * w4.z + b4.z;
    o.w = (v.w - mu) * rs * w4.w + b4.w;
    ((float4*)(xn + (size_t)row * D_MODEL))[threadIdx.x] = o;
}

// ---------------- Generic fp32 tiled GEMM: C[M,N] = A[M,K] @ W[K,N] -------
// mode 0: plain   mode 1: softplus(acc + bias[c])   mode 2: scale*acc + resid
#define BM 64
#define BN 64
#define BK 16
__global__ __launch_bounds__(256)
void gemm_kernel(const float* __restrict__ A, int lda,
                 const float* __restrict__ W, int ldw,
                 float* __restrict__ C, int ldc,
                 int M, int N, int K,
                 int mode, const float* __restrict__ bias,
                 const float* __restrict__ resid,
                 const float* __restrict__ scale_ptr) {
    __shared__ float As[BK][BM];
    __shared__ float Ws[BK][BN];
    int tid = threadIdx.x;
    int row0 = blockIdx.y * BM, col0 = blockIdx.x * BN;
    int tx = tid & 15, ty = tid >> 4;
    int ar = tid >> 2;          // 0..63 (A row within tile)
    int ac = (tid & 3) * 4;     // 0,4,8,12
    int wr = tid >> 4;          // 0..15 (W row within k-tile)
    int wc = (tid & 15) * 4;    // 0..60
    float acc[4][4] = {{0,0,0,0},{0,0,0,0},{0,0,0,0},{0,0,0,0}};
    for (int k0 = 0; k0 < K; k0 += BK) {
        float4 av = *(const float4*)(A + (size_t)(row0 + ar) * lda + k0 + ac);
        float4 wv;
        if (col0 + wc < N)
            wv = *(const float4*)(W + (size_t)(k0 + wr) * ldw + col0 + wc);
        else
            wv = make_float4(0.f, 0.f, 0.f, 0.f);
        __syncthreads();
        As[ac + 0][ar] = av.x; As[ac + 1][ar] = av.y;
        As[ac + 2][ar] = av.z; As[ac + 3][ar] = av.w;
        *(float4*)&Ws[wr][wc] = wv;
        __syncthreads();
#pragma unroll
        for (int kk = 0; kk < BK; ++kk) {
            float4 a4 = *(const float4*)&As[kk][ty * 4];
            float4 w4 = *(const float4*)&Ws[kk][tx * 4];
            acc[0][0] = fmaf(a4.x, w4.x, acc[0][0]);
            acc[0][1] = fmaf(a4.x, w4.y, acc[0][1]);
            acc[0][2] = fmaf(a4.x, w4.z, acc[0][2]);
            acc[0][3] = fmaf(a4.x, w4.w, acc[0][3]);
            acc[1][0] = fmaf(a4.y, w4.x, acc[1][0]);
            acc[1][1] = fmaf(a4.y, w4.y, acc[1][1]);
            acc[1][2] = fmaf(a4.y, w4.z, acc[1][2]);
            acc[1][3] = fmaf(a4.y, w4.w, acc[1][3]);
            acc[2][0] = fmaf(a4.z, w4.x, acc[2][0]);
            acc[2][1] = fmaf(a4.z, w4.y, acc[2][1]);
            acc[2][2] = fmaf(a4.z, w4.z, acc[2][2]);
            acc[2][3] = fmaf(a4.z, w4.w, acc[2][3]);
            acc[3][0] = fmaf(a4.w, w4.x, acc[3][0]);
            acc[3][1] = fmaf(a4.w, w4.y, acc[3][1]);
            acc[3][2] = fmaf(a4.w, w4.z, acc[3][2]);
            acc[3][3] = fmaf(a4.w, w4.w, acc[3][3]);
        }
    }
    float scale = scale_ptr ? scale_ptr[0] : 1.0f;
#pragma unroll
    for (int i = 0; i < 4; ++i) {
        int r = row0 + ty * 4 + i;
#pragma unroll
        for (int j = 0; j < 4; ++j) {
            int c = col0 + tx * 4 + j;
            if (c >= N) continue;
            float v = acc[i][j];
            if (mode == 1) {
                v += bias[c];
                v = (v > 20.0f) ? v : log1pf(expf(v));   // softplus
            } else if (mode == 2) {
                v = scale * v + resid[(size_t)r * ldc + c];
            }
            C[(size_t)r * ldc + c] = v;
        }
    }
}

// ---------------- Causal depthwise conv (K=4) + bias + silu ----------------
__global__ __launch_bounds__(256)
void conv_kernel(const float* __restrict__ xm, const float* __restrict__ cw,
                 const float* __restrict__ cb, float* __restrict__ xs,
                 float* __restrict__ conv_state_out) {
    int idx = blockIdx.x * 256 + threadIdx.x;
    int d = idx & (D_INNER - 1);
    int l = (idx / D_INNER) & (LL - 1);
    int b = idx / (D_INNER * LL);
    const float* base = xm + (size_t)b * LL * D_INNER + d;
    float acc = cb[d];
#pragma unroll
    for (int k = 0; k < D_CONVK; ++k) {
        int li = l - (D_CONVK - 1) + k;
        if (li >= 0) acc += base[(size_t)li * D_INNER] * cw[d * D_CONVK + k];
    }
    xs[idx] = acc / (1.0f + expf(-acc));   // silu
    if (l >= LL - (D_CONVK - 1)) {
        float xv = base[(size_t)l * D_INNER];
        conv_state_out[((size_t)b * D_INNER + d) * (D_CONVK - 1) + (l - (LL - (D_CONVK - 1)))] = xv;
    }
}

// ---------------- Selective scan, chunked ----------------
// Pass 1: per (b, chunk, d, n) compute E = prod(e_t), S = chunk-local h (h_in=0)
// grid (Di/16, NC, B), block 256 = 16d x 16n
__global__ __launch_bounds__(256)
void scan_part1(const float* __restrict__ dt, const float* __restrict__ xdbl,
                const float* __restrict__ xs, const float* __restrict__ A_log,
                float* __restrict__ Ebuf, float* __restrict__ Sbuf) {
    __shared__ float dt_t[SC][16], x_t[SC][16], Bt[SC][16];
    int d0 = blockIdx.x * 16;
    int c  = blockIdx.y;
    int b  = blockIdx.z;
    int tid = threadIdx.x;
    int n = tid & 15, dg = tid >> 4;
    int d = d0 + dg;
    float al2 = -expf(A_log[d * D_STATE + n]) * 1.44269504088896340736f;
    float E = 1.0f, S = 0.0f;
    size_t rowbase = (size_t)b * LL + (size_t)c * CH;
    for (int l0 = 0; l0 < CH; l0 += SC) {
        for (int e_i = tid; e_i < SC * 16; e_i += 256) {
            int i = e_i >> 4, j = e_i & 15;
            size_t r = rowbase + l0 + i;
            dt_t[i][j] = dt[r * D_INNER + d0 + j];
            x_t[i][j]  = xs[r * D_INNER + d0 + j];
            Bt[i][j]   = xdbl[r * 96 + DT_RANK + j];
        }
        __syncthreads();
#pragma unroll 8
        for (int i = 0; i < SC; ++i) {
            float dtv = dt_t[i][dg];
            float e = exp2f(al2 * dtv);
            S = fmaf(e, S, dtv * Bt[i][n] * x_t[i][dg]);
            E *= e;
        }
        __syncthreads();
    }
    size_t idx = (((size_t)b * NC + c) * D_INNER + d) * D_STATE + n;
    Ebuf[idx] = E;
    Sbuf[idx] = S;
}

// Pass 2(fused)+3: reconstruct h_in by folding earlier chunks' (E,S), then
// run the chunk producing y (with D-skip and z-gate). Last chunk emits ssm h.
__global__ __launch_bounds__(256)
void scan_part3(const float* __restrict__ dt, const float* __restrict__ xdbl,
                const float* __restrict__ xs, const float* __restrict__ z,
                const float* __restrict__ A_log, const float* __restrict__ Dp,
                const float* __restrict__ Ebuf, const float* __restrict__ Sbuf,
                float* __restrict__ y, float* __restrict__ ssm_out) {
    __shared__ float dt_t[SC][16], x_t[SC][16], z_t[SC][16];
    __shared__ float Bt[SC][16], Ct[SC][16], y_t[SC][16];
    int d0 = blockIdx.x * 16;
    int c  = blockIdx.y;
    int b  = blockIdx.z;
    int tid = threadIdx.x;
    int n = tid & 15, dg = tid >> 4;
    int d = d0 + dg;
    float al2 = -expf(A_log[d * D_STATE + n]) * 1.44269504088896340736f;
    float Dv = Dp[d];
    // prefix: h_in = fold over chunks < c
    float h = 0.0f;
    size_t pidx = (((size_t)b * NC) * D_INNER + d) * D_STATE + n;
    for (int k = 0; k < c; ++k) {
        size_t q = pidx + (size_t)k * D_INNER * D_STATE;
        h = fmaf(Ebuf[q], h, Sbuf[q]);
    }
    size_t rowbase = (size_t)b * LL + (size_t)c * CH;
    for (int l0 = 0; l0 < CH; l0 += SC) {
        for (int e_i = tid; e_i < SC * 16; e_i += 256) {
            int i = e_i >> 4, j = e_i & 15;
            size_t r = rowbase + l0 + i;
            dt_t[i][j] = dt[r * D_INNER + d0 + j];
            x_t[i][j]  = xs[r * D_INNER + d0 + j];
            z_t[i][j]  = z [r * D_INNER + d0 + j];
            Bt[i][j]   = xdbl[r * 96 + DT_RANK + j];
            Ct[i][j]   = xdbl[r * 96 + DT_RANK + D_STATE + j];
        }
        __syncthreads();
#pragma unroll 4
        for (int i = 0; i < SC; ++i) {
            float dtv = dt_t[i][dg];
            float xv  = x_t[i][dg];
            float e = exp2f(al2 * dtv);
            h = fmaf(e, h, dtv * Bt[i][n] * xv);
            float p = h * Ct[i][n];
            p += __shfl_xor(p, 1);
            p += __shfl_xor(p, 2);
            p += __shfl_xor(p, 4);
            p += __shfl_xor(p, 8);
            if (n == 0) {
                float zv = z_t[i][dg];
                y_t[i][dg] = (p + xv * Dv) * (zv / (1.0f + expf(-zv)));
            }
        }
        __syncthreads();
        for (int e_i = tid; e_i < SC * 16; e_i += 256) {
            int i = e_i >> 4, j = e_i & 15;
            y[(rowbase + l0 + i) * D_INNER + d0 + j] = y_t[i][j];
        }
        __syncthreads();
    }
    if (c == NC - 1)
        ssm_out[((size_t)b * D_INNER + d) * D_STATE + n] = h;
}

// ---------------- launch ----------------
extern "C" void kernel_launch(void* const* d_in, const int* in_sizes, int n_in,
                              void* d_out, int out_size, void* d_ws, size_t ws_size,
                              hipStream_t stream) {
    (void)in_sizes; (void)n_in; (void)out_size; (void)ws_size;
    const float* x      = (const float*)d_in[0];
    const float* ln_w   = (const float*)d_in[1];
    const float* ln_b   = (const float*)d_in[2];
    const float* Win    = (const float*)d_in[3];   // [1024, 4096]
    const float* convw  = (const float*)d_in[4];   // [2048, 4]
    const float* convb  = (const float*)d_in[5];
    const float* Wx     = (const float*)d_in[6];   // [2048, 96]
    const float* Wdt    = (const float*)d_in[7];   // [64, 2048]
    const float* bdt    = (const float*)d_in[8];
    const float* A_log  = (const float*)d_in[9];   // [2048, 16]
    const float* Dp     = (const float*)d_in[10];
    const float* Wout   = (const float*)d_in[11];  // [2048, 1024]
    const float* rscale = (const float*)d_in[12];  // [1]

    float* out      = (float*)d_out;                          // [4096,1024]
    float* ssm_out  = out + (size_t)NROWS * D_MODEL;          // [2,2048,16]
    float* conv_out = ssm_out + (size_t)BB * D_INNER * D_STATE; // [2,2048,3]

    float* ws    = (float*)d_ws;
    float* xn    = ws;                                   // 4096*1024
    float* xmain = xn + (size_t)NROWS * D_MODEL;         // 4096*2048
    float* zbuf  = xmain + (size_t)NROWS * D_INNER;      // 4096*2048
    float* xsb   = zbuf + (size_t)NROWS * D_INNER;       // 4096*2048
    float* xdbl  = xsb + (size_t)NROWS * D_INNER;        // 4096*96
    float* dtb   = xdbl + (size_t)NROWS * 96;            // 4096*2048
    float* ybuf  = xmain;          // x_main dead after conv; reuse for y
    float* Ebuf  = xn;             // xn dead after in_proj GEMMs; reuse
    float* Sbuf  = xn + (size_t)BB * NC * D_INNER * D_STATE;  // +1M floats

    ln_kernel<<<NROWS, 256, 0, stream>>>(x, ln_w, ln_b, xn);

    // in_proj split into x_main and z halves
    gemm_kernel<<<dim3(D_INNER / BN, NROWS / BM), 256, 0, stream>>>(
        xn, D_MODEL, Win, 2 * D_INNER, xmain, D_INNER,
        NROWS, D_INNER, D_MODEL, 0, nullptr, nullptr, nullptr);
    gemm_kernel<<<dim3(D_INNER / BN, NROWS / BM), 256, 0, stream>>>(
        xn, D_MODEL, Win + D_INNER, 2 * D_INNER, zbuf, D_INNER,
        NROWS, D_INNER, D_MODEL, 0, nullptr, nullptr, nullptr);

    conv_kernel<<<(NROWS * D_INNER) / 256, 256, 0, stream>>>(
        xmain, convw, convb, xsb, conv_out);

    // x_dbl = x_s @ x_proj_w   [4096 x 96]
    gemm_kernel<<<dim3((96 + BN - 1) / BN, NROWS / BM), 256, 0, stream>>>(
        xsb, D_INNER, Wx, 96, xdbl, 96,
        NROWS, 96, D_INNER, 0, nullptr, nullptr, nullptr);

    // dt = softplus(x_dbl[:, :64] @ dt_proj_w + b)   [4096 x 2048]
    gemm_kernel<<<dim3(D_INNER / BN, NROWS / BM), 256, 0, stream>>>(
        xdbl, 96, Wdt, D_INNER, dtb, D_INNER,
        NROWS, D_INNER, DT_RANK, 1, bdt, nullptr, nullptr);

    // chunked selective scan (after this point xn/Ebuf region is scratch)
    scan_part1<<<dim3(D_INNER / 16, NC, BB), 256, 0, stream>>>(
        dtb, xdbl, xsb, A_log, Ebuf, Sbuf);
    scan_part3<<<dim3(D_INNER / 16, NC, BB), 256, 0, stream>>>(
        dtb, xdbl, xsb, zbuf, A_log, Dp, Ebuf, Sbuf, ybuf, ssm_out);

    // out = res_scale * (y @ out_proj_w) + residual
    gemm_kernel<<<dim3(D_MODEL / BN, NROWS / BM), 256, 0, stream>>>(
        ybuf, D_INNER, Wout, D_MODEL, out, D_MODEL,
        NROWS, D_MODEL, D_INNER, 2, nullptr, x, rscale);
}

// Round 3
// 628.278 us; speedup vs baseline: 2.6131x; 1.9390x over previous
//
#include <hip/hip_runtime.h>
#include <math.h>

#define D_MODEL 1024
#define D_STATE 16
#define D_CONVK 4
#define D_INNER 2048
#define DT_RANK 64
#define BB 2
#define LL 2048
#define NROWS (BB*LL)   // 4096
#define NC 16           // scan chunks
#define CH (LL/NC)      // 128 steps per chunk
#define SC 32           // staging sub-chunk
#define XZLD 4096       // row stride of fused xz buffer

typedef __attribute__((ext_vector_type(8))) short bf16x8;
typedef __attribute__((ext_vector_type(4))) float f32x4;

typedef __attribute__((address_space(3))) unsigned char lds_ucp;
typedef const __attribute__((address_space(1))) unsigned char glb_ucp;
#define GLD16(gp, lp) __builtin_amdgcn_global_load_lds((glb_ucp*)(gp), (lds_ucp*)(lp), 16, 0, 0)

__device__ inline unsigned short f2bf(float f) {
    union { float f; unsigned u; } c; c.f = f;
    unsigned r = c.u + 0x7fff + ((c.u >> 16) & 1);   // round-to-nearest-even
    return (unsigned short)(r >> 16);
}

// ---------------- LayerNorm -> bf16: one block per row of 1024 ----------------
__global__ __launch_bounds__(256)
void ln_kernel(const float* __restrict__ x, const float* __restrict__ w,
               const float* __restrict__ b, unsigned short* __restrict__ xnb) {
    int row = blockIdx.x;
    const float* xr = x + (size_t)row * D_MODEL;
    float4 v = ((const float4*)xr)[threadIdx.x];
    float s  = v.x + v.y + v.z + v.w;
    float ss = v.x*v.x + v.y*v.y + v.z*v.z + v.w*v.w;
    for (int off = 32; off > 0; off >>= 1) {
        s  += __shfl_down(s, off);
        ss += __shfl_down(ss, off);
    }
    __shared__ float red[8];
    int lane = threadIdx.x & 63, wv = threadIdx.x >> 6;
    if (lane == 0) { red[wv] = s; red[wv + 4] = ss; }
    __syncthreads();
    if (threadIdx.x == 0) {
        float ts  = red[0] + red[1] + red[2] + red[3];
        float tss = red[4] + red[5] + red[6] + red[7];
        float mu  = ts / D_MODEL;
        float var = tss / D_MODEL - mu * mu;
        red[0] = mu; red[1] = rsqrtf(var + 1e-5f);
    }
    __syncthreads();
    float mu = red[0], rs = red[1];
    float4 w4 = ((const float4*)w)[threadIdx.x];
    float4 b4 = ((const float4*)b)[threadIdx.x];
    ushort4 o;
    o.x = f2bf((v.x - mu) * rs * w4.x + b4.x);
    o.y = f2bf((v.y - mu) * rs * w4.y + b4.y);
    o.z = f2bf((v.z - mu) * rs * w4.z + b4.z);
    o.w = f2bf((v.w - mu) * rs * w4.w + b4.w);
    ((ushort4*)(xnb + (size_t)row * D_MODEL))[threadIdx.x] = o;
}

// ------------- transpose + cast fp32 W[K][N] -> bf16 Wt[N][K] -------------
__global__ __launch_bounds__(256)
void transpose_cast(const float* __restrict__ W, unsigned short* __restrict__ Wt,
                    int K, int N) {
    __shared__ float t[32][33];
    int k0 = blockIdx.y * 32, n0 = blockIdx.x * 32;
    int tx = threadIdx.x & 31, ty = threadIdx.x >> 5;   // ty 0..7
#pragma unroll
    for (int i = 0; i < 32; i += 8)
        t[ty + i][tx] = W[(size_t)(k0 + ty + i) * N + n0 + tx];
    __syncthreads();
#pragma unroll
    for (int i = 0; i < 32; i += 8)
        Wt[(size_t)(n0 + ty + i) * K + k0 + tx] = f2bf(t[tx][ty + i]);
}

// ---------------- bf16 MFMA GEMM: C[M,N]fp32 = A[M,K] @ Wt[N,K]^T ----------
// 128x128 block tile, 4 waves, each wave 64x64 via 4x4 of 16x16x32 MFMA.
// mode 0: plain store.  mode 2: scale*acc + resid.
__global__ __launch_bounds__(256)
void mfma_gemm(const unsigned short* __restrict__ A,
               const unsigned short* __restrict__ Wt,
               float* __restrict__ C, int ldc, int K, int mode,
               const float* __restrict__ resid,
               const float* __restrict__ scale_ptr) {
    __shared__ short As[128 * 32];
    __shared__ short Bs[128 * 32];
    int tid = threadIdx.x;
    int lane = tid & 63, w = tid >> 6;
    int wm = w & 1, wn = w >> 1;
    int row0 = blockIdx.y * 128, col0 = blockIdx.x * 128;
    f32x4 acc[4][4] = {};
    const unsigned short* gA0 = A  + (size_t)row0 * K;
    const unsigned short* gB0 = Wt + (size_t)col0 * K;
    int r_in = lane >> 2;          // 0..15 row within 16-row issue group
    int e16  = (lane & 3) * 8;     // element offset (8 bf16 = 16B)
    int quad = lane >> 4, r16 = lane & 15;
    for (int k0 = 0; k0 < K; k0 += 32) {
        __syncthreads();
#pragma unroll
        for (int t = 0; t < 2; ++t) {
            int p = w * 2 + t;             // issue index 0..7
            int row = p * 16 + r_in;
            GLD16(gA0 + (size_t)row * K + k0 + e16, (char*)As + p * 1024);
            GLD16(gB0 + (size_t)row * K + k0 + e16, (char*)Bs + p * 1024);
        }
        __syncthreads();
        bf16x8 af[4], bfr[4];
#pragma unroll
        for (int i = 0; i < 4; ++i) {
            af[i]  = *(const bf16x8*)&As[(wm * 64 + i * 16 + r16) * 32 + quad * 8];
            bfr[i] = *(const bf16x8*)&Bs[(wn * 64 + i * 16 + r16) * 32 + quad * 8];
        }
#pragma unroll
        for (int mi = 0; mi < 4; ++mi)
#pragma unroll
            for (int ni = 0; ni < 4; ++ni)
                acc[mi][ni] = __builtin_amdgcn_mfma_f32_16x16x32_bf16(
                    af[mi], bfr[ni], acc[mi][ni], 0, 0, 0);
    }
    float scale = scale_ptr ? scale_ptr[0] : 1.0f;
#pragma unroll
    for (int mi = 0; mi < 4; ++mi)
#pragma unroll
        for (int ni = 0; ni < 4; ++ni)
#pragma unroll
            for (int r = 0; r < 4; ++r) {
                int row = row0 + wm * 64 + mi * 16 + quad * 4 + r;
                int col = col0 + wn * 64 + ni * 16 + r16;
                float v = acc[mi][ni][r];
                if (mode == 2) v = scale * v + resid[(size_t)row * ldc + col];
                C[(size_t)row * ldc + col] = v;
            }
}

// ---------------- Generic fp32 tiled GEMM (small GEMMs only) -------
// mode 0: plain   mode 1: softplus(acc + bias[c])
#define BM 64
#define BN 64
#define BK 16
__global__ __launch_bounds__(256)
void gemm_kernel(const float* __restrict__ A, int lda,
                 const float* __restrict__ W, int ldw,
                 float* __restrict__ C, int ldc,
                 int M, int N, int K,
                 int mode, const float* __restrict__ bias) {
    __shared__ float As[BK][BM];
    __shared__ float Ws[BK][BN];
    int tid = threadIdx.x;
    int row0 = blockIdx.y * BM, col0 = blockIdx.x * BN;
    int tx = tid & 15, ty = tid >> 4;
    int ar = tid >> 2;
    int ac = (tid & 3) * 4;
    int wr = tid >> 4;
    int wc = (tid & 15) * 4;
    float acc[4][4] = {{0,0,0,0},{0,0,0,0},{0,0,0,0},{0,0,0,0}};
    for (int k0 = 0; k0 < K; k0 += BK) {
        float4 av = *(const float4*)(A + (size_t)(row0 + ar) * lda + k0 + ac);
        float4 wv;
        if (col0 + wc < N)
            wv = *(const float4*)(W + (size_t)(k0 + wr) * ldw + col0 + wc);
        else
            wv = make_float4(0.f, 0.f, 0.f, 0.f);
        __syncthreads();
        As[ac + 0][ar] = av.x; As[ac + 1][ar] = av.y;
        As[ac + 2][ar] = av.z; As[ac + 3][ar] = av.w;
        *(float4*)&Ws[wr][wc] = wv;
        __syncthreads();
#pragma unroll
        for (int kk = 0; kk < BK; ++kk) {
            float4 a4 = *(const float4*)&As[kk][ty * 4];
            float4 w4 = *(const float4*)&Ws[kk][tx * 4];
            acc[0][0] = fmaf(a4.x, w4.x, acc[0][0]);
            acc[0][1] = fmaf(a4.x, w4.y, acc[0][1]);
            acc[0][2] = fmaf(a4.x, w4.z, acc[0][2]);
            acc[0][3] = fmaf(a4.x, w4.w, acc[0][3]);
            acc[1][0] = fmaf(a4.y, w4.x, acc[1][0]);
            acc[1][1] = fmaf(a4.y, w4.y, acc[1][1]);
            acc[1][2] = fmaf(a4.y, w4.z, acc[1][2]);
            acc[1][3] = fmaf(a4.y, w4.w, acc[1][3]);
            acc[2][0] = fmaf(a4.z, w4.x, acc[2][0]);
            acc[2][1] = fmaf(a4.z, w4.y, acc[2][1]);
            acc[2][2] = fmaf(a4.z, w4.z, acc[2][2]);
            acc[2][3] = fmaf(a4.z, w4.w, acc[2][3]);
            acc[3][0] = fmaf(a4.w, w4.x, acc[3][0]);
            acc[3][1] = fmaf(a4.w, w4.y, acc[3][1]);
            acc[3][2] = fmaf(a4.w, w4.z, acc[3][2]);
            acc[3][3] = fmaf(a4.w, w4.w, acc[3][3]);
        }
    }
#pragma unroll
    for (int i = 0; i < 4; ++i) {
        int r = row0 + ty * 4 + i;
#pragma unroll
        for (int j = 0; j < 4; ++j) {
            int c = col0 + tx * 4 + j;
            if (c >= N) continue;
            float v = acc[i][j];
            if (mode == 1) {
                v += bias[c];
                v = (v > 20.0f) ? v : log1pf(expf(v));   // softplus
            }
            C[(size_t)r * ldc + c] = v;
        }
    }
}

// ---------------- Causal depthwise conv (K=4) + bias + silu ----------------
// xm has row stride XZLD (x_main half of fused xz buffer)
__global__ __launch_bounds__(256)
void conv_kernel(const float* __restrict__ xm, const float* __restrict__ cw,
                 const float* __restrict__ cb, float* __restrict__ xs,
                 float* __restrict__ conv_state_out) {
    int idx = blockIdx.x * 256 + threadIdx.x;
    int d = idx & (D_INNER - 1);
    int l = (idx / D_INNER) & (LL - 1);
    int b = idx / (D_INNER * LL);
    const float* base = xm + (size_t)b * LL * XZLD + d;
    float acc = cb[d];
#pragma unroll
    for (int k = 0; k < D_CONVK; ++k) {
        int li = l - (D_CONVK - 1) + k;
        if (li >= 0) acc += base[(size_t)li * XZLD] * cw[d * D_CONVK + k];
    }
    xs[idx] = acc / (1.0f + expf(-acc));   // silu
    if (l >= LL - (D_CONVK - 1)) {
        float xv = base[(size_t)l * XZLD];
        conv_state_out[((size_t)b * D_INNER + d) * (D_CONVK - 1) + (l - (LL - (D_CONVK - 1)))] = xv;
    }
}

// ---------------- Selective scan, chunked ----------------
__global__ __launch_bounds__(256)
void scan_part1(const float* __restrict__ dt, const float* __restrict__ xdbl,
                const float* __restrict__ xs, const float* __restrict__ A_log,
                float* __restrict__ Ebuf, float* __restrict__ Sbuf) {
    __shared__ float dt_t[SC][16], x_t[SC][16], Bt[SC][16];
    int d0 = blockIdx.x * 16;
    int c  = blockIdx.y;
    int b  = blockIdx.z;
    int tid = threadIdx.x;
    int n = tid & 15, dg = tid >> 4;
    int d = d0 + dg;
    float al2 = -expf(A_log[d * D_STATE + n]) * 1.44269504088896340736f;
    float E = 1.0f, S = 0.0f;
    size_t rowbase = (size_t)b * LL + (size_t)c * CH;
    for (int l0 = 0; l0 < CH; l0 += SC) {
        for (int e_i = tid; e_i < SC * 16; e_i += 256) {
            int i = e_i >> 4, j = e_i & 15;
            size_t r = rowbase + l0 + i;
            dt_t[i][j] = dt[r * D_INNER + d0 + j];
            x_t[i][j]  = xs[r * D_INNER + d0 + j];
            Bt[i][j]   = xdbl[r * 96 + DT_RANK + j];
        }
        __syncthreads();
#pragma unroll 8
        for (int i = 0; i < SC; ++i) {
            float dtv = dt_t[i][dg];
            float e = exp2f(al2 * dtv);
            S = fmaf(e, S, dtv * Bt[i][n] * x_t[i][dg]);
            E *= e;
        }
        __syncthreads();
    }
    size_t idx = (((size_t)b * NC + c) * D_INNER + d) * D_STATE + n;
    Ebuf[idx] = E;
    Sbuf[idx] = S;
}

// y written as bf16 (feeds out_proj MFMA). z read from fused xz (stride XZLD).
__global__ __launch_bounds__(256)
void scan_part3(const float* __restrict__ dt, const float* __restrict__ xdbl,
                const float* __restrict__ xs, const float* __restrict__ z,
                const float* __restrict__ A_log, const float* __restrict__ Dp,
                const float* __restrict__ Ebuf, const float* __restrict__ Sbuf,
                unsigned short* __restrict__ y, float* __restrict__ ssm_out) {
    __shared__ float dt_t[SC][16], x_t[SC][16], z_t[SC][16];
    __shared__ float Bt[SC][16], Ct[SC][16], y_t[SC][16];
    int d0 = blockIdx.x * 16;
    int c  = blockIdx.y;
    int b  = blockIdx.z;
    int tid = threadIdx.x;
    int n = tid & 15, dg = tid >> 4;
    int d = d0 + dg;
    float al2 = -expf(A_log[d * D_STATE + n]) * 1.44269504088896340736f;
    float Dv = Dp[d];
    float h = 0.0f;
    size_t pidx = (((size_t)b * NC) * D_INNER + d) * D_STATE + n;
    for (int k = 0; k < c; ++k) {
        size_t q = pidx + (size_t)k * D_INNER * D_STATE;
        h = fmaf(Ebuf[q], h, Sbuf[q]);
    }
    size_t rowbase = (size_t)b * LL + (size_t)c * CH;
    for (int l0 = 0; l0 < CH; l0 += SC) {
        for (int e_i = tid; e_i < SC * 16; e_i += 256) {
            int i = e_i >> 4, j = e_i & 15;
            size_t r = rowbase + l0 + i;
            dt_t[i][j] = dt[r * D_INNER + d0 + j];
            x_t[i][j]  = xs[r * D_INNER + d0 + j];
            z_t[i][j]  = z [r * XZLD + d0 + j];
            Bt[i][j]   = xdbl[r * 96 + DT_RANK + j];
            Ct[i][j]   = xdbl[r * 96 + DT_RANK + D_STATE + j];
        }
        __syncthreads();
#pragma unroll 4
        for (int i = 0; i < SC; ++i) {
            float dtv = dt_t[i][dg];
            float xv  = x_t[i][dg];
            float e = exp2f(al2 * dtv);
            h = fmaf(e, h, dtv * Bt[i][n] * xv);
            float p = h * Ct[i][n];
            p += __shfl_xor(p, 1);
            p += __shfl_xor(p, 2);
            p += __shfl_xor(p, 4);
            p += __shfl_xor(p, 8);
            if (n == 0) {
                float zv = z_t[i][dg];
                y_t[i][dg] = (p + xv * Dv) * (zv / (1.0f + expf(-zv)));
            }
        }
        __syncthreads();
        for (int e_i = tid; e_i < SC * 16; e_i += 256) {
            int i = e_i >> 4, j = e_i & 15;
            y[(rowbase + l0 + i) * D_INNER + d0 + j] = f2bf(y_t[i][j]);
        }
        __syncthreads();
    }
    if (c == NC - 1)
        ssm_out[((size_t)b * D_INNER + d) * D_STATE + n] = h;
}

// ---------------- launch ----------------
extern "C" void kernel_launch(void* const* d_in, const int* in_sizes, int n_in,
                              void* d_out, int out_size, void* d_ws, size_t ws_size,
                              hipStream_t stream) {
    (void)in_sizes; (void)n_in; (void)out_size; (void)ws_size;
    const float* x      = (const float*)d_in[0];
    const float* ln_w   = (const float*)d_in[1];
    const float* ln_b   = (const float*)d_in[2];
    const float* Win    = (const float*)d_in[3];   // [1024, 4096]
    const float* convw  = (const float*)d_in[4];   // [2048, 4]
    const float* convb  = (const float*)d_in[5];
    const float* Wx     = (const float*)d_in[6];   // [2048, 96]
    const float* Wdt    = (const float*)d_in[7];   // [64, 2048]
    const float* bdt    = (const float*)d_in[8];
    const float* A_log  = (const float*)d_in[9];   // [2048, 16]
    const float* Dp     = (const float*)d_in[10];
    const float* Wout   = (const float*)d_in[11];  // [2048, 1024]
    const float* rscale = (const float*)d_in[12];  // [1]

    float* out      = (float*)d_out;                          // [4096,1024]
    float* ssm_out  = out + (size_t)NROWS * D_MODEL;          // [2,2048,16]
    float* conv_out = ssm_out + (size_t)BB * D_INNER * D_STATE; // [2,2048,3]

    // workspace layout (<=152.6 MB, proven safe in R2)
    float* ws   = (float*)d_ws;
    float* xz   = ws;                                    // 4096*4096 fp32 (xmain|z)
    float* xsb  = xz + (size_t)NROWS * XZLD;             // 4096*2048 fp32
    float* dtb  = xsb + (size_t)NROWS * D_INNER;         // 4096*2048 fp32
    float* xdbl = dtb + (size_t)NROWS * D_INNER;         // 4096*96 fp32
    unsigned short* xnb  = (unsigned short*)(xdbl + (size_t)NROWS * 96); // 4096*1024 bf16
    unsigned short* wtin = xnb + (size_t)NROWS * D_MODEL;                // 4096*1024 bf16
    // aliases of dead regions:
    float* Ebuf = (float*)xnb;                           // after in_proj, xnb dead
    float* Sbuf = Ebuf + (size_t)BB * NC * D_INNER * D_STATE;
    unsigned short* ybuf  = wtin;                        // after in_proj, wtin dead
    unsigned short* wtout = (unsigned short*)dtb;        // after scan, dtb dead
    float* zhalf = xz + D_INNER;                         // z columns of fused xz

    // 1. LN -> bf16 A
    ln_kernel<<<NROWS, 256, 0, stream>>>(x, ln_w, ln_b, xnb);

    // 2. Win [1024,4096] -> bf16 Wt [4096,1024]
    transpose_cast<<<dim3(2 * D_INNER / 32, D_MODEL / 32), 256, 0, stream>>>(
        Win, wtin, D_MODEL, 2 * D_INNER);

    // 3. fused in_proj: xz[4096,4096] = xnb @ Win   (MFMA bf16)
    mfma_gemm<<<dim3(2 * D_INNER / 128, NROWS / 128), 256, 0, stream>>>(
        xnb, wtin, xz, XZLD, D_MODEL, 0, nullptr, nullptr);

    // 4. conv + silu
    conv_kernel<<<(NROWS * D_INNER) / 256, 256, 0, stream>>>(
        xz, convw, convb, xsb, conv_out);

    // 5. x_dbl = x_s @ x_proj_w   [4096 x 96]  (fp32)
    gemm_kernel<<<dim3((96 + BN - 1) / BN, NROWS / BM), 256, 0, stream>>>(
        xsb, D_INNER, Wx, 96, xdbl, 96,
        NROWS, 96, D_INNER, 0, nullptr);

    // 6. dt = softplus(x_dbl[:, :64] @ dt_proj_w + b)  (fp32)
    gemm_kernel<<<dim3(D_INNER / BN, NROWS / BM), 256, 0, stream>>>(
        xdbl, 96, Wdt, D_INNER, dtb, D_INNER,
        NROWS, D_INNER, DT_RANK, 1, bdt);

    // 7+8. chunked selective scan
    scan_part1<<<dim3(D_INNER / 16, NC, BB), 256, 0, stream>>>(
        dtb, xdbl, xsb, A_log, Ebuf, Sbuf);
    scan_part3<<<dim3(D_INNER / 16, NC, BB), 256, 0, stream>>>(
        dtb, xdbl, xsb, zhalf, A_log, Dp, Ebuf, Sbuf, ybuf, ssm_out);

    // 9. Wout [2048,1024] -> bf16 Wt [1024,2048]  (into dead dtb region)
    transpose_cast<<<dim3(D_MODEL / 32, D_INNER / 32), 256, 0, stream>>>(
        Wout, wtout, D_INNER, D_MODEL);

    // 10. out = res_scale * (y @ out_proj_w) + residual  (MFMA bf16)
    mfma_gemm<<<dim3(D_MODEL / 128, NROWS / 128), 256, 0, stream>>>(
        ybuf, wtout, out, D_MODEL, D_INNER, 2, x, rscale);
}

// Round 4
// 476.206 us; speedup vs baseline: 3.4475x; 1.3193x over previous
//
#include <hip/hip_runtime.h>
#include <math.h>

#define D_MODEL 1024
#define D_STATE 16
#define D_CONVK 4
#define D_INNER 2048
#define DT_RANK 64
#define BB 2
#define LL 2048
#define NROWS (BB*LL)   // 4096
#define NC 64           // scan chunks
#define CH (LL/NC)      // 32 steps per chunk
#define LOG2E 1.44269504088896340736f

typedef __attribute__((ext_vector_type(8))) short bf16x8;
typedef __attribute__((ext_vector_type(4))) float f32x4;

typedef __attribute__((address_space(3))) unsigned char lds_ucp;
typedef const __attribute__((address_space(1))) unsigned char glb_ucp;
#define GLD16(gp, lp) __builtin_amdgcn_global_load_lds((glb_ucp*)(gp), (lds_ucp*)(lp), 16, 0, 0)

__device__ inline unsigned short f2bf(float f) {
    union { float f; unsigned u; } c; c.f = f;
    unsigned r = c.u + 0x7fff + ((c.u >> 16) & 1);   // round-to-nearest-even
    return (unsigned short)(r >> 16);
}
__device__ inline float bf2f(unsigned short s) {
    union { unsigned u; float f; } c; c.u = ((unsigned)s) << 16;
    return c.f;
}

// ---------------- LayerNorm -> bf16 ----------------
__global__ __launch_bounds__(256)
void ln_kernel(const float* __restrict__ x, const float* __restrict__ w,
               const float* __restrict__ b, unsigned short* __restrict__ xnb) {
    int row = blockIdx.x;
    const float* xr = x + (size_t)row * D_MODEL;
    float4 v = ((const float4*)xr)[threadIdx.x];
    float s  = v.x + v.y + v.z + v.w;
    float ss = v.x*v.x + v.y*v.y + v.z*v.z + v.w*v.w;
    for (int off = 32; off > 0; off >>= 1) {
        s  += __shfl_down(s, off);
        ss += __shfl_down(ss, off);
    }
    __shared__ float red[8];
    int lane = threadIdx.x & 63, wv = threadIdx.x >> 6;
    if (lane == 0) { red[wv] = s; red[wv + 4] = ss; }
    __syncthreads();
    if (threadIdx.x == 0) {
        float ts  = red[0] + red[1] + red[2] + red[3];
        float tss = red[4] + red[5] + red[6] + red[7];
        float mu  = ts / D_MODEL;
        float var = tss / D_MODEL - mu * mu;
        red[0] = mu; red[1] = rsqrtf(var + 1e-5f);
    }
    __syncthreads();
    float mu = red[0], rs = red[1];
    float4 w4 = ((const float4*)w)[threadIdx.x];
    float4 b4 = ((const float4*)b)[threadIdx.x];
    ushort4 o;
    o.x = f2bf((v.x - mu) * rs * w4.x + b4.x);
    o.y = f2bf((v.y - mu) * rs * w4.y + b4.y);
    o.z = f2bf((v.z - mu) * rs * w4.z + b4.z);
    o.w = f2bf((v.w - mu) * rs * w4.w + b4.w);
    ((ushort4*)(xnb + (size_t)row * D_MODEL))[threadIdx.x] = o;
}

// ------- transpose + cast fp32 W[K][Nsrc] -> bf16 Wt[Npad][K], pad w/ 0 -----
// grid (Npad/32, K/32)
__global__ __launch_bounds__(256)
void transpose_cast(const float* __restrict__ W, unsigned short* __restrict__ Wt,
                    int K, int Nsrc) {
    __shared__ float t[32][33];
    int k0 = blockIdx.y * 32, n0 = blockIdx.x * 32;
    int tx = threadIdx.x & 31, ty = threadIdx.x >> 5;   // ty 0..7
#pragma unroll
    for (int i = 0; i < 32; i += 8)
        t[ty + i][tx] = (n0 + tx < Nsrc)
            ? W[(size_t)(k0 + ty + i) * Nsrc + n0 + tx] : 0.0f;
    __syncthreads();
#pragma unroll
    for (int i = 0; i < 32; i += 8)
        Wt[(size_t)(n0 + ty + i) * K + k0 + tx] = f2bf(t[tx][ty + i]);
}

// ---------------- bf16 MFMA GEMM: C = A[M,K] @ Wt[N,K]^T -------------------
// 128x128 tile, 4 waves x (4x4 of 16x16x32).
// mode 0: store fp32 if col<Ncols
// mode 2: scale*acc + resid, store fp32
// mode 3: col<split -> fp32 C[row*ldc+col]; else bf16 out2[row*ldc+col-split]
__global__ __launch_bounds__(256)
void mfma_gemm(const unsigned short* __restrict__ A,
               const unsigned short* __restrict__ Wt,
               float* __restrict__ C, int ldc, int K, int mode,
               const float* __restrict__ resid,
               const float* __restrict__ scale_ptr,
               int Ncols, int split, unsigned short* __restrict__ out2) {
    __shared__ short As[128 * 32];
    __shared__ short Bs[128 * 32];
    int tid = threadIdx.x;
    int lane = tid & 63, w = tid >> 6;
    int wm = w & 1, wn = w >> 1;
    int row0 = blockIdx.y * 128, col0 = blockIdx.x * 128;
    f32x4 acc[4][4] = {};
    const unsigned short* gA0 = A  + (size_t)row0 * K;
    const unsigned short* gB0 = Wt + (size_t)col0 * K;
    int r_in = lane >> 2;
    int e16  = (lane & 3) * 8;
    int quad = lane >> 4, r16 = lane & 15;
    for (int k0 = 0; k0 < K; k0 += 32) {
        __syncthreads();
#pragma unroll
        for (int t = 0; t < 2; ++t) {
            int p = w * 2 + t;
            int row = p * 16 + r_in;
            GLD16(gA0 + (size_t)row * K + k0 + e16, (char*)As + p * 1024);
            GLD16(gB0 + (size_t)row * K + k0 + e16, (char*)Bs + p * 1024);
        }
        __syncthreads();
        bf16x8 af[4], bfr[4];
#pragma unroll
        for (int i = 0; i < 4; ++i) {
            af[i]  = *(const bf16x8*)&As[(wm * 64 + i * 16 + r16) * 32 + quad * 8];
            bfr[i] = *(const bf16x8*)&Bs[(wn * 64 + i * 16 + r16) * 32 + quad * 8];
        }
#pragma unroll
        for (int mi = 0; mi < 4; ++mi)
#pragma unroll
            for (int ni = 0; ni < 4; ++ni)
                acc[mi][ni] = __builtin_amdgcn_mfma_f32_16x16x32_bf16(
                    af[mi], bfr[ni], acc[mi][ni], 0, 0, 0);
    }
    float scale = scale_ptr ? scale_ptr[0] : 1.0f;
#pragma unroll
    for (int mi = 0; mi < 4; ++mi)
#pragma unroll
        for (int ni = 0; ni < 4; ++ni)
#pragma unroll
            for (int r = 0; r < 4; ++r) {
                int row = row0 + wm * 64 + mi * 16 + quad * 4 + r;
                int col = col0 + wn * 64 + ni * 16 + r16;
                float v = acc[mi][ni][r];
                if (mode == 3) {
                    if (col < split) C[(size_t)row * ldc + col] = v;
                    else out2[(size_t)row * ldc + col - split] = f2bf(v);
                } else {
                    if (col >= Ncols) continue;
                    if (mode == 2) v = scale * v + resid[(size_t)row * ldc + col];
                    C[(size_t)row * ldc + col] = v;
                }
            }
}

// ---------------- fp32 tiled GEMM (dt projection only) -------
// mode 1: softplus(acc + bias[c])
#define BM 64
#define BN 64
#define BK 16
__global__ __launch_bounds__(256)
void gemm_kernel(const float* __restrict__ A, int lda,
                 const float* __restrict__ W, int ldw,
                 float* __restrict__ C, int ldc,
                 int M, int N, int K,
                 int mode, const float* __restrict__ bias) {
    __shared__ float As[BK][BM];
    __shared__ float Ws[BK][BN];
    int tid = threadIdx.x;
    int row0 = blockIdx.y * BM, col0 = blockIdx.x * BN;
    int tx = tid & 15, ty = tid >> 4;
    int ar = tid >> 2;
    int ac = (tid & 3) * 4;
    int wr = tid >> 4;
    int wc = (tid & 15) * 4;
    float acc[4][4] = {{0,0,0,0},{0,0,0,0},{0,0,0,0},{0,0,0,0}};
    for (int k0 = 0; k0 < K; k0 += BK) {
        float4 av = *(const float4*)(A + (size_t)(row0 + ar) * lda + k0 + ac);
        float4 wv = *(const float4*)(W + (size_t)(k0 + wr) * ldw + col0 + wc);
        __syncthreads();
        As[ac + 0][ar] = av.x; As[ac + 1][ar] = av.y;
        As[ac + 2][ar] = av.z; As[ac + 3][ar] = av.w;
        *(float4*)&Ws[wr][wc] = wv;
        __syncthreads();
#pragma unroll
        for (int kk = 0; kk < BK; ++kk) {
            float4 a4 = *(const float4*)&As[kk][ty * 4];
            float4 w4 = *(const float4*)&Ws[kk][tx * 4];
            acc[0][0] = fmaf(a4.x, w4.x, acc[0][0]);
            acc[0][1] = fmaf(a4.x, w4.y, acc[0][1]);
            acc[0][2] = fmaf(a4.x, w4.z, acc[0][2]);
            acc[0][3] = fmaf(a4.x, w4.w, acc[0][3]);
            acc[1][0] = fmaf(a4.y, w4.x, acc[1][0]);
            acc[1][1] = fmaf(a4.y, w4.y, acc[1][1]);
            acc[1][2] = fmaf(a4.y, w4.z, acc[1][2]);
            acc[1][3] = fmaf(a4.y, w4.w, acc[1][3]);
            acc[2][0] = fmaf(a4.z, w4.x, acc[2][0]);
            acc[2][1] = fmaf(a4.z, w4.y, acc[2][1]);
            acc[2][2] = fmaf(a4.z, w4.z, acc[2][2]);
            acc[2][3] = fmaf(a4.z, w4.w, acc[2][3]);
            acc[3][0] = fmaf(a4.w, w4.x, acc[3][0]);
            acc[3][1] = fmaf(a4.w, w4.y, acc[3][1]);
            acc[3][2] = fmaf(a4.w, w4.z, acc[3][2]);
            acc[3][3] = fmaf(a4.w, w4.w, acc[3][3]);
        }
    }
#pragma unroll
    for (int i = 0; i < 4; ++i) {
        int r = row0 + ty * 4 + i;
#pragma unroll
        for (int j = 0; j < 4; ++j) {
            int c = col0 + tx * 4 + j;
            float v = acc[i][j];
            if (mode == 1) {
                v += bias[c];
                v = (v > 20.0f) ? v : log1pf(expf(v));   // softplus
            }
            C[(size_t)r * ldc + c] = v;
        }
    }
}

// ---------- Causal depthwise conv (K=4) + bias + silu -> bf16 ----------
__global__ __launch_bounds__(256)
void conv_kernel(const float* __restrict__ xm, const float* __restrict__ cw,
                 const float* __restrict__ cb, unsigned short* __restrict__ xs,
                 float* __restrict__ conv_state_out) {
    int idx = blockIdx.x * 256 + threadIdx.x;
    int d = idx & (D_INNER - 1);
    int l = (idx >> 11) & (LL - 1);
    int b = idx >> 22;
    const float* base = xm + (size_t)b * LL * D_INNER + d;
    float acc = cb[d];
#pragma unroll
    for (int k = 0; k < D_CONVK; ++k) {
        int li = l - (D_CONVK - 1) + k;
        if (li >= 0) acc += base[(size_t)li * D_INNER] * cw[d * D_CONVK + k];
    }
    xs[idx] = f2bf(acc / (1.0f + expf(-acc)));   // silu
    if (l >= LL - (D_CONVK - 1)) {
        float xv = base[(size_t)l * D_INNER];
        conv_state_out[((size_t)b * D_INNER + d) * (D_CONVK - 1) + (l - (LL - (D_CONVK - 1)))] = xv;
    }
}

// ---------------- Selective scan: thread-per-d, 16 n-states in regs --------
// Pass 1: per (b,c,d) compute E[16] = exp2(al2*sum dt), S[16] = local scan.
// grid (Di/256, NC, B)
__global__ __launch_bounds__(256)
void scan_part1(const float* __restrict__ dt, const float* __restrict__ xdbl,
                const unsigned short* __restrict__ xs,
                const float* __restrict__ A_log,
                float* __restrict__ Ebuf, float* __restrict__ Sbuf) {
    __shared__ float Bs[CH][32];
    int d = blockIdx.x * 256 + threadIdx.x;
    int c = blockIdx.y, b = blockIdx.z;
    size_t rowbase = (size_t)b * LL + (size_t)c * CH;
    // stage B|C (xdbl cols 64..95) for the chunk
    for (int e = threadIdx.x; e < CH * 32; e += 256) {
        int i = e >> 5, j = e & 31;
        Bs[i][j] = xdbl[(rowbase + i) * 96 + DT_RANK + j];
    }
    float al2[16];
    {
        const float4* ap = (const float4*)(A_log + (size_t)d * D_STATE);
#pragma unroll
        for (int q = 0; q < 4; ++q) {
            float4 a4 = ap[q];
            al2[q*4+0] = -expf(a4.x) * LOG2E;
            al2[q*4+1] = -expf(a4.y) * LOG2E;
            al2[q*4+2] = -expf(a4.z) * LOG2E;
            al2[q*4+3] = -expf(a4.w) * LOG2E;
        }
    }
    __syncthreads();
    float S[16];
#pragma unroll
    for (int n = 0; n < 16; ++n) S[n] = 0.0f;
    float Tsum = 0.0f;
    float dtv = dt[rowbase * D_INNER + d];
    float xv  = bf2f(xs[rowbase * D_INNER + d]);
    for (int i = 0; i < CH; ++i) {
        float dtn = 0.0f, xn2 = 0.0f;
        if (i + 1 < CH) {
            size_t r2 = (rowbase + i + 1) * D_INNER + d;
            dtn = dt[r2]; xn2 = bf2f(xs[r2]);
        }
        Tsum += dtv;
        float dtx = dtv * xv;
#pragma unroll
        for (int q = 0; q < 4; ++q) {
            float4 Bv = *(const float4*)&Bs[i][q * 4];
            S[q*4+0] = fmaf(exp2f(al2[q*4+0] * dtv), S[q*4+0], dtx * Bv.x);
            S[q*4+1] = fmaf(exp2f(al2[q*4+1] * dtv), S[q*4+1], dtx * Bv.y);
            S[q*4+2] = fmaf(exp2f(al2[q*4+2] * dtv), S[q*4+2], dtx * Bv.z);
            S[q*4+3] = fmaf(exp2f(al2[q*4+3] * dtv), S[q*4+3], dtx * Bv.w);
        }
        dtv = dtn; xv = xn2;
    }
    size_t o = (((size_t)b * NC + c) * D_INNER + d) * D_STATE;
#pragma unroll
    for (int q = 0; q < 4; ++q) {
        float4 Ev, Sv;
        Ev.x = exp2f(al2[q*4+0] * Tsum); Ev.y = exp2f(al2[q*4+1] * Tsum);
        Ev.z = exp2f(al2[q*4+2] * Tsum); Ev.w = exp2f(al2[q*4+3] * Tsum);
        Sv.x = S[q*4+0]; Sv.y = S[q*4+1]; Sv.z = S[q*4+2]; Sv.w = S[q*4+3];
        *(float4*)(Ebuf + o + q * 4) = Ev;
        *(float4*)(Sbuf + o + q * 4) = Sv;
    }
}

// Pass 2: fold (E,S) across chunks -> Hin[b,c,d,n] = state entering chunk c.
// Hin may alias Ebuf (loads of each batch precede its stores). 65536 threads.
__global__ __launch_bounds__(256)
void scan_part2(const float* E, const float* S, float* Hin) {
    int t = blockIdx.x * 256 + threadIdx.x;
    int b = t >> 15;
    int rem = t & 32767;
    size_t base = (size_t)b * NC * (D_INNER * D_STATE) + rem;
    float h = 0.0f;
    for (int c0 = 0; c0 < NC; c0 += 16) {
        float Ec[16], Sc[16];
#pragma unroll
        for (int k = 0; k < 16; ++k) {
            size_t q = base + (size_t)(c0 + k) * (D_INNER * D_STATE);
            Ec[k] = E[q]; Sc[k] = S[q];
        }
#pragma unroll
        for (int k = 0; k < 16; ++k) {
            Hin[base + (size_t)(c0 + k) * (D_INNER * D_STATE)] = h;
            h = fmaf(Ec[k], h, Sc[k]);
        }
    }
}

// Pass 3: local scan with h_in from Hin; emits y (bf16) and final ssm state.
__global__ __launch_bounds__(256)
void scan_part3(const float* __restrict__ dt, const float* __restrict__ xdbl,
                const unsigned short* __restrict__ xs,
                const unsigned short* __restrict__ zb,
                const float* __restrict__ A_log, const float* __restrict__ Dp,
                const float* __restrict__ Hin,
                unsigned short* __restrict__ y, float* __restrict__ ssm_out) {
    __shared__ float Bs[CH][32];
    int d = blockIdx.x * 256 + threadIdx.x;
    int c = blockIdx.y, b = blockIdx.z;
    size_t rowbase = (size_t)b * LL + (size_t)c * CH;
    for (int e = threadIdx.x; e < CH * 32; e += 256) {
        int i = e >> 5, j = e & 31;
        Bs[i][j] = xdbl[(rowbase + i) * 96 + DT_RANK + j];
    }
    float al2[16];
    {
        const float4* ap = (const float4*)(A_log + (size_t)d * D_STATE);
#pragma unroll
        for (int q = 0; q < 4; ++q) {
            float4 a4 = ap[q];
            al2[q*4+0] = -expf(a4.x) * LOG2E;
            al2[q*4+1] = -expf(a4.y) * LOG2E;
            al2[q*4+2] = -expf(a4.z) * LOG2E;
            al2[q*4+3] = -expf(a4.w) * LOG2E;
        }
    }
    float Dv = Dp[d];
    float h[16];
    {
        const float4* hp = (const float4*)(Hin + (((size_t)b * NC + c) * D_INNER + d) * D_STATE);
#pragma unroll
        for (int q = 0; q < 4; ++q) {
            float4 h4 = hp[q];
            h[q*4+0] = h4.x; h[q*4+1] = h4.y; h[q*4+2] = h4.z; h[q*4+3] = h4.w;
        }
    }
    __syncthreads();
    size_t r0 = rowbase * D_INNER + d;
    float dtv = dt[r0];
    float xv  = bf2f(xs[r0]);
    float zv  = bf2f(zb[r0]);
    for (int i = 0; i < CH; ++i) {
        float dtn = 0.0f, xn2 = 0.0f, zn2 = 0.0f;
        if (i + 1 < CH) {
            size_t r2 = (rowbase + i + 1) * D_INNER + d;
            dtn = dt[r2]; xn2 = bf2f(xs[r2]); zn2 = bf2f(zb[r2]);
        }
        float dtx = dtv * xv;
        float yv = 0.0f;
#pragma unroll
        for (int q = 0; q < 4; ++q) {
            float4 Bv = *(const float4*)&Bs[i][q * 4];
            float4 Cv = *(const float4*)&Bs[i][16 + q * 4];
            h[q*4+0] = fmaf(exp2f(al2[q*4+0] * dtv), h[q*4+0], dtx * Bv.x);
            h[q*4+1] = fmaf(exp2f(al2[q*4+1] * dtv), h[q*4+1], dtx * Bv.y);
            h[q*4+2] = fmaf(exp2f(al2[q*4+2] * dtv), h[q*4+2], dtx * Bv.z);
            h[q*4+3] = fmaf(exp2f(al2[q*4+3] * dtv), h[q*4+3], dtx * Bv.w);
            yv = fmaf(h[q*4+0], Cv.x, yv);
            yv = fmaf(h[q*4+1], Cv.y, yv);
            yv = fmaf(h[q*4+2], Cv.z, yv);
            yv = fmaf(h[q*4+3], Cv.w, yv);
        }
        yv = (yv + xv * Dv) * (zv / (1.0f + expf(-zv)));
        y[(rowbase + i) * D_INNER + d] = f2bf(yv);
        dtv = dtn; xv = xn2; zv = zn2;
    }
    if (c == NC - 1) {
        float* sp = ssm_out + ((size_t)b * D_INNER + d) * D_STATE;
#pragma unroll
        for (int q = 0; q < 4; ++q) {
            float4 h4;
            h4.x = h[q*4+0]; h4.y = h[q*4+1]; h4.z = h[q*4+2]; h4.w = h[q*4+3];
            *(float4*)(sp + q * 4) = h4;
        }
    }
}

// ---------------- launch ----------------
extern "C" void kernel_launch(void* const* d_in, const int* in_sizes, int n_in,
                              void* d_out, int out_size, void* d_ws, size_t ws_size,
                              hipStream_t stream) {
    (void)in_sizes; (void)n_in; (void)out_size; (void)ws_size;
    const float* x      = (const float*)d_in[0];
    const float* ln_w   = (const float*)d_in[1];
    const float* ln_b   = (const float*)d_in[2];
    const float* Win    = (const float*)d_in[3];   // [1024, 4096]
    const float* convw  = (const float*)d_in[4];   // [2048, 4]
    const float* convb  = (const float*)d_in[5];
    const float* Wx     = (const float*)d_in[6];   // [2048, 96]
    const float* Wdt    = (const float*)d_in[7];   // [64, 2048]
    const float* bdt    = (const float*)d_in[8];
    const float* A_log  = (const float*)d_in[9];   // [2048, 16]
    const float* Dp     = (const float*)d_in[10];
    const float* Wout   = (const float*)d_in[11];  // [2048, 1024]
    const float* rscale = (const float*)d_in[12];  // [1]

    float* out      = (float*)d_out;
    float* ssm_out  = out + (size_t)NROWS * D_MODEL;
    float* conv_out = ssm_out + (size_t)BB * D_INNER * D_STATE;

    // ---- workspace layout (floats), ~136 MB total ----
    float* ws = (float*)d_ws;
    float* xmain = ws;                                      // 8.39M f  [in_proj->conv]
    unsigned short* zb = (unsigned short*)(xmain + (size_t)NROWS * D_INNER);       // 8.39M us (4.19M f)
    float* dtb  = (float*)zb + (size_t)NROWS * D_INNER / 2; // 8.39M f
    float* xdbl = dtb + (size_t)NROWS * D_INNER;            // 0.393M f
    unsigned short* xnb  = (unsigned short*)(xdbl + (size_t)NROWS * 96);  // 4.19M us
    unsigned short* wtin = xnb + (size_t)NROWS * D_MODEL;                 // 4.19M us
    float* Ebuf = (float*)(wtin + (size_t)(2 * D_INNER) * D_MODEL);       // 4.19M f
    float* Sbuf = Ebuf + (size_t)BB * NC * D_INNER * D_STATE;             // 4.19M f
    unsigned short* Wxt = (unsigned short*)(Sbuf + (size_t)BB * NC * D_INNER * D_STATE); // 0.26M us
    // aliases of dead regions:
    unsigned short* xsb   = xnb;                   // bf16 x_s (conv out), after in_proj
    float* Hin            = Ebuf;                  // pass2 output (aliases E, safe)
    unsigned short* ybuf  = (unsigned short*)xmain;                  // after conv
    unsigned short* wtout = (unsigned short*)(xmain + (size_t)NROWS * D_INNER / 2); // after conv

    // 1. LN -> bf16
    ln_kernel<<<NROWS, 256, 0, stream>>>(x, ln_w, ln_b, xnb);

    // 2. Win -> bf16 Wt [4096,1024]
    transpose_cast<<<dim3(2 * D_INNER / 32, D_MODEL / 32), 256, 0, stream>>>(
        Win, wtin, D_MODEL, 2 * D_INNER);

    // 3. in_proj: cols<2048 -> fp32 xmain, cols>=2048 -> bf16 zb
    mfma_gemm<<<dim3(2 * D_INNER / 128, NROWS / 128), 256, 0, stream>>>(
        xnb, wtin, xmain, D_INNER, D_MODEL, 3, nullptr, nullptr,
        0, D_INNER, zb);

    // 4. conv + silu -> bf16 x_s (+ conv_state)
    conv_kernel<<<(NROWS * D_INNER) / 256, 256, 0, stream>>>(
        xmain, convw, convb, xsb, conv_out);

    // 5. Wout -> bf16 Wt [1024,2048] (xmain region now free)
    transpose_cast<<<dim3(D_MODEL / 32, D_INNER / 32), 256, 0, stream>>>(
        Wout, wtout, D_INNER, D_MODEL);

    // 6. Wx -> bf16 Wt [128(pad),2048]
    transpose_cast<<<dim3(128 / 32, D_INNER / 32), 256, 0, stream>>>(
        Wx, Wxt, D_INNER, 96);

    // 7. x_dbl = x_s @ Wx  [4096 x 96] fp32 (MFMA)
    mfma_gemm<<<dim3(1, NROWS / 128), 256, 0, stream>>>(
        xsb, Wxt, xdbl, 96, D_INNER, 0, nullptr, nullptr, 96, 0, nullptr);

    // 8. dt = softplus(x_dbl[:, :64] @ Wdt + b)  fp32
    gemm_kernel<<<dim3(D_INNER / BN, NROWS / BM), 256, 0, stream>>>(
        xdbl, 96, Wdt, D_INNER, dtb, D_INNER,
        NROWS, D_INNER, DT_RANK, 1, bdt);

    // 9-11. chunked selective scan
    scan_part1<<<dim3(D_INNER / 256, NC, BB), 256, 0, stream>>>(
        dtb, xdbl, xsb, A_log, Ebuf, Sbuf);
    scan_part2<<<(BB * D_INNER * D_STATE) / 256, 256, 0, stream>>>(
        Ebuf, Sbuf, Hin);
    scan_part3<<<dim3(D_INNER / 256, NC, BB), 256, 0, stream>>>(
        dtb, xdbl, xsb, zb, A_log, Dp, Hin, ybuf, ssm_out);

    // 12. out = res_scale * (y @ Wout) + residual  (MFMA)
    mfma_gemm<<<dim3(D_MODEL / 128, NROWS / 128), 256, 0, stream>>>(
        ybuf, wtout, out, D_MODEL, D_INNER, 2, x, rscale,
        D_MODEL, 0, nullptr);
}

// Round 6
// 455.237 us; speedup vs baseline: 3.6063x; 1.0461x over previous
//
#include <hip/hip_runtime.h>
#include <math.h>

#define D_MODEL 1024
#define D_STATE 16
#define D_CONVK 4
#define D_INNER 2048
#define DT_RANK 64
#define BB 2
#define LL 2048
#define NROWS (BB*LL)   // 4096
#define NC 64           // scan chunks
#define CH (LL/NC)      // 32 steps per chunk
#define LOG2E 1.44269504088896340736f

typedef __attribute__((ext_vector_type(8))) short bf16x8;
typedef __attribute__((ext_vector_type(4))) float f32x4;

typedef __attribute__((address_space(3))) unsigned char lds_ucp;
typedef const __attribute__((address_space(1))) unsigned char glb_ucp;
#define GLD16(gp, lp) __builtin_amdgcn_global_load_lds((glb_ucp*)(gp), (lds_ucp*)(lp), 16, 0, 0)

__device__ inline unsigned short f2bf(float f) {
    union { float f; unsigned u; } c; c.f = f;
    unsigned r = c.u + 0x7fff + ((c.u >> 16) & 1);   // round-to-nearest-even
    return (unsigned short)(r >> 16);
}
__device__ inline float bf2f(unsigned short s) {
    union { unsigned u; float f; } c; c.u = ((unsigned)s) << 16;
    return c.f;
}

// ---------------- LayerNorm -> bf16 ----------------
__global__ __launch_bounds__(256)
void ln_kernel(const float* __restrict__ x, const float* __restrict__ w,
               const float* __restrict__ b, unsigned short* __restrict__ xnb) {
    int row = blockIdx.x;
    const float* xr = x + (size_t)row * D_MODEL;
    float4 v = ((const float4*)xr)[threadIdx.x];
    float s  = v.x + v.y + v.z + v.w;
    float ss = v.x*v.x + v.y*v.y + v.z*v.z + v.w*v.w;
    for (int off = 32; off > 0; off >>= 1) {
        s  += __shfl_down(s, off);
        ss += __shfl_down(ss, off);
    }
    __shared__ float red[8];
    int lane = threadIdx.x & 63, wv = threadIdx.x >> 6;
    if (lane == 0) { red[wv] = s; red[wv + 4] = ss; }
    __syncthreads();
    if (threadIdx.x == 0) {
        float ts  = red[0] + red[1] + red[2] + red[3];
        float tss = red[4] + red[5] + red[6] + red[7];
        float mu  = ts / D_MODEL;
        float var = tss / D_MODEL - mu * mu;
        red[0] = mu; red[1] = rsqrtf(var + 1e-5f);
    }
    __syncthreads();
    float mu = red[0], rs = red[1];
    float4 w4 = ((const float4*)w)[threadIdx.x];
    float4 b4 = ((const float4*)b)[threadIdx.x];
    ushort4 o;
    o.x = f2bf((v.x - mu) * rs * w4.x + b4.x);
    o.y = f2bf((v.y - mu) * rs * w4.y + b4.y);
    o.z = f2bf((v.z - mu) * rs * w4.z + b4.z);
    o.w = f2bf((v.w - mu) * rs * w4.w + b4.w);
    ((ushort4*)(xnb + (size_t)row * D_MODEL))[threadIdx.x] = o;
}

// ------- transpose + cast fp32 W[K][Nsrc] -> bf16 Wt[Npad][K], pad w/ 0 -----
__global__ __launch_bounds__(256)
void transpose_cast(const float* __restrict__ W, unsigned short* __restrict__ Wt,
                    int K, int Nsrc) {
    __shared__ float t[32][33];
    int k0 = blockIdx.y * 32, n0 = blockIdx.x * 32;
    int tx = threadIdx.x & 31, ty = threadIdx.x >> 5;   // ty 0..7
#pragma unroll
    for (int i = 0; i < 32; i += 8)
        t[ty + i][tx] = (n0 + tx < Nsrc)
            ? W[(size_t)(k0 + ty + i) * Nsrc + n0 + tx] : 0.0f;
    __syncthreads();
#pragma unroll
    for (int i = 0; i < 32; i += 8)
        Wt[(size_t)(n0 + ty + i) * K + k0 + tx] = f2bf(t[tx][ty + i]);
}

// ---------------- bf16 MFMA GEMM: C = A[M,K] @ Wt[N,K]^T -------------------
// 128x128 tile, 4 waves x (4x4 of 16x16x32). XOR-swizzled LDS (conflict-free).
// blockIdx.z = K-slice (kchunk cols each), C += z*zstride (split-K partials).
// mode 0: store fp32 if col<Ncols
// mode 1: softplus(acc + aux[col]) -> fp32
// mode 2: scale*acc + aux[row*ldc+col] -> fp32
// mode 3: col<split -> fp32 C; else bf16 out2[row*ldc+col-split]
__global__ __launch_bounds__(256)
void mfma_gemm(const unsigned short* __restrict__ A,
               const unsigned short* __restrict__ Wt,
               float* __restrict__ C, int ldc, int K, int kchunk,
               size_t zstride, int mode,
               const float* __restrict__ aux,
               const float* __restrict__ scale_ptr,
               int Ncols, int split, unsigned short* __restrict__ out2) {
    __shared__ short As[128 * 32];
    __shared__ short Bs[128 * 32];
    int tid = threadIdx.x;
    int lane = tid & 63, w = tid >> 6;
    int wm = w & 1, wn = w >> 1;
    int row0 = blockIdx.y * 128, col0 = blockIdx.x * 128;
    int kb = blockIdx.z * kchunk, ke = kb + kchunk;
    C += (size_t)blockIdx.z * zstride;
    f32x4 acc[4][4] = {};
    const unsigned short* gA0 = A  + (size_t)row0 * K;
    const unsigned short* gB0 = Wt + (size_t)col0 * K;
    int r_in = lane >> 2;                                   // row within 16-group
    int e16  = (((lane & 3) ^ ((lane >> 3) & 3)) * 8);      // swizzled chunk
    int quad = lane >> 4, r16 = lane & 15;
    int swz  = (r16 >> 1) & 3;                              // read-side swizzle
    for (int k0 = kb; k0 < ke; k0 += 32) {
        __syncthreads();
#pragma unroll
        for (int t = 0; t < 2; ++t) {
            int p = w * 2 + t;
            int row = p * 16 + r_in;
            GLD16(gA0 + (size_t)row * K + k0 + e16, (char*)As + p * 1024);
            GLD16(gB0 + (size_t)row * K + k0 + e16, (char*)Bs + p * 1024);
        }
        __syncthreads();
        bf16x8 af[4], bfr[4];
#pragma unroll
        for (int i = 0; i < 4; ++i) {
            af[i]  = *(const bf16x8*)&As[(wm * 64 + i * 16 + r16) * 32 + (quad ^ swz) * 8];
            bfr[i] = *(const bf16x8*)&Bs[(wn * 64 + i * 16 + r16) * 32 + (quad ^ swz) * 8];
        }
#pragma unroll
        for (int mi = 0; mi < 4; ++mi)
#pragma unroll
            for (int ni = 0; ni < 4; ++ni)
                acc[mi][ni] = __builtin_amdgcn_mfma_f32_16x16x32_bf16(
                    af[mi], bfr[ni], acc[mi][ni], 0, 0, 0);
    }
    float scale = scale_ptr ? scale_ptr[0] : 1.0f;
    if (mode == 3 && col0 >= split) {
        // whole block in z-half -> bf16
#pragma unroll
        for (int mi = 0; mi < 4; ++mi)
#pragma unroll
            for (int ni = 0; ni < 4; ++ni)
#pragma unroll
                for (int r = 0; r < 4; ++r) {
                    int row = row0 + wm * 64 + mi * 16 + quad * 4 + r;
                    int col = col0 - split + wn * 64 + ni * 16 + r16;
                    out2[(size_t)row * ldc + col] = f2bf(acc[mi][ni][r]);
                }
        return;
    }
#pragma unroll
    for (int mi = 0; mi < 4; ++mi)
#pragma unroll
        for (int ni = 0; ni < 4; ++ni)
#pragma unroll
            for (int r = 0; r < 4; ++r) {
                int row = row0 + wm * 64 + mi * 16 + quad * 4 + r;
                int col = col0 + wn * 64 + ni * 16 + r16;
                if (col >= Ncols && mode != 3) continue;
                float v = acc[mi][ni][r];
                if (mode == 1) {
                    v += aux[col];
                    v = (v > 20.0f) ? v : log1pf(expf(v));   // softplus
                } else if (mode == 2) {
                    v = scale * v + aux[(size_t)row * ldc + col];
                }
                C[(size_t)row * ldc + col] = v;
            }
}

// ---- reduce 4 split-K partials of x_dbl; emit dt-rank bf16 + B|C fp32 ----
__global__ __launch_bounds__(256)
void xdbl_reduce(const float* __restrict__ P,
                 unsigned short* __restrict__ xdtr, float* __restrict__ xbc) {
    const int S1 = NROWS * 96;
    int t = blockIdx.x * 256 + threadIdx.x;
    float s = P[t] + P[t + S1] + P[t + 2 * S1] + P[t + 3 * S1];
    int row = t / 96, col = t - row * 96;
    if (col < DT_RANK) xdtr[(size_t)row * DT_RANK + col] = f2bf(s);
    else xbc[(size_t)row * 32 + col - DT_RANK] = s;
}

// ---------- Causal depthwise conv (K=4) + bias + silu -> bf16 ----------
__global__ __launch_bounds__(256)
void conv_kernel(const float* __restrict__ xm, const float* __restrict__ cw,
                 const float* __restrict__ cb, unsigned short* __restrict__ xs,
                 float* __restrict__ conv_state_out) {
    int idx = blockIdx.x * 256 + threadIdx.x;
    int d = idx & (D_INNER - 1);
    int l = (idx >> 11) & (LL - 1);
    int b = idx >> 22;
    const float* base = xm + (size_t)b * LL * D_INNER + d;
    float acc = cb[d];
#pragma unroll
    for (int k = 0; k < D_CONVK; ++k) {
        int li = l - (D_CONVK - 1) + k;
        if (li >= 0) acc += base[(size_t)li * D_INNER] * cw[d * D_CONVK + k];
    }
    xs[idx] = f2bf(acc / (1.0f + expf(-acc)));   // silu
    if (l >= LL - (D_CONVK - 1)) {
        float xv = base[(size_t)l * D_INNER];
        conv_state_out[((size_t)b * D_INNER + d) * (D_CONVK - 1) + (l - (LL - (D_CONVK - 1)))] = xv;
    }
}

// ---------------- Selective scan: thread-per-d, 16 n-states in regs --------
__global__ __launch_bounds__(256)
void scan_part1(const float* __restrict__ dt, const float* __restrict__ xbc,
                const unsigned short* __restrict__ xs,
                const float* __restrict__ A_log,
                float* __restrict__ Ebuf, float* __restrict__ Sbuf) {
    __shared__ float Bs[CH][32];
    int d = blockIdx.x * 256 + threadIdx.x;
    int c = blockIdx.y, b = blockIdx.z;
    size_t rowbase = (size_t)b * LL + (size_t)c * CH;
    for (int e = threadIdx.x; e < CH * 32; e += 256) {
        int i = e >> 5, j = e & 31;
        Bs[i][j] = xbc[(rowbase + i) * 32 + j];
    }
    float al2[16];
    {
        const float4* ap = (const float4*)(A_log + (size_t)d * D_STATE);
#pragma unroll
        for (int q = 0; q < 4; ++q) {
            float4 a4 = ap[q];
            al2[q*4+0] = -expf(a4.x) * LOG2E;
            al2[q*4+1] = -expf(a4.y) * LOG2E;
            al2[q*4+2] = -expf(a4.z) * LOG2E;
            al2[q*4+3] = -expf(a4.w) * LOG2E;
        }
    }
    __syncthreads();
    float S[16];
#pragma unroll
    for (int n = 0; n < 16; ++n) S[n] = 0.0f;
    float Tsum = 0.0f;
    float dtv = dt[rowbase * D_INNER + d];
    float xv  = bf2f(xs[rowbase * D_INNER + d]);
    for (int i = 0; i < CH; ++i) {
        float dtn = 0.0f, xn2 = 0.0f;
        if (i + 1 < CH) {
            size_t r2 = (rowbase + i + 1) * D_INNER + d;
            dtn = dt[r2]; xn2 = bf2f(xs[r2]);
        }
        Tsum += dtv;
        float dtx = dtv * xv;
#pragma unroll
        for (int q = 0; q < 4; ++q) {
            float4 Bv = *(const float4*)&Bs[i][q * 4];
            S[q*4+0] = fmaf(exp2f(al2[q*4+0] * dtv), S[q*4+0], dtx * Bv.x);
            S[q*4+1] = fmaf(exp2f(al2[q*4+1] * dtv), S[q*4+1], dtx * Bv.y);
            S[q*4+2] = fmaf(exp2f(al2[q*4+2] * dtv), S[q*4+2], dtx * Bv.z);
            S[q*4+3] = fmaf(exp2f(al2[q*4+3] * dtv), S[q*4+3], dtx * Bv.w);
        }
        dtv = dtn; xv = xn2;
    }
    size_t o = (((size_t)b * NC + c) * D_INNER + d) * D_STATE;
#pragma unroll
    for (int q = 0; q < 4; ++q) {
        float4 Ev, Sv;
        Ev.x = exp2f(al2[q*4+0] * Tsum); Ev.y = exp2f(al2[q*4+1] * Tsum);
        Ev.z = exp2f(al2[q*4+2] * Tsum); Ev.w = exp2f(al2[q*4+3] * Tsum);
        Sv.x = S[q*4+0]; Sv.y = S[q*4+1]; Sv.z = S[q*4+2]; Sv.w = S[q*4+3];
        *(float4*)(Ebuf + o + q * 4) = Ev;
        *(float4*)(Sbuf + o + q * 4) = Sv;
    }
}

__global__ __launch_bounds__(256)
void scan_part2(const float* E, const float* S, float* Hin) {
    int t = blockIdx.x * 256 + threadIdx.x;
    int b = t >> 15;
    int rem = t & 32767;
    size_t base = (size_t)b * NC * (D_INNER * D_STATE) + rem;
    float h = 0.0f;
    for (int c0 = 0; c0 < NC; c0 += 16) {
        float Ec[16], Sc[16];
#pragma unroll
        for (int k = 0; k < 16; ++k) {
            size_t q = base + (size_t)(c0 + k) * (D_INNER * D_STATE);
            Ec[k] = E[q]; Sc[k] = S[q];
        }
#pragma unroll
        for (int k = 0; k < 16; ++k) {
            Hin[base + (size_t)(c0 + k) * (D_INNER * D_STATE)] = h;
            h = fmaf(Ec[k], h, Sc[k]);
        }
    }
}

__global__ __launch_bounds__(256)
void scan_part3(const float* __restrict__ dt, const float* __restrict__ xbc,
                const unsigned short* __restrict__ xs,
                const unsigned short* __restrict__ zb,
                const float* __restrict__ A_log, const float* __restrict__ Dp,
                const float* __restrict__ Hin,
                unsigned short* __restrict__ y, float* __restrict__ ssm_out) {
    __shared__ float Bs[CH][32];
    int d = blockIdx.x * 256 + threadIdx.x;
    int c = blockIdx.y, b = blockIdx.z;
    size_t rowbase = (size_t)b * LL + (size_t)c * CH;
    for (int e = threadIdx.x; e < CH * 32; e += 256) {
        int i = e >> 5, j = e & 31;
        Bs[i][j] = xbc[(rowbase + i) * 32 + j];
    }
    float al2[16];
    {
        const float4* ap = (const float4*)(A_log + (size_t)d * D_STATE);
#pragma unroll
        for (int q = 0; q < 4; ++q) {
            float4 a4 = ap[q];
            al2[q*4+0] = -expf(a4.x) * LOG2E;
            al2[q*4+1] = -expf(a4.y) * LOG2E;
            al2[q*4+2] = -expf(a4.z) * LOG2E;
            al2[q*4+3] = -expf(a4.w) * LOG2E;
        }
    }
    float Dv = Dp[d];
    float h[16];
    {
        const float4* hp = (const float4*)(Hin + (((size_t)b * NC + c) * D_INNER + d) * D_STATE);
#pragma unroll
        for (int q = 0; q < 4; ++q) {
            float4 h4 = hp[q];
            h[q*4+0] = h4.x; h[q*4+1] = h4.y; h[q*4+2] = h4.z; h[q*4+3] = h4.w;
        }
    }
    __syncthreads();
    size_t r0 = rowbase * D_INNER + d;
    float dtv = dt[r0];
    float xv  = bf2f(xs[r0]);
    float zv  = bf2f(zb[r0]);
    for (int i = 0; i < CH; ++i) {
        float dtn = 0.0f, xn2 = 0.0f, zn2 = 0.0f;
        if (i + 1 < CH) {
            size_t r2 = (rowbase + i + 1) * D_INNER + d;
            dtn = dt[r2]; xn2 = bf2f(xs[r2]); zn2 = bf2f(zb[r2]);
        }
        float dtx = dtv * xv;
        float yv = 0.0f;
#pragma unroll
        for (int q = 0; q < 4; ++q) {
            float4 Bv = *(const float4*)&Bs[i][q * 4];
            float4 Cv = *(const float4*)&Bs[i][16 + q * 4];
            h[q*4+0] = fmaf(exp2f(al2[q*4+0] * dtv), h[q*4+0], dtx * Bv.x);
            h[q*4+1] = fmaf(exp2f(al2[q*4+1] * dtv), h[q*4+1], dtx * Bv.y);
            h[q*4+2] = fmaf(exp2f(al2[q*4+2] * dtv), h[q*4+2], dtx * Bv.z);
            h[q*4+3] = fmaf(exp2f(al2[q*4+3] * dtv), h[q*4+3], dtx * Bv.w);
            yv = fmaf(h[q*4+0], Cv.x, yv);
            yv = fmaf(h[q*4+1], Cv.y, yv);
            yv = fmaf(h[q*4+2], Cv.z, yv);
            yv = fmaf(h[q*4+3], Cv.w, yv);
        }
        yv = (yv + xv * Dv) * (zv / (1.0f + expf(-zv)));
        y[(rowbase + i) * D_INNER + d] = f2bf(yv);
        dtv = dtn; xv = xn2; zv = zn2;
    }
    if (c == NC - 1) {
        float* sp = ssm_out + ((size_t)b * D_INNER + d) * D_STATE;
#pragma unroll
        for (int q = 0; q < 4; ++q) {
            float4 h4;
            h4.x = h[q*4+0]; h4.y = h[q*4+1]; h4.z = h[q*4+2]; h4.w = h[q*4+3];
            *(float4*)(sp + q * 4) = h4;
        }
    }
}

// ---------------- launch ----------------
extern "C" void kernel_launch(void* const* d_in, const int* in_sizes, int n_in,
                              void* d_out, int out_size, void* d_ws, size_t ws_size,
                              hipStream_t stream) {
    (void)in_sizes; (void)n_in; (void)out_size; (void)ws_size;
    const float* x      = (const float*)d_in[0];
    const float* ln_w   = (const float*)d_in[1];
    const float* ln_b   = (const float*)d_in[2];
    const float* Win    = (const float*)d_in[3];   // [1024, 4096]
    const float* convw  = (const float*)d_in[4];   // [2048, 4]
    const float* convb  = (const float*)d_in[5];
    const float* Wx     = (const float*)d_in[6];   // [2048, 96]
    const float* Wdt    = (const float*)d_in[7];   // [64, 2048]
    const float* bdt    = (const float*)d_in[8];
    const float* A_log  = (const float*)d_in[9];   // [2048, 16]
    const float* Dp     = (const float*)d_in[10];
    const float* Wout   = (const float*)d_in[11];  // [2048, 1024]
    const float* rscale = (const float*)d_in[12];  // [1]

    float* out      = (float*)d_out;
    float* ssm_out  = out + (size_t)NROWS * D_MODEL;
    float* conv_out = ssm_out + (size_t)BB * D_INNER * D_STATE;

    // ---- workspace layout (~142.4 MB; R1 proved >=152.5 MB available) ----
    float* ws = (float*)d_ws;
    float* xmain = ws;                                            // 33.55 MB
    unsigned short* zb = (unsigned short*)(xmain + (size_t)NROWS * D_INNER); // 16.78 MB
    float* dtb  = (float*)zb + (size_t)NROWS * D_INNER / 2;       // 33.55 MB
    float* xbc  = dtb + (size_t)NROWS * D_INNER;                  // 0.52 MB
    unsigned short* xdtr = (unsigned short*)(xbc + (size_t)NROWS * 32);     // 0.52 MB
    unsigned short* xnb  = xdtr + (size_t)NROWS * DT_RANK;        // 8.39 MB
    unsigned short* wtin = xnb + (size_t)NROWS * D_MODEL;         // 8.39 MB
    float* Ebuf = (float*)(wtin + (size_t)(2 * D_INNER) * D_MODEL); // 16.78 MB
    float* Sbuf = Ebuf + (size_t)BB * NC * D_INNER * D_STATE;       // 16.78 MB
    unsigned short* Wxt  = (unsigned short*)(Sbuf + (size_t)BB * NC * D_INNER * D_STATE); // 0.52 MB
    unsigned short* Wdtt = Wxt + (size_t)128 * D_INNER;           // 0.26 MB
    float* Pxdbl = (float*)(Wdtt + (size_t)D_INNER * DT_RANK);    // 6.29 MB DEDICATED
    // aliases of dead regions:
    // xsb spans xnb+wtin (exactly 16.78 MB) — wtin dead after in_proj.
    unsigned short* xsb   = xnb;
    float* Hin            = Ebuf;                   // pass2 out (aliases E, safe)
    unsigned short* ybuf  = (unsigned short*)xmain; // after conv (lower half)
    unsigned short* wtout = (unsigned short*)(xmain + (size_t)NROWS * D_INNER / 2); // upper half

    // 1. LN -> bf16
    ln_kernel<<<NROWS, 256, 0, stream>>>(x, ln_w, ln_b, xnb);

    // 2. Win -> bf16 Wt [4096,1024]
    transpose_cast<<<dim3(2 * D_INNER / 32, D_MODEL / 32), 256, 0, stream>>>(
        Win, wtin, D_MODEL, 2 * D_INNER);

    // 3. in_proj: cols<2048 -> fp32 xmain, cols>=2048 -> bf16 zb
    mfma_gemm<<<dim3(2 * D_INNER / 128, NROWS / 128), 256, 0, stream>>>(
        xnb, wtin, xmain, D_INNER, D_MODEL, D_MODEL, 0, 3,
        nullptr, nullptr, 0, D_INNER, zb);

    // 4. conv + silu -> bf16 x_s (+ conv_state)  [overwrites xnb+wtin]
    conv_kernel<<<(NROWS * D_INNER) / 256, 256, 0, stream>>>(
        xmain, convw, convb, xsb, conv_out);

    // 5-7. weight transposes (xmain region now free)
    transpose_cast<<<dim3(D_MODEL / 32, D_INNER / 32), 256, 0, stream>>>(
        Wout, wtout, D_INNER, D_MODEL);
    transpose_cast<<<dim3(128 / 32, D_INNER / 32), 256, 0, stream>>>(
        Wx, Wxt, D_INNER, 96);
    transpose_cast<<<dim3(D_INNER / 32, DT_RANK / 32), 256, 0, stream>>>(
        Wdt, Wdtt, DT_RANK, D_INNER);

    // 8. x_dbl split-K x4 -> dedicated partials (MFMA), then reduce
    mfma_gemm<<<dim3(1, NROWS / 128, 4), 256, 0, stream>>>(
        xsb, Wxt, Pxdbl, 96, D_INNER, D_INNER / 4, (size_t)NROWS * 96, 0,
        nullptr, nullptr, 96, 0, nullptr);
    xdbl_reduce<<<(NROWS * 96) / 256, 256, 0, stream>>>(Pxdbl, xdtr, xbc);

    // 9. dt = softplus(xdtr @ Wdt + b)  (MFMA, K=64)
    mfma_gemm<<<dim3(D_INNER / 128, NROWS / 128), 256, 0, stream>>>(
        xdtr, Wdtt, dtb, D_INNER, DT_RANK, DT_RANK, 0, 1,
        bdt, nullptr, D_INNER, 0, nullptr);

    // 10-12. chunked selective scan
    scan_part1<<<dim3(D_INNER / 256, NC, BB), 256, 0, stream>>>(
        dtb, xbc, xsb, A_log, Ebuf, Sbuf);
    scan_part2<<<(BB * D_INNER * D_STATE) / 256, 256, 0, stream>>>(
        Ebuf, Sbuf, Hin);
    scan_part3<<<dim3(D_INNER / 256, NC, BB), 256, 0, stream>>>(
        dtb, xbc, xsb, zb, A_log, Dp, Hin, ybuf, ssm_out);

    // 13. out = res_scale * (y @ Wout) + residual  (MFMA)
    mfma_gemm<<<dim3(D_MODEL / 128, NROWS / 128), 256, 0, stream>>>(
        ybuf, wtout, out, D_MODEL, D_INNER, D_INNER, 0, 2,
        x, rscale, D_MODEL, 0, nullptr);
}

// Round 7
// 409.531 us; speedup vs baseline: 4.0088x; 1.1116x over previous
//
#include <hip/hip_runtime.h>
#include <math.h>

#define D_MODEL 1024
#define D_STATE 16
#define D_CONVK 4
#define D_INNER 2048
#define DT_RANK 64
#define BB 2
#define LL 2048
#define NROWS (BB*LL)   // 4096
#define NC 64           // scan chunks
#define CH (LL/NC)      // 32 steps per chunk
#define XZLD 4096       // fused xz bf16 row stride
#define LOG2E 1.44269504088896340736f

typedef __attribute__((ext_vector_type(8))) short bf16x8;
typedef __attribute__((ext_vector_type(8))) unsigned short u16x8;
typedef __attribute__((ext_vector_type(4))) float f32x4;

typedef __attribute__((address_space(3))) unsigned char lds_ucp;
typedef const __attribute__((address_space(1))) unsigned char glb_ucp;
#define GLD16(gp, lp) __builtin_amdgcn_global_load_lds((glb_ucp*)(gp), (lds_ucp*)(lp), 16, 0, 0)

__device__ inline unsigned short f2bf(float f) {
    union { float f; unsigned u; } c; c.f = f;
    unsigned r = c.u + 0x7fff + ((c.u >> 16) & 1);   // round-to-nearest-even
    return (unsigned short)(r >> 16);
}
__device__ inline float bf2f(unsigned short s) {
    union { unsigned u; float f; } c; c.u = ((unsigned)s) << 16;
    return c.f;
}

// ---------------- LayerNorm -> bf16 ----------------
__global__ __launch_bounds__(256)
void ln_kernel(const float* __restrict__ x, const float* __restrict__ w,
               const float* __restrict__ b, unsigned short* __restrict__ xnb) {
    int row = blockIdx.x;
    const float* xr = x + (size_t)row * D_MODEL;
    float4 v = ((const float4*)xr)[threadIdx.x];
    float s  = v.x + v.y + v.z + v.w;
    float ss = v.x*v.x + v.y*v.y + v.z*v.z + v.w*v.w;
    for (int off = 32; off > 0; off >>= 1) {
        s  += __shfl_down(s, off);
        ss += __shfl_down(ss, off);
    }
    __shared__ float red[8];
    int lane = threadIdx.x & 63, wv = threadIdx.x >> 6;
    if (lane == 0) { red[wv] = s; red[wv + 4] = ss; }
    __syncthreads();
    if (threadIdx.x == 0) {
        float ts  = red[0] + red[1] + red[2] + red[3];
        float tss = red[4] + red[5] + red[6] + red[7];
        float mu  = ts / D_MODEL;
        float var = tss / D_MODEL - mu * mu;
        red[0] = mu; red[1] = rsqrtf(var + 1e-5f);
    }
    __syncthreads();
    float mu = red[0], rs = red[1];
    float4 w4 = ((const float4*)w)[threadIdx.x];
    float4 b4 = ((const float4*)b)[threadIdx.x];
    ushort4 o;
    o.x = f2bf((v.x - mu) * rs * w4.x + b4.x);
    o.y = f2bf((v.y - mu) * rs * w4.y + b4.y);
    o.z = f2bf((v.z - mu) * rs * w4.z + b4.z);
    o.w = f2bf((v.w - mu) * rs * w4.w + b4.w);
    ((ushort4*)(xnb + (size_t)row * D_MODEL))[threadIdx.x] = o;
}

// ------ all 4 weight transposes (fp32 W[K][Nsrc] -> bf16 Wt[Npad][K]) ------
// grid (228, 64): x<128 Win | <160 Wout | <164 Wx | else Wdt
__global__ __launch_bounds__(256)
void transpose_all(const float* __restrict__ Win, const float* __restrict__ Wout,
                   const float* __restrict__ Wx, const float* __restrict__ Wdt,
                   unsigned short* __restrict__ wtin, unsigned short* __restrict__ wtout,
                   unsigned short* __restrict__ Wxt, unsigned short* __restrict__ Wdtt) {
    __shared__ float t[32][33];
    int bx = blockIdx.x, by = blockIdx.y;
    const float* W; unsigned short* Wt; int K, Nsrc, xb;
    if (bx < 128)      { W = Win;  Wt = wtin;  K = 1024; Nsrc = 4096; xb = bx; }
    else if (bx < 160) { W = Wout; Wt = wtout; K = 2048; Nsrc = 1024; xb = bx - 128; }
    else if (bx < 164) { W = Wx;   Wt = Wxt;   K = 2048; Nsrc = 96;   xb = bx - 160; }
    else               { W = Wdt;  Wt = Wdtt;  K = 64;   Nsrc = 2048; xb = bx - 164; }
    int k0 = by * 32, n0 = xb * 32;
    if (k0 >= K) return;
    int tx = threadIdx.x & 31, ty = threadIdx.x >> 5;   // ty 0..7
#pragma unroll
    for (int i = 0; i < 32; i += 8)
        t[ty + i][tx] = (n0 + tx < Nsrc)
            ? W[(size_t)(k0 + ty + i) * Nsrc + n0 + tx] : 0.0f;
    __syncthreads();
#pragma unroll
    for (int i = 0; i < 32; i += 8)
        Wt[(size_t)(n0 + ty + i) * K + k0 + tx] = f2bf(t[tx][ty + i]);
}

// ---------------- bf16 MFMA GEMM: C = A[M,K] @ Wt[N,K]^T -------------------
// 128x128 tile, 4 waves x (4x4 of 16x16x32). R4 layout (no swizzle).
// blockIdx.z = K-slice (kchunk each), C += z*zstride (split-K partials).
// mode 0: fp32 store if col<Ncols | mode 1: softplus(acc+aux[col])
// mode 3: ALL cols -> bf16 out2[row*ldc+col]
__global__ __launch_bounds__(256)
void mfma_gemm(const unsigned short* __restrict__ A,
               const unsigned short* __restrict__ Wt,
               float* __restrict__ C, int ldc, int K, int kchunk,
               size_t zstride, int mode,
               const float* __restrict__ aux,
               int Ncols, unsigned short* __restrict__ out2) {
    __shared__ short As[128 * 32];
    __shared__ short Bs[128 * 32];
    int tid = threadIdx.x;
    int lane = tid & 63, w = tid >> 6;
    int wm = w & 1, wn = w >> 1;
    int row0 = blockIdx.y * 128, col0 = blockIdx.x * 128;
    int kb = blockIdx.z * kchunk, ke = kb + kchunk;
    C += (size_t)blockIdx.z * zstride;
    f32x4 acc[4][4] = {};
    const unsigned short* gA0 = A  + (size_t)row0 * K;
    const unsigned short* gB0 = Wt + (size_t)col0 * K;
    int r_in = lane >> 2;
    int e16  = (lane & 3) * 8;
    int quad = lane >> 4, r16 = lane & 15;
    for (int k0 = kb; k0 < ke; k0 += 32) {
        __syncthreads();
#pragma unroll
        for (int t = 0; t < 2; ++t) {
            int p = w * 2 + t;
            int row = p * 16 + r_in;
            GLD16(gA0 + (size_t)row * K + k0 + e16, (char*)As + p * 1024);
            GLD16(gB0 + (size_t)row * K + k0 + e16, (char*)Bs + p * 1024);
        }
        __syncthreads();
        bf16x8 af[4], bfr[4];
#pragma unroll
        for (int i = 0; i < 4; ++i) {
            af[i]  = *(const bf16x8*)&As[(wm * 64 + i * 16 + r16) * 32 + quad * 8];
            bfr[i] = *(const bf16x8*)&Bs[(wn * 64 + i * 16 + r16) * 32 + quad * 8];
        }
#pragma unroll
        for (int mi = 0; mi < 4; ++mi)
#pragma unroll
            for (int ni = 0; ni < 4; ++ni)
                acc[mi][ni] = __builtin_amdgcn_mfma_f32_16x16x32_bf16(
                    af[mi], bfr[ni], acc[mi][ni], 0, 0, 0);
    }
#pragma unroll
    for (int mi = 0; mi < 4; ++mi)
#pragma unroll
        for (int ni = 0; ni < 4; ++ni)
#pragma unroll
            for (int r = 0; r < 4; ++r) {
                int row = row0 + wm * 64 + mi * 16 + quad * 4 + r;
                int col = col0 + wn * 64 + ni * 16 + r16;
                float v = acc[mi][ni][r];
                if (mode == 3) {
                    out2[(size_t)row * ldc + col] = f2bf(v);
                } else {
                    if (col >= Ncols) continue;
                    if (mode == 1) {
                        v += aux[col];
                        v = (v > 20.0f) ? v : log1pf(expf(v));   // softplus
                    }
                    C[(size_t)row * ldc + col] = v;
                }
            }
}

// ---- reduce 4 split-K partials of x_dbl; emit dt-rank bf16 + B|C fp32 ----
__global__ __launch_bounds__(256)
void xdbl_reduce(const float* __restrict__ P,
                 unsigned short* __restrict__ xdtr, float* __restrict__ xbc) {
    const int S1 = NROWS * 96;
    int t = blockIdx.x * 256 + threadIdx.x;
    float s = P[t] + P[t + S1] + P[t + 2 * S1] + P[t + 3 * S1];
    int row = t / 96, col = t - row * 96;
    if (col < DT_RANK) xdtr[(size_t)row * DT_RANK + col] = f2bf(s);
    else xbc[(size_t)row * 32 + col - DT_RANK] = s;
}

// ---- out = rs*(P0+P1) + residual ----
__global__ __launch_bounds__(256)
void out_final(const float* __restrict__ P0, const float* __restrict__ P1,
               const float* __restrict__ x, const float* __restrict__ rscale,
               float* __restrict__ out) {
    int t = blockIdx.x * 256 + threadIdx.x;
    float rs = rscale[0];
    float4 a = ((const float4*)P0)[t];
    float4 b = ((const float4*)P1)[t];
    float4 r = ((const float4*)x)[t];
    float4 o;
    o.x = rs * (a.x + b.x) + r.x;
    o.y = rs * (a.y + b.y) + r.y;
    o.z = rs * (a.z + b.z) + r.z;
    o.w = rs * (a.w + b.w) + r.w;
    ((float4*)out)[t] = o;
}

// ---- Causal depthwise conv (K=4) + bias + silu, bf16 in/out, vectorized ----
// thread = 8 d-channels x 8 l-steps. grid = BB * LL/8, block 256 (d8 = tid).
__global__ __launch_bounds__(256)
void conv_kernel(const unsigned short* __restrict__ xzb, const float* __restrict__ cw,
                 const float* __restrict__ cb, unsigned short* __restrict__ xs,
                 float* __restrict__ conv_state_out) {
    int loct = blockIdx.x & 255;         // l-octet 0..255
    int b    = blockIdx.x >> 8;
    int d0   = threadIdx.x * 8;
    float wgt[8][4];
#pragma unroll
    for (int j = 0; j < 8; ++j) {
        float4 w4 = *(const float4*)(cw + (size_t)(d0 + j) * 4);
        wgt[j][0] = w4.x; wgt[j][1] = w4.y; wgt[j][2] = w4.z; wgt[j][3] = w4.w;
    }
    float bias[8];
    *(float4*)&bias[0] = *(const float4*)(cb + d0);
    *(float4*)&bias[4] = *(const float4*)(cb + d0 + 4);
    float xr[11][8];
#pragma unroll
    for (int r = 0; r < 11; ++r) {
        int l = loct * 8 - 3 + r;
        if (l >= 0) {
            u16x8 v = *(const u16x8*)&xzb[((size_t)b * LL + l) * XZLD + d0];
#pragma unroll
            for (int j = 0; j < 8; ++j) xr[r][j] = bf2f(v[j]);
        } else {
#pragma unroll
            for (int j = 0; j < 8; ++j) xr[r][j] = 0.0f;
        }
    }
#pragma unroll
    for (int i = 0; i < 8; ++i) {
        unsigned short o[8];
#pragma unroll
        for (int j = 0; j < 8; ++j) {
            float a = bias[j];
#pragma unroll
            for (int k = 0; k < 4; ++k) a = fmaf(xr[i + k][j], wgt[j][k], a);
            a = a / (1.0f + expf(-a));   // silu
            o[j] = f2bf(a);
        }
        *(u16x8*)&xs[((size_t)b * LL + loct * 8 + i) * D_INNER + d0] = *(u16x8*)o;
    }
    if (loct == 255) {   // conv_state = pre-conv x_main at l in {2045,2046,2047}
#pragma unroll
        for (int i = 8; i < 11; ++i)       // row r=i corresponds to l = 2037+i
#pragma unroll
            for (int j = 0; j < 8; ++j)
                conv_state_out[((size_t)b * D_INNER + d0 + j) * 3 + (i - 8)] = xr[i][j];
    }
}

// ---------------- Selective scan: thread-per-d, 16 n-states in regs --------
__global__ __launch_bounds__(256)
void scan_part1(const float* __restrict__ dt, const float* __restrict__ xbc,
                const unsigned short* __restrict__ xs,
                const float* __restrict__ A_log,
                float* __restrict__ Ebuf, float* __restrict__ Sbuf) {
    __shared__ float Bs[CH][32];
    int d = blockIdx.x * 256 + threadIdx.x;
    int c = blockIdx.y, b = blockIdx.z;
    size_t rowbase = (size_t)b * LL + (size_t)c * CH;
    for (int e = threadIdx.x; e < CH * 32; e += 256) {
        int i = e >> 5, j = e & 31;
        Bs[i][j] = xbc[(rowbase + i) * 32 + j];
    }
    float al2[16];
    {
        const float4* ap = (const float4*)(A_log + (size_t)d * D_STATE);
#pragma unroll
        for (int q = 0; q < 4; ++q) {
            float4 a4 = ap[q];
            al2[q*4+0] = -expf(a4.x) * LOG2E;
            al2[q*4+1] = -expf(a4.y) * LOG2E;
            al2[q*4+2] = -expf(a4.z) * LOG2E;
            al2[q*4+3] = -expf(a4.w) * LOG2E;
        }
    }
    __syncthreads();
    float S[16];
#pragma unroll
    for (int n = 0; n < 16; ++n) S[n] = 0.0f;
    float Tsum = 0.0f;
    float dtv = dt[rowbase * D_INNER + d];
    float xv  = bf2f(xs[rowbase * D_INNER + d]);
    for (int i = 0; i < CH; ++i) {
        float dtn = 0.0f, xn2 = 0.0f;
        if (i + 1 < CH) {
            size_t r2 = (rowbase + i + 1) * D_INNER + d;
            dtn = dt[r2]; xn2 = bf2f(xs[r2]);
        }
        Tsum += dtv;
        float dtx = dtv * xv;
#pragma unroll
        for (int q = 0; q < 4; ++q) {
            float4 Bv = *(const float4*)&Bs[i][q * 4];
            S[q*4+0] = fmaf(exp2f(al2[q*4+0] * dtv), S[q*4+0], dtx * Bv.x);
            S[q*4+1] = fmaf(exp2f(al2[q*4+1] * dtv), S[q*4+1], dtx * Bv.y);
            S[q*4+2] = fmaf(exp2f(al2[q*4+2] * dtv), S[q*4+2], dtx * Bv.z);
            S[q*4+3] = fmaf(exp2f(al2[q*4+3] * dtv), S[q*4+3], dtx * Bv.w);
        }
        dtv = dtn; xv = xn2;
    }
    size_t o = (((size_t)b * NC + c) * D_INNER + d) * D_STATE;
#pragma unroll
    for (int q = 0; q < 4; ++q) {
        float4 Ev, Sv;
        Ev.x = exp2f(al2[q*4+0] * Tsum); Ev.y = exp2f(al2[q*4+1] * Tsum);
        Ev.z = exp2f(al2[q*4+2] * Tsum); Ev.w = exp2f(al2[q*4+3] * Tsum);
        Sv.x = S[q*4+0]; Sv.y = S[q*4+1]; Sv.z = S[q*4+2]; Sv.w = S[q*4+3];
        *(float4*)(Ebuf + o + q * 4) = Ev;
        *(float4*)(Sbuf + o + q * 4) = Sv;
    }
}

__global__ __launch_bounds__(256)
void scan_part2(const float* E, const float* S, float* Hin) {
    int t = blockIdx.x * 256 + threadIdx.x;
    int b = t >> 15;
    int rem = t & 32767;
    size_t base = (size_t)b * NC * (D_INNER * D_STATE) + rem;
    float h = 0.0f;
    for (int c0 = 0; c0 < NC; c0 += 16) {
        float Ec[16], Sc[16];
#pragma unroll
        for (int k = 0; k < 16; ++k) {
            size_t q = base + (size_t)(c0 + k) * (D_INNER * D_STATE);
            Ec[k] = E[q]; Sc[k] = S[q];
        }
#pragma unroll
        for (int k = 0; k < 16; ++k) {
            Hin[base + (size_t)(c0 + k) * (D_INNER * D_STATE)] = h;
            h = fmaf(Ec[k], h, Sc[k]);
        }
    }
}

__global__ __launch_bounds__(256)
void scan_part3(const float* __restrict__ dt, const float* __restrict__ xbc,
                const unsigned short* __restrict__ xs,
                const unsigned short* __restrict__ xzb,  // z at col 2048+, stride XZLD
                const float* __restrict__ A_log, const float* __restrict__ Dp,
                const float* __restrict__ Hin,
                unsigned short* __restrict__ y, float* __restrict__ ssm_out) {
    __shared__ float Bs[CH][32];
    int d = blockIdx.x * 256 + threadIdx.x;
    int c = blockIdx.y, b = blockIdx.z;
    size_t rowbase = (size_t)b * LL + (size_t)c * CH;
    for (int e = threadIdx.x; e < CH * 32; e += 256) {
        int i = e >> 5, j = e & 31;
        Bs[i][j] = xbc[(rowbase + i) * 32 + j];
    }
    float al2[16];
    {
        const float4* ap = (const float4*)(A_log + (size_t)d * D_STATE);
#pragma unroll
        for (int q = 0; q < 4; ++q) {
            float4 a4 = ap[q];
            al2[q*4+0] = -expf(a4.x) * LOG2E;
            al2[q*4+1] = -expf(a4.y) * LOG2E;
            al2[q*4+2] = -expf(a4.z) * LOG2E;
            al2[q*4+3] = -expf(a4.w) * LOG2E;
        }
    }
    float Dv = Dp[d];
    float h[16];
    {
        const float4* hp = (const float4*)(Hin + (((size_t)b * NC + c) * D_INNER + d) * D_STATE);
#pragma unroll
        for (int q = 0; q < 4; ++q) {
            float4 h4 = hp[q];
            h[q*4+0] = h4.x; h[q*4+1] = h4.y; h[q*4+2] = h4.z; h[q*4+3] = h4.w;
        }
    }
    __syncthreads();
    size_t r0 = rowbase * D_INNER + d;
    float dtv = dt[r0];
    float xv  = bf2f(xs[r0]);
    float zv  = bf2f(xzb[rowbase * XZLD + D_INNER + d]);
    for (int i = 0; i < CH; ++i) {
        float dtn = 0.0f, xn2 = 0.0f, zn2 = 0.0f;
        if (i + 1 < CH) {
            size_t r2 = (rowbase + i + 1) * D_INNER + d;
            dtn = dt[r2]; xn2 = bf2f(xs[r2]);
            zn2 = bf2f(xzb[(rowbase + i + 1) * XZLD + D_INNER + d]);
        }
        float dtx = dtv * xv;
        float yv = 0.0f;
#pragma unroll
        for (int q = 0; q < 4; ++q) {
            float4 Bv = *(const float4*)&Bs[i][q * 4];
            float4 Cv = *(const float4*)&Bs[i][16 + q * 4];
            h[q*4+0] = fmaf(exp2f(al2[q*4+0] * dtv), h[q*4+0], dtx * Bv.x);
            h[q*4+1] = fmaf(exp2f(al2[q*4+1] * dtv), h[q*4+1], dtx * Bv.y);
            h[q*4+2] = fmaf(exp2f(al2[q*4+2] * dtv), h[q*4+2], dtx * Bv.z);
            h[q*4+3] = fmaf(exp2f(al2[q*4+3] * dtv), h[q*4+3], dtx * Bv.w);
            yv = fmaf(h[q*4+0], Cv.x, yv);
            yv = fmaf(h[q*4+1], Cv.y, yv);
            yv = fmaf(h[q*4+2], Cv.z, yv);
            yv = fmaf(h[q*4+3], Cv.w, yv);
        }
        yv = (yv + xv * Dv) * (zv / (1.0f + expf(-zv)));
        y[(rowbase + i) * D_INNER + d] = f2bf(yv);
        dtv = dtn; xv = xn2; zv = zn2;
    }
    if (c == NC - 1) {
        float* sp = ssm_out + ((size_t)b * D_INNER + d) * D_STATE;
#pragma unroll
        for (int q = 0; q < 4; ++q) {
            float4 h4;
            h4.x = h[q*4+0]; h4.y = h[q*4+1]; h4.z = h[q*4+2]; h4.w = h[q*4+3];
            *(float4*)(sp + q * 4) = h4;
        }
    }
}

// ---------------- launch ----------------
extern "C" void kernel_launch(void* const* d_in, const int* in_sizes, int n_in,
                              void* d_out, int out_size, void* d_ws, size_t ws_size,
                              hipStream_t stream) {
    (void)in_sizes; (void)n_in; (void)out_size; (void)ws_size;
    const float* x      = (const float*)d_in[0];
    const float* ln_w   = (const float*)d_in[1];
    const float* ln_b   = (const float*)d_in[2];
    const float* Win    = (const float*)d_in[3];   // [1024, 4096]
    const float* convw  = (const float*)d_in[4];   // [2048, 4]
    const float* convb  = (const float*)d_in[5];
    const float* Wx     = (const float*)d_in[6];   // [2048, 96]
    const float* Wdt    = (const float*)d_in[7];   // [64, 2048]
    const float* bdt    = (const float*)d_in[8];
    const float* A_log  = (const float*)d_in[9];   // [2048, 16]
    const float* Dp     = (const float*)d_in[10];
    const float* Wout   = (const float*)d_in[11];  // [2048, 1024]
    const float* rscale = (const float*)d_in[12];  // [1]

    float* out      = (float*)d_out;
    float* ssm_out  = out + (size_t)NROWS * D_MODEL;
    float* conv_out = ssm_out + (size_t)BB * D_INNER * D_STATE;

    // ---- workspace layout (~146.5 MB; 152.6 MB proven available in R1) ----
    float* ws = (float*)d_ws;
    unsigned short* xzb = (unsigned short*)ws;                     // 33.55 MB bf16 [4096x4096]
    unsigned short* xsb = xzb + (size_t)NROWS * XZLD;              // 16.78 MB bf16 [4096x2048]
    float* dtb  = (float*)(xsb + (size_t)NROWS * D_INNER);         // 33.55 MB
    float* xbc  = dtb + (size_t)NROWS * D_INNER;                   // 0.52 MB
    unsigned short* xdtr = (unsigned short*)(xbc + (size_t)NROWS * 32);  // 0.52 MB
    unsigned short* xnb  = xdtr + (size_t)NROWS * DT_RANK;         // 8.39 MB
    unsigned short* wtin = xnb + (size_t)NROWS * D_MODEL;          // 8.39 MB
    unsigned short* wtout = wtin + (size_t)(2 * D_INNER) * D_MODEL; // 4.19 MB
    unsigned short* Wxt  = wtout + (size_t)D_MODEL * D_INNER;      // 0.52 MB
    unsigned short* Wdtt = Wxt + (size_t)128 * D_INNER;            // 0.26 MB
    float* Ebuf = (float*)(Wdtt + (size_t)D_INNER * DT_RANK);      // 16.78 MB (later P0)
    float* Sbuf = Ebuf + (size_t)BB * NC * D_INNER * D_STATE;      // 16.78 MB (later P1)
    float* Pxdbl = Sbuf + (size_t)BB * NC * D_INNER * D_STATE;     // 6.29 MB
    float* Hin   = Ebuf;   // scan2 output aliases E (safe: per-batch load-then-store)
    float* P0 = Ebuf, *P1 = Sbuf;  // out_proj partials (dead after scan3)

    // 1. all weight transposes (one launch)
    transpose_all<<<dim3(228, 64), 256, 0, stream>>>(
        Win, Wout, Wx, Wdt, wtin, wtout, Wxt, Wdtt);

    // 2. LN -> bf16
    ln_kernel<<<NROWS, 256, 0, stream>>>(x, ln_w, ln_b, xnb);

    // 3. in_proj: all 4096 cols -> bf16 fused xz buffer
    mfma_gemm<<<dim3(2 * D_INNER / 128, NROWS / 128), 256, 0, stream>>>(
        xnb, wtin, nullptr, XZLD, D_MODEL, D_MODEL, 0, 3,
        nullptr, 0, xzb);

    // 4. conv + silu -> bf16 x_s (+ conv_state)
    conv_kernel<<<BB * (LL / 8), 256, 0, stream>>>(
        xzb, convw, convb, xsb, conv_out);

    // 5. x_dbl split-K x4 -> partials (MFMA), then reduce
    mfma_gemm<<<dim3(1, NROWS / 128, 4), 256, 0, stream>>>(
        xsb, Wxt, Pxdbl, 96, D_INNER, D_INNER / 4, (size_t)NROWS * 96, 0,
        nullptr, 96, nullptr);
    xdbl_reduce<<<(NROWS * 96) / 256, 256, 0, stream>>>(Pxdbl, xdtr, xbc);

    // 6. dt = softplus(xdtr @ Wdt + b)  (MFMA, K=64)
    mfma_gemm<<<dim3(D_INNER / 128, NROWS / 128), 256, 0, stream>>>(
        xdtr, Wdtt, dtb, D_INNER, DT_RANK, DT_RANK, 0, 1,
        bdt, D_INNER, nullptr);

    // 7-9. chunked selective scan (y -> bf16 into xnb region, dead after in_proj)
    unsigned short* ybuf = xnb;
    // y is [4096 x 2048] bf16 = 16.78 MB: xnb(8.39)+wtin(8.39) both dead now
    scan_part1<<<dim3(D_INNER / 256, NC, BB), 256, 0, stream>>>(
        dtb, xbc, xsb, A_log, Ebuf, Sbuf);
    scan_part2<<<(BB * D_INNER * D_STATE) / 256, 256, 0, stream>>>(
        Ebuf, Sbuf, Hin);
    scan_part3<<<dim3(D_INNER / 256, NC, BB), 256, 0, stream>>>(
        dtb, xbc, xsb, xzb, A_log, Dp, Hin, ybuf, ssm_out);

    // 10. out_proj split-K x2 -> partials P0/P1 (Ebuf/Sbuf dead after scan3)
    mfma_gemm<<<dim3(D_MODEL / 128, NROWS / 128, 2), 256, 0, stream>>>(
        ybuf, wtout, P0, D_MODEL, D_INNER, D_INNER / 2,
        (size_t)BB * NC * D_INNER * D_STATE, 0,
        nullptr, D_MODEL, nullptr);

    // 11. out = rs*(P0+P1) + residual
    out_final<<<(NROWS * D_MODEL) / (256 * 4), 256, 0, stream>>>(
        P0, P1, x, rscale, out);
}

// Round 8
// 392.133 us; speedup vs baseline: 4.1867x; 1.0444x over previous
//
#include <hip/hip_runtime.h>
#include <math.h>

#define D_MODEL 1024
#define D_STATE 16
#define D_CONVK 4
#define D_INNER 2048
#define DT_RANK 64
#define BB 2
#define LL 2048
#define NROWS (BB*LL)   // 4096
#define NC 64           // scan chunks
#define CH (LL/NC)      // 32 steps per chunk
#define XZLD 4096       // fused xz bf16 row stride
#define LOG2E 1.44269504088896340736f

typedef __attribute__((ext_vector_type(8))) short bf16x8;
typedef __attribute__((ext_vector_type(8))) unsigned short u16x8;
typedef __attribute__((ext_vector_type(4))) float f32x4;

typedef __attribute__((address_space(3))) unsigned char lds_ucp;
typedef const __attribute__((address_space(1))) unsigned char glb_ucp;
#define GLD16(gp, lp) __builtin_amdgcn_global_load_lds((glb_ucp*)(gp), (lds_ucp*)(lp), 16, 0, 0)

__device__ inline unsigned short f2bf(float f) {
    union { float f; unsigned u; } c; c.f = f;
    unsigned r = c.u + 0x7fff + ((c.u >> 16) & 1);   // round-to-nearest-even
    return (unsigned short)(r >> 16);
}
__device__ inline float bf2f(unsigned short s) {
    union { unsigned u; float f; } c; c.u = ((unsigned)s) << 16;
    return c.f;
}

// ---- merged prologue: LN (bx<4096) + all 4 weight transposes (bx>=4096) ----
__global__ __launch_bounds__(256)
void prologue_kernel(const float* __restrict__ x, const float* __restrict__ lw,
                     const float* __restrict__ lb, unsigned short* __restrict__ xnb,
                     const float* __restrict__ Win, const float* __restrict__ Wout,
                     const float* __restrict__ Wx, const float* __restrict__ Wdt,
                     unsigned short* __restrict__ wtin, unsigned short* __restrict__ wtout,
                     unsigned short* __restrict__ Wxt, unsigned short* __restrict__ Wdtt) {
    if (blockIdx.x < NROWS) {
        int row = blockIdx.x;
        const float* xr = x + (size_t)row * D_MODEL;
        float4 v = ((const float4*)xr)[threadIdx.x];
        float s  = v.x + v.y + v.z + v.w;
        float ss = v.x*v.x + v.y*v.y + v.z*v.z + v.w*v.w;
        for (int off = 32; off > 0; off >>= 1) {
            s  += __shfl_down(s, off);
            ss += __shfl_down(ss, off);
        }
        __shared__ float red[8];
        int lane = threadIdx.x & 63, wv = threadIdx.x >> 6;
        if (lane == 0) { red[wv] = s; red[wv + 4] = ss; }
        __syncthreads();
        if (threadIdx.x == 0) {
            float ts  = red[0] + red[1] + red[2] + red[3];
            float tss = red[4] + red[5] + red[6] + red[7];
            float mu  = ts / D_MODEL;
            float var = tss / D_MODEL - mu * mu;
            red[0] = mu; red[1] = rsqrtf(var + 1e-5f);
        }
        __syncthreads();
        float mu = red[0], rs = red[1];
        float4 w4 = ((const float4*)lw)[threadIdx.x];
        float4 b4 = ((const float4*)lb)[threadIdx.x];
        ushort4 o;
        o.x = f2bf((v.x - mu) * rs * w4.x + b4.x);
        o.y = f2bf((v.y - mu) * rs * w4.y + b4.y);
        o.z = f2bf((v.z - mu) * rs * w4.z + b4.z);
        o.w = f2bf((v.w - mu) * rs * w4.w + b4.w);
        ((ushort4*)(xnb + (size_t)row * D_MODEL))[threadIdx.x] = o;
        return;
    }
    // transpose part: tb in [0, 228*64)
    int tb = blockIdx.x - NROWS;
    int bx = tb % 228, by = tb / 228;
    __shared__ float t[32][33];
    const float* W; unsigned short* Wt; int K, Nsrc, xb;
    if (bx < 128)      { W = Win;  Wt = wtin;  K = 1024; Nsrc = 4096; xb = bx; }
    else if (bx < 160) { W = Wout; Wt = wtout; K = 2048; Nsrc = 1024; xb = bx - 128; }
    else if (bx < 164) { W = Wx;   Wt = Wxt;   K = 2048; Nsrc = 96;   xb = bx - 160; }
    else               { W = Wdt;  Wt = Wdtt;  K = 64;   Nsrc = 2048; xb = bx - 164; }
    int k0 = by * 32, n0 = xb * 32;
    if (k0 >= K) return;
    int tx = threadIdx.x & 31, ty = threadIdx.x >> 5;   // ty 0..7
#pragma unroll
    for (int i = 0; i < 32; i += 8)
        t[ty + i][tx] = (n0 + tx < Nsrc)
            ? W[(size_t)(k0 + ty + i) * Nsrc + n0 + tx] : 0.0f;
    __syncthreads();
#pragma unroll
    for (int i = 0; i < 32; i += 8)
        Wt[(size_t)(n0 + ty + i) * K + k0 + tx] = f2bf(t[tx][ty + i]);
}

// ---------------- bf16 MFMA GEMM: C = A[M,K] @ Wt[N,K]^T -------------------
// 128x128 tile, 4 waves x (4x4 of 16x16x32), BK=64 (32 MFMA per barrier).
// blockIdx.z = K-slice (kchunk each, multiple of 64), C += z*zstride.
// mode 0: fp32 (pair-packed dwordx2) if col<Ncols
// mode 1: softplus(acc+aux[col]) -> fp32 pair-packed
// mode 3: bf16 pair-packed dword -> out2
__global__ __launch_bounds__(256)
void mfma_gemm(const unsigned short* __restrict__ A,
               const unsigned short* __restrict__ Wt,
               float* __restrict__ C, int ldc, int K, int kchunk,
               size_t zstride, int mode,
               const float* __restrict__ aux,
               int Ncols, unsigned short* __restrict__ out2) {
    __shared__ short As[128 * 64];
    __shared__ short Bs[128 * 64];
    int tid = threadIdx.x;
    int lane = tid & 63, w = tid >> 6;
    int wm = w & 1, wn = w >> 1;
    int row0 = blockIdx.y * 128, col0 = blockIdx.x * 128;
    int kb = blockIdx.z * kchunk, ke = kb + kchunk;
    C += (size_t)blockIdx.z * zstride;
    f32x4 acc[4][4] = {};
    const unsigned short* gA0 = A  + (size_t)row0 * K;
    const unsigned short* gB0 = Wt + (size_t)col0 * K;
    int r_in = lane >> 3;          // 0..7 row within 8-row issue group
    int e16  = (lane & 7) * 8;     // element offset (8 bf16 = 16 B)
    int quad = lane >> 4, r16 = lane & 15;
    for (int k0 = kb; k0 < ke; k0 += 64) {
        __syncthreads();
#pragma unroll
        for (int t = 0; t < 4; ++t) {
            int p = w * 4 + t;               // 0..15, issue covers rows p*8..p*8+7
            int row = p * 8 + r_in;
            GLD16(gA0 + (size_t)row * K + k0 + e16, (char*)As + p * 1024);
            GLD16(gB0 + (size_t)row * K + k0 + e16, (char*)Bs + p * 1024);
        }
        __syncthreads();
#pragma unroll
        for (int ks = 0; ks < 2; ++ks) {
            bf16x8 af[4], bfr[4];
#pragma unroll
            for (int i = 0; i < 4; ++i) {
                af[i]  = *(const bf16x8*)&As[(wm * 64 + i * 16 + r16) * 64 + ks * 32 + quad * 8];
                bfr[i] = *(const bf16x8*)&Bs[(wn * 64 + i * 16 + r16) * 64 + ks * 32 + quad * 8];
            }
#pragma unroll
            for (int mi = 0; mi < 4; ++mi)
#pragma unroll
                for (int ni = 0; ni < 4; ++ni)
                    acc[mi][ni] = __builtin_amdgcn_mfma_f32_16x16x32_bf16(
                        af[mi], bfr[ni], acc[mi][ni], 0, 0, 0);
        }
    }
    // ---- divergence-free pair-packed epilogue ----
    int odd = lane & 1;
#pragma unroll
    for (int mi = 0; mi < 4; ++mi)
#pragma unroll
        for (int ni = 0; ni < 4; ++ni) {
            int colE = col0 + wn * 64 + ni * 16 + r16;     // own col
            float v[4];
#pragma unroll
            for (int r = 0; r < 4; ++r) v[r] = acc[mi][ni][r];
            if (mode == 1) {
                float bv = aux[colE];
#pragma unroll
                for (int r = 0; r < 4; ++r) {
                    float tv = v[r] + bv;
                    v[r] = (tv > 20.0f) ? tv : log1pf(expf(tv));
                }
            }
#pragma unroll
            for (int rp = 0; rp < 2; ++rp) {
                int rowE = row0 + wm * 64 + mi * 16 + quad * 4 + rp * 2;
                int row  = rowE + odd;
                int colp = colE - odd;
                if (mode == 3) {
                    unsigned hh = (unsigned)f2bf(v[rp*2]) | ((unsigned)f2bf(v[rp*2+1]) << 16);
                    unsigned ph = __shfl_xor((int)hh, 1);
                    unsigned u_even = (hh & 0xffffu) | (ph << 16);
                    unsigned u_odd  = (ph >> 16) | (hh & 0xffff0000u);
                    unsigned u = odd ? u_odd : u_even;
                    *(unsigned*)&out2[(size_t)row * ldc + colp] = u;
                } else {
                    float a0 = v[rp*2], a1 = v[rp*2+1];
                    float b0 = __shfl_xor(a0, 1), b1 = __shfl_xor(a1, 1);
                    float2 f2;
                    f2.x = odd ? b1 : a0;
                    f2.y = odd ? a1 : b0;
                    if (colp < Ncols)
                        *(float2*)&C[(size_t)row * ldc + colp] = f2;
                }
            }
        }
}

// ---- reduce 4 split-K partials of x_dbl; emit dt-rank bf16 + B|C fp32 ----
__global__ __launch_bounds__(256)
void xdbl_reduce(const float* __restrict__ P,
                 unsigned short* __restrict__ xdtr, float* __restrict__ xbc) {
    const int S1 = NROWS * 96;
    int t = blockIdx.x * 256 + threadIdx.x;
    float s = P[t] + P[t + S1] + P[t + 2 * S1] + P[t + 3 * S1];
    int row = t / 96, col = t - row * 96;
    if (col < DT_RANK) xdtr[(size_t)row * DT_RANK + col] = f2bf(s);
    else xbc[(size_t)row * 32 + col - DT_RANK] = s;
}

// ---- out = rs*(P0+P1) + residual ----
__global__ __launch_bounds__(256)
void out_final(const float* __restrict__ P0, const float* __restrict__ P1,
               const float* __restrict__ x, const float* __restrict__ rscale,
               float* __restrict__ out) {
    int t = blockIdx.x * 256 + threadIdx.x;
    float rs = rscale[0];
    float4 a = ((const float4*)P0)[t];
    float4 b = ((const float4*)P1)[t];
    float4 r = ((const float4*)x)[t];
    float4 o;
    o.x = rs * (a.x + b.x) + r.x;
    o.y = rs * (a.y + b.y) + r.y;
    o.z = rs * (a.z + b.z) + r.z;
    o.w = rs * (a.w + b.w) + r.w;
    ((float4*)out)[t] = o;
}

// ---- Causal depthwise conv (K=4) + bias + silu, bf16 in/out, vectorized ----
__global__ __launch_bounds__(256)
void conv_kernel(const unsigned short* __restrict__ xzb, const float* __restrict__ cw,
                 const float* __restrict__ cb, unsigned short* __restrict__ xs,
                 float* __restrict__ conv_state_out) {
    int loct = blockIdx.x & 255;         // l-octet 0..255
    int b    = blockIdx.x >> 8;
    int d0   = threadIdx.x * 8;
    float wgt[8][4];
#pragma unroll
    for (int j = 0; j < 8; ++j) {
        float4 w4 = *(const float4*)(cw + (size_t)(d0 + j) * 4);
        wgt[j][0] = w4.x; wgt[j][1] = w4.y; wgt[j][2] = w4.z; wgt[j][3] = w4.w;
    }
    float bias[8];
    *(float4*)&bias[0] = *(const float4*)(cb + d0);
    *(float4*)&bias[4] = *(const float4*)(cb + d0 + 4);
    float xr[11][8];
#pragma unroll
    for (int r = 0; r < 11; ++r) {
        int l = loct * 8 - 3 + r;
        if (l >= 0) {
            u16x8 v = *(const u16x8*)&xzb[((size_t)b * LL + l) * XZLD + d0];
#pragma unroll
            for (int j = 0; j < 8; ++j) xr[r][j] = bf2f(v[j]);
        } else {
#pragma unroll
            for (int j = 0; j < 8; ++j) xr[r][j] = 0.0f;
        }
    }
#pragma unroll
    for (int i = 0; i < 8; ++i) {
        unsigned short o[8];
#pragma unroll
        for (int j = 0; j < 8; ++j) {
            float a = bias[j];
#pragma unroll
            for (int k = 0; k < 4; ++k) a = fmaf(xr[i + k][j], wgt[j][k], a);
            a = a / (1.0f + expf(-a));   // silu
            o[j] = f2bf(a);
        }
        *(u16x8*)&xs[((size_t)b * LL + loct * 8 + i) * D_INNER + d0] = *(u16x8*)o;
    }
    if (loct == 255) {   // conv_state = pre-conv x_main at l in {2045,2046,2047}
#pragma unroll
        for (int i = 8; i < 11; ++i)
#pragma unroll
            for (int j = 0; j < 8; ++j)
                conv_state_out[((size_t)b * D_INNER + d0 + j) * 3 + (i - 8)] = xr[i][j];
    }
}

// ---------------- Selective scan: thread-per-d, 16 n-states in regs --------
__global__ __launch_bounds__(256)
void scan_part1(const float* __restrict__ dt, const float* __restrict__ xbc,
                const unsigned short* __restrict__ xs,
                const float* __restrict__ A_log,
                float* __restrict__ Ebuf, float* __restrict__ Sbuf) {
    __shared__ float Bs[CH][32];
    int d = blockIdx.x * 256 + threadIdx.x;
    int c = blockIdx.y, b = blockIdx.z;
    size_t rowbase = (size_t)b * LL + (size_t)c * CH;
    for (int e = threadIdx.x; e < CH * 32; e += 256) {
        int i = e >> 5, j = e & 31;
        Bs[i][j] = xbc[(rowbase + i) * 32 + j];
    }
    float al2[16];
    {
        const float4* ap = (const float4*)(A_log + (size_t)d * D_STATE);
#pragma unroll
        for (int q = 0; q < 4; ++q) {
            float4 a4 = ap[q];
            al2[q*4+0] = -expf(a4.x) * LOG2E;
            al2[q*4+1] = -expf(a4.y) * LOG2E;
            al2[q*4+2] = -expf(a4.z) * LOG2E;
            al2[q*4+3] = -expf(a4.w) * LOG2E;
        }
    }
    __syncthreads();
    float S[16];
#pragma unroll
    for (int n = 0; n < 16; ++n) S[n] = 0.0f;
    float Tsum = 0.0f;
    float dtv = dt[rowbase * D_INNER + d];
    float xv  = bf2f(xs[rowbase * D_INNER + d]);
    for (int i = 0; i < CH; ++i) {
        float dtn = 0.0f, xn2 = 0.0f;
        if (i + 1 < CH) {
            size_t r2 = (rowbase + i + 1) * D_INNER + d;
            dtn = dt[r2]; xn2 = bf2f(xs[r2]);
        }
        Tsum += dtv;
        float dtx = dtv * xv;
#pragma unroll
        for (int q = 0; q < 4; ++q) {
            float4 Bv = *(const float4*)&Bs[i][q * 4];
            S[q*4+0] = fmaf(exp2f(al2[q*4+0] * dtv), S[q*4+0], dtx * Bv.x);
            S[q*4+1] = fmaf(exp2f(al2[q*4+1] * dtv), S[q*4+1], dtx * Bv.y);
            S[q*4+2] = fmaf(exp2f(al2[q*4+2] * dtv), S[q*4+2], dtx * Bv.z);
            S[q*4+3] = fmaf(exp2f(al2[q*4+3] * dtv), S[q*4+3], dtx * Bv.w);
        }
        dtv = dtn; xv = xn2;
    }
    size_t o = (((size_t)b * NC + c) * D_INNER + d) * D_STATE;
#pragma unroll
    for (int q = 0; q < 4; ++q) {
        float4 Ev, Sv;
        Ev.x = exp2f(al2[q*4+0] * Tsum); Ev.y = exp2f(al2[q*4+1] * Tsum);
        Ev.z = exp2f(al2[q*4+2] * Tsum); Ev.w = exp2f(al2[q*4+3] * Tsum);
        Sv.x = S[q*4+0]; Sv.y = S[q*4+1]; Sv.z = S[q*4+2]; Sv.w = S[q*4+3];
        *(float4*)(Ebuf + o + q * 4) = Ev;
        *(float4*)(Sbuf + o + q * 4) = Sv;
    }
}

__global__ __launch_bounds__(256)
void scan_part2(const float* E, const float* S, float* Hin) {
    int t = blockIdx.x * 256 + threadIdx.x;
    int b = t >> 15;
    int rem = t & 32767;
    size_t base = (size_t)b * NC * (D_INNER * D_STATE) + rem;
    float h = 0.0f;
    for (int c0 = 0; c0 < NC; c0 += 16) {
        float Ec[16], Sc[16];
#pragma unroll
        for (int k = 0; k < 16; ++k) {
            size_t q = base + (size_t)(c0 + k) * (D_INNER * D_STATE);
            Ec[k] = E[q]; Sc[k] = S[q];
        }
#pragma unroll
        for (int k = 0; k < 16; ++k) {
            Hin[base + (size_t)(c0 + k) * (D_INNER * D_STATE)] = h;
            h = fmaf(Ec[k], h, Sc[k]);
        }
    }
}

__global__ __launch_bounds__(256)
void scan_part3(const float* __restrict__ dt, const float* __restrict__ xbc,
                const unsigned short* __restrict__ xs,
                const unsigned short* __restrict__ xzb,  // z at col 2048+, stride XZLD
                const float* __restrict__ A_log, const float* __restrict__ Dp,
                const float* __restrict__ Hin,
                unsigned short* __restrict__ y, float* __restrict__ ssm_out) {
    __shared__ float Bs[CH][32];
    int d = blockIdx.x * 256 + threadIdx.x;
    int c = blockIdx.y, b = blockIdx.z;
    size_t rowbase = (size_t)b * LL + (size_t)c * CH;
    for (int e = threadIdx.x; e < CH * 32; e += 256) {
        int i = e >> 5, j = e & 31;
        Bs[i][j] = xbc[(rowbase + i) * 32 + j];
    }
    float al2[16];
    {
        const float4* ap = (const float4*)(A_log + (size_t)d * D_STATE);
#pragma unroll
        for (int q = 0; q < 4; ++q) {
            float4 a4 = ap[q];
            al2[q*4+0] = -expf(a4.x) * LOG2E;
            al2[q*4+1] = -expf(a4.y) * LOG2E;
            al2[q*4+2] = -expf(a4.z) * LOG2E;
            al2[q*4+3] = -expf(a4.w) * LOG2E;
        }
    }
    float Dv = Dp[d];
    float h[16];
    {
        const float4* hp = (const float4*)(Hin + (((size_t)b * NC + c) * D_INNER + d) * D_STATE);
#pragma unroll
        for (int q = 0; q < 4; ++q) {
            float4 h4 = hp[q];
            h[q*4+0] = h4.x; h[q*4+1] = h4.y; h[q*4+2] = h4.z; h[q*4+3] = h4.w;
        }
    }
    __syncthreads();
    size_t r0 = rowbase * D_INNER + d;
    float dtv = dt[r0];
    float xv  = bf2f(xs[r0]);
    float zv  = bf2f(xzb[rowbase * XZLD + D_INNER + d]);
    for (int i = 0; i < CH; ++i) {
        float dtn = 0.0f, xn2 = 0.0f, zn2 = 0.0f;
        if (i + 1 < CH) {
            size_t r2 = (rowbase + i + 1) * D_INNER + d;
            dtn = dt[r2]; xn2 = bf2f(xs[r2]);
            zn2 = bf2f(xzb[(rowbase + i + 1) * XZLD + D_INNER + d]);
        }
        float dtx = dtv * xv;
        float yv = 0.0f;
#pragma unroll
        for (int q = 0; q < 4; ++q) {
            float4 Bv = *(const float4*)&Bs[i][q * 4];
            float4 Cv = *(const float4*)&Bs[i][16 + q * 4];
            h[q*4+0] = fmaf(exp2f(al2[q*4+0] * dtv), h[q*4+0], dtx * Bv.x);
            h[q*4+1] = fmaf(exp2f(al2[q*4+1] * dtv), h[q*4+1], dtx * Bv.y);
            h[q*4+2] = fmaf(exp2f(al2[q*4+2] * dtv), h[q*4+2], dtx * Bv.z);
            h[q*4+3] = fmaf(exp2f(al2[q*4+3] * dtv), h[q*4+3], dtx * Bv.w);
            yv = fmaf(h[q*4+0], Cv.x, yv);
            yv = fmaf(h[q*4+1], Cv.y, yv);
            yv = fmaf(h[q*4+2], Cv.z, yv);
            yv = fmaf(h[q*4+3], Cv.w, yv);
        }
        yv = (yv + xv * Dv) * (zv / (1.0f + expf(-zv)));
        y[(rowbase + i) * D_INNER + d] = f2bf(yv);
        dtv = dtn; xv = xn2; zv = zn2;
    }
    if (c == NC - 1) {
        float* sp = ssm_out + ((size_t)b * D_INNER + d) * D_STATE;
#pragma unroll
        for (int q = 0; q < 4; ++q) {
            float4 h4;
            h4.x = h[q*4+0]; h4.y = h[q*4+1]; h4.z = h[q*4+2]; h4.w = h[q*4+3];
            *(float4*)(sp + q * 4) = h4;
        }
    }
}

// ---------------- launch ----------------
extern "C" void kernel_launch(void* const* d_in, const int* in_sizes, int n_in,
                              void* d_out, int out_size, void* d_ws, size_t ws_size,
                              hipStream_t stream) {
    (void)in_sizes; (void)n_in; (void)out_size; (void)ws_size;
    const float* x      = (const float*)d_in[0];
    const float* ln_w   = (const float*)d_in[1];
    const float* ln_b   = (const float*)d_in[2];
    const float* Win    = (const float*)d_in[3];   // [1024, 4096]
    const float* convw  = (const float*)d_in[4];   // [2048, 4]
    const float* convb  = (const float*)d_in[5];
    const float* Wx     = (const float*)d_in[6];   // [2048, 96]
    const float* Wdt    = (const float*)d_in[7];   // [64, 2048]
    const float* bdt    = (const float*)d_in[8];
    const float* A_log  = (const float*)d_in[9];   // [2048, 16]
    const float* Dp     = (const float*)d_in[10];
    const float* Wout   = (const float*)d_in[11];  // [2048, 1024]
    const float* rscale = (const float*)d_in[12];  // [1]

    float* out      = (float*)d_out;
    float* ssm_out  = out + (size_t)NROWS * D_MODEL;
    float* conv_out = ssm_out + (size_t)BB * D_INNER * D_STATE;

    // ---- workspace layout (~146.5 MB; 152.6 MB proven available) ----
    float* ws = (float*)d_ws;
    unsigned short* xzb = (unsigned short*)ws;                     // 33.55 MB bf16 [4096x4096]
    unsigned short* xsb = xzb + (size_t)NROWS * XZLD;              // 16.78 MB bf16 [4096x2048]
    float* dtb  = (float*)(xsb + (size_t)NROWS * D_INNER);         // 33.55 MB
    float* xbc  = dtb + (size_t)NROWS * D_INNER;                   // 0.52 MB
    unsigned short* xdtr = (unsigned short*)(xbc + (size_t)NROWS * 32);  // 0.52 MB
    unsigned short* xnb  = xdtr + (size_t)NROWS * DT_RANK;         // 8.39 MB
    unsigned short* wtin = xnb + (size_t)NROWS * D_MODEL;          // 8.39 MB
    unsigned short* wtout = wtin + (size_t)(2 * D_INNER) * D_MODEL; // 4.19 MB
    unsigned short* Wxt  = wtout + (size_t)D_MODEL * D_INNER;      // 0.52 MB
    unsigned short* Wdtt = Wxt + (size_t)128 * D_INNER;            // 0.26 MB
    float* Ebuf = (float*)(Wdtt + (size_t)D_INNER * DT_RANK);      // 16.78 MB (later P0)
    float* Sbuf = Ebuf + (size_t)BB * NC * D_INNER * D_STATE;      // 16.78 MB (later P1)
    float* Pxdbl = Sbuf + (size_t)BB * NC * D_INNER * D_STATE;     // 6.29 MB
    float* Hin   = Ebuf;   // scan2 output aliases E (safe: load-then-store order)
    float* P0 = Ebuf, *P1 = Sbuf;  // out_proj partials (dead after scan3)

    // 1. LN + all weight transposes (one launch)
    prologue_kernel<<<NROWS + 228 * 64, 256, 0, stream>>>(
        x, ln_w, ln_b, xnb, Win, Wout, Wx, Wdt, wtin, wtout, Wxt, Wdtt);

    // 2. in_proj: all 4096 cols -> bf16 fused xz buffer
    mfma_gemm<<<dim3(2 * D_INNER / 128, NROWS / 128), 256, 0, stream>>>(
        xnb, wtin, nullptr, XZLD, D_MODEL, D_MODEL, 0, 3,
        nullptr, 0, xzb);

    // 3. conv + silu -> bf16 x_s (+ conv_state)
    conv_kernel<<<BB * (LL / 8), 256, 0, stream>>>(
        xzb, convw, convb, xsb, conv_out);

    // 4. x_dbl split-K x4 -> partials (MFMA), then reduce
    mfma_gemm<<<dim3(1, NROWS / 128, 4), 256, 0, stream>>>(
        xsb, Wxt, Pxdbl, 96, D_INNER, D_INNER / 4, (size_t)NROWS * 96, 0,
        nullptr, 96, nullptr);
    xdbl_reduce<<<(NROWS * 96) / 256, 256, 0, stream>>>(Pxdbl, xdtr, xbc);

    // 5. dt = softplus(xdtr @ Wdt + b)  (MFMA, K=64, single k-tile)
    mfma_gemm<<<dim3(D_INNER / 128, NROWS / 128), 256, 0, stream>>>(
        xdtr, Wdtt, dtb, D_INNER, DT_RANK, DT_RANK, 0, 1,
        bdt, D_INNER, nullptr);

    // 6-8. chunked selective scan (y -> bf16 into dead xnb+wtin region)
    unsigned short* ybuf = xnb;
    scan_part1<<<dim3(D_INNER / 256, NC, BB), 256, 0, stream>>>(
        dtb, xbc, xsb, A_log, Ebuf, Sbuf);
    scan_part2<<<(BB * D_INNER * D_STATE) / 256, 256, 0, stream>>>(
        Ebuf, Sbuf, Hin);
    scan_part3<<<dim3(D_INNER / 256, NC, BB), 256, 0, stream>>>(
        dtb, xbc, xsb, xzb, A_log, Dp, Hin, ybuf, ssm_out);

    // 9. out_proj split-K x2 -> partials P0/P1 (Ebuf/Sbuf dead after scan3)
    mfma_gemm<<<dim3(D_MODEL / 128, NROWS / 128, 2), 256, 0, stream>>>(
        ybuf, wtout, P0, D_MODEL, D_INNER, D_INNER / 2,
        (size_t)BB * NC * D_INNER * D_STATE, 0,
        nullptr, D_MODEL, nullptr);

    // 10. out = rs*(P0+P1) + residual
    out_final<<<(NROWS * D_MODEL) / (256 * 4), 256, 0, stream>>>(
        P0, P1, x, rscale, out);
}

// Round 9
// 378.646 us; speedup vs baseline: 4.3358x; 1.0356x over previous
//
#include <hip/hip_runtime.h>
#include <math.h>

#define D_MODEL 1024
#define D_STATE 16
#define D_CONVK 4
#define D_INNER 2048
#define DT_RANK 64
#define BB 2
#define LL 2048
#define NROWS (BB*LL)   // 4096
#define NC 64           // scan chunks
#define CH (LL/NC)      // 32 steps per chunk
#define XZLD 4096       // fused xz bf16 row stride
#define LOG2E 1.44269504088896340736f

typedef __attribute__((ext_vector_type(8))) short bf16x8;
typedef __attribute__((ext_vector_type(8))) unsigned short u16x8;
typedef __attribute__((ext_vector_type(4))) float f32x4;

typedef __attribute__((address_space(3))) unsigned char lds_ucp;
typedef const __attribute__((address_space(1))) unsigned char glb_ucp;
#define GLD16(gp, lp) __builtin_amdgcn_global_load_lds((glb_ucp*)(gp), (lds_ucp*)(lp), 16, 0, 0)

__device__ inline unsigned short f2bf(float f) {
    union { float f; unsigned u; } c; c.f = f;
    unsigned r = c.u + 0x7fff + ((c.u >> 16) & 1);   // round-to-nearest-even
    return (unsigned short)(r >> 16);
}
__device__ inline float bf2f(unsigned short s) {
    union { unsigned u; float f; } c; c.u = ((unsigned)s) << 16;
    return c.f;
}

// ---- merged prologue: LN (bx<4096) + all 4 weight transposes (bx>=4096) ----
__global__ __launch_bounds__(256)
void prologue_kernel(const float* __restrict__ x, const float* __restrict__ lw,
                     const float* __restrict__ lb, unsigned short* __restrict__ xnb,
                     const float* __restrict__ Win, const float* __restrict__ Wout,
                     const float* __restrict__ Wx, const float* __restrict__ Wdt,
                     unsigned short* __restrict__ wtin, unsigned short* __restrict__ wtout,
                     unsigned short* __restrict__ Wxt, unsigned short* __restrict__ Wdtt) {
    if (blockIdx.x < NROWS) {
        int row = blockIdx.x;
        const float* xr = x + (size_t)row * D_MODEL;
        float4 v = ((const float4*)xr)[threadIdx.x];
        float s  = v.x + v.y + v.z + v.w;
        float ss = v.x*v.x + v.y*v.y + v.z*v.z + v.w*v.w;
        for (int off = 32; off > 0; off >>= 1) {
            s  += __shfl_down(s, off);
            ss += __shfl_down(ss, off);
        }
        __shared__ float red[8];
        int lane = threadIdx.x & 63, wv = threadIdx.x >> 6;
        if (lane == 0) { red[wv] = s; red[wv + 4] = ss; }
        __syncthreads();
        if (threadIdx.x == 0) {
            float ts  = red[0] + red[1] + red[2] + red[3];
            float tss = red[4] + red[5] + red[6] + red[7];
            float mu  = ts / D_MODEL;
            float var = tss / D_MODEL - mu * mu;
            red[0] = mu; red[1] = rsqrtf(var + 1e-5f);
        }
        __syncthreads();
        float mu = red[0], rs = red[1];
        float4 w4 = ((const float4*)lw)[threadIdx.x];
        float4 b4 = ((const float4*)lb)[threadIdx.x];
        ushort4 o;
        o.x = f2bf((v.x - mu) * rs * w4.x + b4.x);
        o.y = f2bf((v.y - mu) * rs * w4.y + b4.y);
        o.z = f2bf((v.z - mu) * rs * w4.z + b4.z);
        o.w = f2bf((v.w - mu) * rs * w4.w + b4.w);
        ((ushort4*)(xnb + (size_t)row * D_MODEL))[threadIdx.x] = o;
        return;
    }
    int tb = blockIdx.x - NROWS;
    int bx = tb % 228, by = tb / 228;
    __shared__ float t[32][33];
    const float* W; unsigned short* Wt; int K, Nsrc, xb;
    if (bx < 128)      { W = Win;  Wt = wtin;  K = 1024; Nsrc = 4096; xb = bx; }
    else if (bx < 160) { W = Wout; Wt = wtout; K = 2048; Nsrc = 1024; xb = bx - 128; }
    else if (bx < 164) { W = Wx;   Wt = Wxt;   K = 2048; Nsrc = 96;   xb = bx - 160; }
    else               { W = Wdt;  Wt = Wdtt;  K = 64;   Nsrc = 2048; xb = bx - 164; }
    int k0 = by * 32, n0 = xb * 32;
    if (k0 >= K) return;
    int tx = threadIdx.x & 31, ty = threadIdx.x >> 5;
#pragma unroll
    for (int i = 0; i < 32; i += 8)
        t[ty + i][tx] = (n0 + tx < Nsrc)
            ? W[(size_t)(k0 + ty + i) * Nsrc + n0 + tx] : 0.0f;
    __syncthreads();
#pragma unroll
    for (int i = 0; i < 32; i += 8)
        Wt[(size_t)(n0 + ty + i) * K + k0 + tx] = f2bf(t[tx][ty + i]);
}

// ------- big-tile bf16 MFMA GEMM: 256x128, 512 threads, bf16 output --------
// 8 waves: wave (w&3)=row-slab of 64, (w>>2)=col-slab of 64. BK=64.
__global__ __launch_bounds__(512)
void mfma_gemm_big(const unsigned short* __restrict__ A,
                   const unsigned short* __restrict__ Wt,
                   int ldc, int K, unsigned short* __restrict__ out2) {
    __shared__ short As[256 * 64];
    __shared__ short Bs[128 * 64];
    int tid = threadIdx.x;
    int lane = tid & 63, w = tid >> 6;
    int wr2 = w & 3, wc2 = w >> 2;
    int row0 = blockIdx.y * 256, col0 = blockIdx.x * 128;
    f32x4 acc[4][4] = {};
    const unsigned short* gA0 = A  + (size_t)row0 * K;
    const unsigned short* gB0 = Wt + (size_t)col0 * K;
    int r_in = lane >> 3;          // 0..7
    int e16  = (lane & 7) * 8;
    int quad = lane >> 4, r16 = lane & 15;
    for (int k0 = 0; k0 < K; k0 += 64) {
        __syncthreads();
#pragma unroll
        for (int t = 0; t < 4; ++t) {
            int p = w * 4 + t;               // 0..31
            int row = p * 8 + r_in;
            GLD16(gA0 + (size_t)row * K + k0 + e16, (char*)As + p * 1024);
        }
#pragma unroll
        for (int t = 0; t < 2; ++t) {
            int p = w * 2 + t;               // 0..15
            int row = p * 8 + r_in;
            GLD16(gB0 + (size_t)row * K + k0 + e16, (char*)Bs + p * 1024);
        }
        __syncthreads();
#pragma unroll
        for (int ks = 0; ks < 2; ++ks) {
            bf16x8 af[4], bfr[4];
#pragma unroll
            for (int i = 0; i < 4; ++i) {
                af[i]  = *(const bf16x8*)&As[(wr2 * 64 + i * 16 + r16) * 64 + ks * 32 + quad * 8];
                bfr[i] = *(const bf16x8*)&Bs[(wc2 * 64 + i * 16 + r16) * 64 + ks * 32 + quad * 8];
            }
#pragma unroll
            for (int mi = 0; mi < 4; ++mi)
#pragma unroll
                for (int ni = 0; ni < 4; ++ni)
                    acc[mi][ni] = __builtin_amdgcn_mfma_f32_16x16x32_bf16(
                        af[mi], bfr[ni], acc[mi][ni], 0, 0, 0);
        }
    }
    int odd = lane & 1;
#pragma unroll
    for (int mi = 0; mi < 4; ++mi)
#pragma unroll
        for (int ni = 0; ni < 4; ++ni) {
            int colE = col0 + wc2 * 64 + ni * 16 + r16;
#pragma unroll
            for (int rp = 0; rp < 2; ++rp) {
                int rowE = row0 + wr2 * 64 + mi * 16 + quad * 4 + rp * 2;
                int row  = rowE + odd;
                int colp = colE - odd;
                unsigned hh = (unsigned)f2bf(acc[mi][ni][rp*2]) |
                              ((unsigned)f2bf(acc[mi][ni][rp*2+1]) << 16);
                unsigned ph = __shfl_xor((int)hh, 1);
                unsigned u_even = (hh & 0xffffu) | (ph << 16);
                unsigned u_odd  = (ph >> 16) | (hh & 0xffff0000u);
                unsigned u = odd ? u_odd : u_even;
                *(unsigned*)&out2[(size_t)row * ldc + colp] = u;
            }
        }
}

// ---------------- bf16 MFMA GEMM: 128x128, 256 threads, BK=64 --------------
// mode 0: fp32 pair-packed if col<Ncols | mode 3: bf16 pair-packed
// mode 4: softplus(acc+aux[col]) -> bf16 pair-packed
__global__ __launch_bounds__(256)
void mfma_gemm(const unsigned short* __restrict__ A,
               const unsigned short* __restrict__ Wt,
               float* __restrict__ C, int ldc, int K, int kchunk,
               size_t zstride, int mode,
               const float* __restrict__ aux,
               int Ncols, unsigned short* __restrict__ out2) {
    __shared__ short As[128 * 64];
    __shared__ short Bs[128 * 64];
    int tid = threadIdx.x;
    int lane = tid & 63, w = tid >> 6;
    int wm = w & 1, wn = w >> 1;
    int row0 = blockIdx.y * 128, col0 = blockIdx.x * 128;
    int kb = blockIdx.z * kchunk, ke = kb + kchunk;
    C += (size_t)blockIdx.z * zstride;
    f32x4 acc[4][4] = {};
    const unsigned short* gA0 = A  + (size_t)row0 * K;
    const unsigned short* gB0 = Wt + (size_t)col0 * K;
    int r_in = lane >> 3;
    int e16  = (lane & 7) * 8;
    int quad = lane >> 4, r16 = lane & 15;
    for (int k0 = kb; k0 < ke; k0 += 64) {
        __syncthreads();
#pragma unroll
        for (int t = 0; t < 4; ++t) {
            int p = w * 4 + t;
            int row = p * 8 + r_in;
            GLD16(gA0 + (size_t)row * K + k0 + e16, (char*)As + p * 1024);
            GLD16(gB0 + (size_t)row * K + k0 + e16, (char*)Bs + p * 1024);
        }
        __syncthreads();
#pragma unroll
        for (int ks = 0; ks < 2; ++ks) {
            bf16x8 af[4], bfr[4];
#pragma unroll
            for (int i = 0; i < 4; ++i) {
                af[i]  = *(const bf16x8*)&As[(wm * 64 + i * 16 + r16) * 64 + ks * 32 + quad * 8];
                bfr[i] = *(const bf16x8*)&Bs[(wn * 64 + i * 16 + r16) * 64 + ks * 32 + quad * 8];
            }
#pragma unroll
            for (int mi = 0; mi < 4; ++mi)
#pragma unroll
                for (int ni = 0; ni < 4; ++ni)
                    acc[mi][ni] = __builtin_amdgcn_mfma_f32_16x16x32_bf16(
                        af[mi], bfr[ni], acc[mi][ni], 0, 0, 0);
        }
    }
    int odd = lane & 1;
#pragma unroll
    for (int mi = 0; mi < 4; ++mi)
#pragma unroll
        for (int ni = 0; ni < 4; ++ni) {
            int colE = col0 + wn * 64 + ni * 16 + r16;
            float v[4];
#pragma unroll
            for (int r = 0; r < 4; ++r) v[r] = acc[mi][ni][r];
            if (mode == 4) {
                float bv = aux[colE];
#pragma unroll
                for (int r = 0; r < 4; ++r) {
                    float tv = v[r] + bv;
                    v[r] = (tv > 20.0f) ? tv : log1pf(expf(tv));
                }
            }
#pragma unroll
            for (int rp = 0; rp < 2; ++rp) {
                int rowE = row0 + wm * 64 + mi * 16 + quad * 4 + rp * 2;
                int row  = rowE + odd;
                int colp = colE - odd;
                if (mode >= 3) {
                    unsigned hh = (unsigned)f2bf(v[rp*2]) | ((unsigned)f2bf(v[rp*2+1]) << 16);
                    unsigned ph = __shfl_xor((int)hh, 1);
                    unsigned u_even = (hh & 0xffffu) | (ph << 16);
                    unsigned u_odd  = (ph >> 16) | (hh & 0xffff0000u);
                    unsigned u = odd ? u_odd : u_even;
                    *(unsigned*)&out2[(size_t)row * ldc + colp] = u;
                } else {
                    float a0 = v[rp*2], a1 = v[rp*2+1];
                    float b0 = __shfl_xor(a0, 1), b1 = __shfl_xor(a1, 1);
                    float2 f2;
                    f2.x = odd ? b1 : a0;
                    f2.y = odd ? a1 : b0;
                    if (colp < Ncols)
                        *(float2*)&C[(size_t)row * ldc + colp] = f2;
                }
            }
        }
}

// ---- reduce 8 split-K partials of x_dbl; emit dt-rank bf16 + B|C fp32 ----
__global__ __launch_bounds__(256)
void xdbl_reduce(const float* __restrict__ P,
                 unsigned short* __restrict__ xdtr, float* __restrict__ xbc) {
    const int S1 = NROWS * 96;
    int t = blockIdx.x * 256 + threadIdx.x;
    float s = 0.0f;
#pragma unroll
    for (int k = 0; k < 8; ++k) s += P[t + k * S1];
    int row = t / 96, col = t - row * 96;
    if (col < DT_RANK) xdtr[(size_t)row * DT_RANK + col] = f2bf(s);
    else xbc[(size_t)row * 32 + col - DT_RANK] = s;
}

// ---- out = rs*(P0+P1) + residual ----
__global__ __launch_bounds__(256)
void out_final(const float* __restrict__ P0, const float* __restrict__ P1,
               const float* __restrict__ x, const float* __restrict__ rscale,
               float* __restrict__ out) {
    int t = blockIdx.x * 256 + threadIdx.x;
    float rs = rscale[0];
    float4 a = ((const float4*)P0)[t];
    float4 b = ((const float4*)P1)[t];
    float4 r = ((const float4*)x)[t];
    float4 o;
    o.x = rs * (a.x + b.x) + r.x;
    o.y = rs * (a.y + b.y) + r.y;
    o.z = rs * (a.z + b.z) + r.z;
    o.w = rs * (a.w + b.w) + r.w;
    ((float4*)out)[t] = o;
}

// ---- Causal depthwise conv (K=4) + bias + silu, bf16 in/out, vectorized ----
__global__ __launch_bounds__(256)
void conv_kernel(const unsigned short* __restrict__ xzb, const float* __restrict__ cw,
                 const float* __restrict__ cb, unsigned short* __restrict__ xs,
                 float* __restrict__ conv_state_out) {
    int loct = blockIdx.x & 255;
    int b    = blockIdx.x >> 8;
    int d0   = threadIdx.x * 8;
    float wgt[8][4];
#pragma unroll
    for (int j = 0; j < 8; ++j) {
        float4 w4 = *(const float4*)(cw + (size_t)(d0 + j) * 4);
        wgt[j][0] = w4.x; wgt[j][1] = w4.y; wgt[j][2] = w4.z; wgt[j][3] = w4.w;
    }
    float bias[8];
    *(float4*)&bias[0] = *(const float4*)(cb + d0);
    *(float4*)&bias[4] = *(const float4*)(cb + d0 + 4);
    float xr[11][8];
#pragma unroll
    for (int r = 0; r < 11; ++r) {
        int l = loct * 8 - 3 + r;
        if (l >= 0) {
            u16x8 v = *(const u16x8*)&xzb[((size_t)b * LL + l) * XZLD + d0];
#pragma unroll
            for (int j = 0; j < 8; ++j) xr[r][j] = bf2f(v[j]);
        } else {
#pragma unroll
            for (int j = 0; j < 8; ++j) xr[r][j] = 0.0f;
        }
    }
#pragma unroll
    for (int i = 0; i < 8; ++i) {
        unsigned short o[8];
#pragma unroll
        for (int j = 0; j < 8; ++j) {
            float a = bias[j];
#pragma unroll
            for (int k = 0; k < 4; ++k) a = fmaf(xr[i + k][j], wgt[j][k], a);
            a = a / (1.0f + expf(-a));   // silu
            o[j] = f2bf(a);
        }
        *(u16x8*)&xs[((size_t)b * LL + loct * 8 + i) * D_INNER + d0] = *(u16x8*)o;
    }
    if (loct == 255) {
#pragma unroll
        for (int i = 8; i < 11; ++i)
#pragma unroll
            for (int j = 0; j < 8; ++j)
                conv_state_out[((size_t)b * D_INNER + d0 + j) * 3 + (i - 8)] = xr[i][j];
    }
}

// ---------------- Selective scan: thread-per-d, 16 n-states in regs --------
__global__ __launch_bounds__(256)
void scan_part1(const unsigned short* __restrict__ dt, const float* __restrict__ xbc,
                const unsigned short* __restrict__ xs,
                const float* __restrict__ A_log,
                float* __restrict__ Ebuf, float* __restrict__ Sbuf) {
    __shared__ float Bs[CH][32];
    int d = blockIdx.x * 256 + threadIdx.x;
    int c = blockIdx.y, b = blockIdx.z;
    size_t rowbase = (size_t)b * LL + (size_t)c * CH;
    for (int e = threadIdx.x; e < CH * 32; e += 256) {
        int i = e >> 5, j = e & 31;
        Bs[i][j] = xbc[(rowbase + i) * 32 + j];
    }
    float al2[16];
    {
        const float4* ap = (const float4*)(A_log + (size_t)d * D_STATE);
#pragma unroll
        for (int q = 0; q < 4; ++q) {
            float4 a4 = ap[q];
            al2[q*4+0] = -expf(a4.x) * LOG2E;
            al2[q*4+1] = -expf(a4.y) * LOG2E;
            al2[q*4+2] = -expf(a4.z) * LOG2E;
            al2[q*4+3] = -expf(a4.w) * LOG2E;
        }
    }
    __syncthreads();
    float S[16];
#pragma unroll
    for (int n = 0; n < 16; ++n) S[n] = 0.0f;
    float Tsum = 0.0f;
    float dtv = bf2f(dt[rowbase * D_INNER + d]);
    float xv  = bf2f(xs[rowbase * D_INNER + d]);
    for (int i = 0; i < CH; ++i) {
        float dtn = 0.0f, xn2 = 0.0f;
        if (i + 1 < CH) {
            size_t r2 = (rowbase + i + 1) * D_INNER + d;
            dtn = bf2f(dt[r2]); xn2 = bf2f(xs[r2]);
        }
        Tsum += dtv;
        float dtx = dtv * xv;
#pragma unroll
        for (int q = 0; q < 4; ++q) {
            float4 Bv = *(const float4*)&Bs[i][q * 4];
            S[q*4+0] = fmaf(exp2f(al2[q*4+0] * dtv), S[q*4+0], dtx * Bv.x);
            S[q*4+1] = fmaf(exp2f(al2[q*4+1] * dtv), S[q*4+1], dtx * Bv.y);
            S[q*4+2] = fmaf(exp2f(al2[q*4+2] * dtv), S[q*4+2], dtx * Bv.z);
            S[q*4+3] = fmaf(exp2f(al2[q*4+3] * dtv), S[q*4+3], dtx * Bv.w);
        }
        dtv = dtn; xv = xn2;
    }
    size_t o = (((size_t)b * NC + c) * D_INNER + d) * D_STATE;
#pragma unroll
    for (int q = 0; q < 4; ++q) {
        float4 Ev, Sv;
        Ev.x = exp2f(al2[q*4+0] * Tsum); Ev.y = exp2f(al2[q*4+1] * Tsum);
        Ev.z = exp2f(al2[q*4+2] * Tsum); Ev.w = exp2f(al2[q*4+3] * Tsum);
        Sv.x = S[q*4+0]; Sv.y = S[q*4+1]; Sv.z = S[q*4+2]; Sv.w = S[q*4+3];
        *(float4*)(Ebuf + o + q * 4) = Ev;
        *(float4*)(Sbuf + o + q * 4) = Sv;
    }
}

__global__ __launch_bounds__(256)
void scan_part2(const float* E, const float* S, float* Hin) {
    int t = blockIdx.x * 256 + threadIdx.x;
    int b = t >> 15;
    int rem = t & 32767;
    size_t base = (size_t)b * NC * (D_INNER * D_STATE) + rem;
    float h = 0.0f;
    for (int c0 = 0; c0 < NC; c0 += 16) {
        float Ec[16], Sc[16];
#pragma unroll
        for (int k = 0; k < 16; ++k) {
            size_t q = base + (size_t)(c0 + k) * (D_INNER * D_STATE);
            Ec[k] = E[q]; Sc[k] = S[q];
        }
#pragma unroll
        for (int k = 0; k < 16; ++k) {
            Hin[base + (size_t)(c0 + k) * (D_INNER * D_STATE)] = h;
            h = fmaf(Ec[k], h, Sc[k]);
        }
    }
}

__global__ __launch_bounds__(256)
void scan_part3(const unsigned short* __restrict__ dt, const float* __restrict__ xbc,
                const unsigned short* __restrict__ xs,
                const unsigned short* __restrict__ xzb,  // z at col 2048+, stride XZLD
                const float* __restrict__ A_log, const float* __restrict__ Dp,
                const float* __restrict__ Hin,
                unsigned short* __restrict__ y, float* __restrict__ ssm_out) {
    __shared__ float Bs[CH][32];
    int d = blockIdx.x * 256 + threadIdx.x;
    int c = blockIdx.y, b = blockIdx.z;
    size_t rowbase = (size_t)b * LL + (size_t)c * CH;
    for (int e = threadIdx.x; e < CH * 32; e += 256) {
        int i = e >> 5, j = e & 31;
        Bs[i][j] = xbc[(rowbase + i) * 32 + j];
    }
    float al2[16];
    {
        const float4* ap = (const float4*)(A_log + (size_t)d * D_STATE);
#pragma unroll
        for (int q = 0; q < 4; ++q) {
            float4 a4 = ap[q];
            al2[q*4+0] = -expf(a4.x) * LOG2E;
            al2[q*4+1] = -expf(a4.y) * LOG2E;
            al2[q*4+2] = -expf(a4.z) * LOG2E;
            al2[q*4+3] = -expf(a4.w) * LOG2E;
        }
    }
    float Dv = Dp[d];
    float h[16];
    {
        const float4* hp = (const float4*)(Hin + (((size_t)b * NC + c) * D_INNER + d) * D_STATE);
#pragma unroll
        for (int q = 0; q < 4; ++q) {
            float4 h4 = hp[q];
            h[q*4+0] = h4.x; h[q*4+1] = h4.y; h[q*4+2] = h4.z; h[q*4+3] = h4.w;
        }
    }
    __syncthreads();
    size_t r0 = rowbase * D_INNER + d;
    float dtv = bf2f(dt[r0]);
    float xv  = bf2f(xs[r0]);
    float zv  = bf2f(xzb[rowbase * XZLD + D_INNER + d]);
    for (int i = 0; i < CH; ++i) {
        float dtn = 0.0f, xn2 = 0.0f, zn2 = 0.0f;
        if (i + 1 < CH) {
            size_t r2 = (rowbase + i + 1) * D_INNER + d;
            dtn = bf2f(dt[r2]); xn2 = bf2f(xs[r2]);
            zn2 = bf2f(xzb[(rowbase + i + 1) * XZLD + D_INNER + d]);
        }
        float dtx = dtv * xv;
        float yv = 0.0f;
#pragma unroll
        for (int q = 0; q < 4; ++q) {
            float4 Bv = *(const float4*)&Bs[i][q * 4];
            float4 Cv = *(const float4*)&Bs[i][16 + q * 4];
            h[q*4+0] = fmaf(exp2f(al2[q*4+0] * dtv), h[q*4+0], dtx * Bv.x);
            h[q*4+1] = fmaf(exp2f(al2[q*4+1] * dtv), h[q*4+1], dtx * Bv.y);
            h[q*4+2] = fmaf(exp2f(al2[q*4+2] * dtv), h[q*4+2], dtx * Bv.z);
            h[q*4+3] = fmaf(exp2f(al2[q*4+3] * dtv), h[q*4+3], dtx * Bv.w);
            yv = fmaf(h[q*4+0], Cv.x, yv);
            yv = fmaf(h[q*4+1], Cv.y, yv);
            yv = fmaf(h[q*4+2], Cv.z, yv);
            yv = fmaf(h[q*4+3], Cv.w, yv);
        }
        yv = (yv + xv * Dv) * (zv / (1.0f + expf(-zv)));
        y[(rowbase + i) * D_INNER + d] = f2bf(yv);
        dtv = dtn; xv = xn2; zv = zn2;
    }
    if (c == NC - 1) {
        float* sp = ssm_out + ((size_t)b * D_INNER + d) * D_STATE;
#pragma unroll
        for (int q = 0; q < 4; ++q) {
            float4 h4;
            h4.x = h[q*4+0]; h4.y = h[q*4+1]; h4.z = h[q*4+2]; h4.w = h[q*4+3];
            *(float4*)(sp + q * 4) = h4;
        }
    }
}

// ---------------- launch ----------------
extern "C" void kernel_launch(void* const* d_in, const int* in_sizes, int n_in,
                              void* d_out, int out_size, void* d_ws, size_t ws_size,
                              hipStream_t stream) {
    (void)in_sizes; (void)n_in; (void)out_size; (void)ws_size;
    const float* x      = (const float*)d_in[0];
    const float* ln_w   = (const float*)d_in[1];
    const float* ln_b   = (const float*)d_in[2];
    const float* Win    = (const float*)d_in[3];   // [1024, 4096]
    const float* convw  = (const float*)d_in[4];   // [2048, 4]
    const float* convb  = (const float*)d_in[5];
    const float* Wx     = (const float*)d_in[6];   // [2048, 96]
    const float* Wdt    = (const float*)d_in[7];   // [64, 2048]
    const float* bdt    = (const float*)d_in[8];
    const float* A_log  = (const float*)d_in[9];   // [2048, 16]
    const float* Dp     = (const float*)d_in[10];
    const float* Wout   = (const float*)d_in[11];  // [2048, 1024]
    const float* rscale = (const float*)d_in[12];  // [1]

    float* out      = (float*)d_out;
    float* ssm_out  = out + (size_t)NROWS * D_MODEL;
    float* conv_out = ssm_out + (size_t)BB * D_INNER * D_STATE;

    // ---- workspace layout (~135 MB) ----
    float* ws = (float*)d_ws;
    unsigned short* xzb = (unsigned short*)ws;                     // 33.55 MB bf16 [4096x4096]
    unsigned short* xsb = xzb + (size_t)NROWS * XZLD;              // 16.78 MB bf16
    unsigned short* dtbb = xsb + (size_t)NROWS * D_INNER;          // 16.78 MB bf16
    float* xbc  = (float*)(dtbb + (size_t)NROWS * D_INNER);        // 0.52 MB
    unsigned short* xdtr = (unsigned short*)(xbc + (size_t)NROWS * 32);  // 0.52 MB
    unsigned short* xnb  = xdtr + (size_t)NROWS * DT_RANK;         // 8.39 MB
    unsigned short* wtin = xnb + (size_t)NROWS * D_MODEL;          // 8.39 MB
    unsigned short* wtout = wtin + (size_t)(2 * D_INNER) * D_MODEL; // 4.19 MB
    unsigned short* Wxt  = wtout + (size_t)D_MODEL * D_INNER;      // 0.52 MB
    unsigned short* Wdtt = Wxt + (size_t)128 * D_INNER;            // 0.26 MB
    float* Ebuf = (float*)(Wdtt + (size_t)D_INNER * DT_RANK);      // 16.78 MB (later P0)
    float* Sbuf = Ebuf + (size_t)BB * NC * D_INNER * D_STATE;      // 16.78 MB (later P1)
    float* Pxdbl = Sbuf + (size_t)BB * NC * D_INNER * D_STATE;     // 12.58 MB (8 slices)
    float* Hin   = Ebuf;
    float* P0 = Ebuf, *P1 = Sbuf;

    // 1. LN + all weight transposes (one launch)
    prologue_kernel<<<NROWS + 228 * 64, 256, 0, stream>>>(
        x, ln_w, ln_b, xnb, Win, Wout, Wx, Wdt, wtin, wtout, Wxt, Wdtt);

    // 2. in_proj: big tile 256x128 -> bf16 fused xz
    mfma_gemm_big<<<dim3(2 * D_INNER / 128, NROWS / 256), 512, 0, stream>>>(
        xnb, wtin, XZLD, D_MODEL, xzb);

    // 3. conv + silu -> bf16 x_s (+ conv_state)
    conv_kernel<<<BB * (LL / 8), 256, 0, stream>>>(
        xzb, convw, convb, xsb, conv_out);

    // 4. x_dbl split-K x8 -> partials (MFMA), then reduce
    mfma_gemm<<<dim3(1, NROWS / 128, 8), 256, 0, stream>>>(
        xsb, Wxt, Pxdbl, 96, D_INNER, D_INNER / 8, (size_t)NROWS * 96, 0,
        nullptr, 96, nullptr);
    xdbl_reduce<<<(NROWS * 96) / 256, 256, 0, stream>>>(Pxdbl, xdtr, xbc);

    // 5. dt = softplus(xdtr @ Wdt + b) -> bf16  (MFMA, K=64)
    mfma_gemm<<<dim3(D_INNER / 128, NROWS / 128), 256, 0, stream>>>(
        xdtr, Wdtt, nullptr, D_INNER, DT_RANK, DT_RANK, 0, 4,
        bdt, D_INNER, dtbb);

    // 6-8. chunked selective scan (y -> bf16 into dead xnb+wtin region)
    unsigned short* ybuf = xnb;
    scan_part1<<<dim3(D_INNER / 256, NC, BB), 256, 0, stream>>>(
        dtbb, xbc, xsb, A_log, Ebuf, Sbuf);
    scan_part2<<<(BB * D_INNER * D_STATE) / 256, 256, 0, stream>>>(
        Ebuf, Sbuf, Hin);
    scan_part3<<<dim3(D_INNER / 256, NC, BB), 256, 0, stream>>>(
        dtbb, xbc, xsb, xzb, A_log, Dp, Hin, ybuf, ssm_out);

    // 9. out_proj split-K x2 -> partials P0/P1
    mfma_gemm<<<dim3(D_MODEL / 128, NROWS / 128, 2), 256, 0, stream>>>(
        ybuf, wtout, P0, D_MODEL, D_INNER, D_INNER / 2,
        (size_t)BB * NC * D_INNER * D_STATE, 0,
        nullptr, D_MODEL, nullptr);

    // 10. out = rs*(P0+P1) + residual
    out_final<<<(NROWS * D_MODEL) / (256 * 4), 256, 0, stream>>>(
        P0, P1, x, rscale, out);
}

// Round 10
// 304.081 us; speedup vs baseline: 5.3990x; 1.2452x over previous
//
#include <hip/hip_runtime.h>
#include <math.h>

#define D_MODEL 1024
#define D_STATE 16
#define D_CONVK 4
#define D_INNER 2048
#define DT_RANK 64
#define BB 2
#define LL 2048
#define NROWS (BB*LL)   // 4096
#define NC 128          // scan chunks
#define CH (LL/NC)      // 16 steps per chunk
#define XZLD 4096       // fused xz bf16 row stride
#define LOG2E 1.44269504088896340736f
#define LN2   0.69314718055994530942f

typedef __attribute__((ext_vector_type(8))) short bf16x8;
typedef __attribute__((ext_vector_type(8))) unsigned short u16x8;
typedef __attribute__((ext_vector_type(4))) float f32x4;

typedef __attribute__((address_space(3))) unsigned char lds_ucp;
typedef const __attribute__((address_space(1))) unsigned char glb_ucp;
#define GLD16(gp, lp) __builtin_amdgcn_global_load_lds((glb_ucp*)(gp), (lds_ucp*)(lp), 16, 0, 0)

__device__ inline unsigned short f2bf(float f) {
    union { float f; unsigned u; } c; c.f = f;
    unsigned r = c.u + 0x7fff + ((c.u >> 16) & 1);   // round-to-nearest-even
    return (unsigned short)(r >> 16);
}
__device__ inline float bf2f(unsigned short s) {
    union { unsigned u; float f; } c; c.u = ((unsigned)s) << 16;
    return c.f;
}
__device__ inline float fexp2(float x) { return __builtin_amdgcn_exp2f(x); }
__device__ inline float frcp(float x)  { return __builtin_amdgcn_rcpf(x); }
__device__ inline float fsilu(float x) { return x * frcp(1.0f + fexp2(-x * LOG2E)); }

// ---- merged prologue: LN (bx<4096) + all 4 weight transposes (bx>=4096) ----
__global__ __launch_bounds__(256)
void prologue_kernel(const float* __restrict__ x, const float* __restrict__ lw,
                     const float* __restrict__ lb, unsigned short* __restrict__ xnb,
                     const float* __restrict__ Win, const float* __restrict__ Wout,
                     const float* __restrict__ Wx, const float* __restrict__ Wdt,
                     unsigned short* __restrict__ wtin, unsigned short* __restrict__ wtout,
                     unsigned short* __restrict__ Wxt, unsigned short* __restrict__ Wdtt) {
    if (blockIdx.x < NROWS) {
        int row = blockIdx.x;
        const float* xr = x + (size_t)row * D_MODEL;
        float4 v = ((const float4*)xr)[threadIdx.x];
        float s  = v.x + v.y + v.z + v.w;
        float ss = v.x*v.x + v.y*v.y + v.z*v.z + v.w*v.w;
        for (int off = 32; off > 0; off >>= 1) {
            s  += __shfl_down(s, off);
            ss += __shfl_down(ss, off);
        }
        __shared__ float red[8];
        int lane = threadIdx.x & 63, wv = threadIdx.x >> 6;
        if (lane == 0) { red[wv] = s; red[wv + 4] = ss; }
        __syncthreads();
        if (threadIdx.x == 0) {
            float ts  = red[0] + red[1] + red[2] + red[3];
            float tss = red[4] + red[5] + red[6] + red[7];
            float mu  = ts / D_MODEL;
            float var = tss / D_MODEL - mu * mu;
            red[0] = mu; red[1] = rsqrtf(var + 1e-5f);
        }
        __syncthreads();
        float mu = red[0], rs = red[1];
        float4 w4 = ((const float4*)lw)[threadIdx.x];
        float4 b4 = ((const float4*)lb)[threadIdx.x];
        ushort4 o;
        o.x = f2bf((v.x - mu) * rs * w4.x + b4.x);
        o.y = f2bf((v.y - mu) * rs * w4.y + b4.y);
        o.z = f2bf((v.z - mu) * rs * w4.z + b4.z);
        o.w = f2bf((v.w - mu) * rs * w4.w + b4.w);
        ((ushort4*)(xnb + (size_t)row * D_MODEL))[threadIdx.x] = o;
        return;
    }
    int tb = blockIdx.x - NROWS;
    int bx = tb % 228, by = tb / 228;
    __shared__ float t[32][33];
    const float* W; unsigned short* Wt; int K, Nsrc, xb;
    if (bx < 128)      { W = Win;  Wt = wtin;  K = 1024; Nsrc = 4096; xb = bx; }
    else if (bx < 160) { W = Wout; Wt = wtout; K = 2048; Nsrc = 1024; xb = bx - 128; }
    else if (bx < 164) { W = Wx;   Wt = Wxt;   K = 2048; Nsrc = 96;   xb = bx - 160; }
    else               { W = Wdt;  Wt = Wdtt;  K = 64;   Nsrc = 2048; xb = bx - 164; }
    int k0 = by * 32, n0 = xb * 32;
    if (k0 >= K) return;
    int tx = threadIdx.x & 31, ty = threadIdx.x >> 5;
#pragma unroll
    for (int i = 0; i < 32; i += 8)
        t[ty + i][tx] = (n0 + tx < Nsrc)
            ? W[(size_t)(k0 + ty + i) * Nsrc + n0 + tx] : 0.0f;
    __syncthreads();
#pragma unroll
    for (int i = 0; i < 32; i += 8)
        Wt[(size_t)(n0 + ty + i) * K + k0 + tx] = f2bf(t[tx][ty + i]);
}

// ------- big-tile bf16 MFMA GEMM: 256x128, 512 threads, bf16 output --------
__global__ __launch_bounds__(512)
void mfma_gemm_big(const unsigned short* __restrict__ A,
                   const unsigned short* __restrict__ Wt,
                   int ldc, int K, unsigned short* __restrict__ out2) {
    __shared__ short As[256 * 64];
    __shared__ short Bs[128 * 64];
    int tid = threadIdx.x;
    int lane = tid & 63, w = tid >> 6;
    int wr2 = w & 3, wc2 = w >> 2;
    int row0 = blockIdx.y * 256, col0 = blockIdx.x * 128;
    f32x4 acc[4][4] = {};
    const unsigned short* gA0 = A  + (size_t)row0 * K;
    const unsigned short* gB0 = Wt + (size_t)col0 * K;
    int r_in = lane >> 3;
    int e16  = (lane & 7) * 8;
    int quad = lane >> 4, r16 = lane & 15;
    for (int k0 = 0; k0 < K; k0 += 64) {
        __syncthreads();
#pragma unroll
        for (int t = 0; t < 4; ++t) {
            int p = w * 4 + t;
            int row = p * 8 + r_in;
            GLD16(gA0 + (size_t)row * K + k0 + e16, (char*)As + p * 1024);
        }
#pragma unroll
        for (int t = 0; t < 2; ++t) {
            int p = w * 2 + t;
            int row = p * 8 + r_in;
            GLD16(gB0 + (size_t)row * K + k0 + e16, (char*)Bs + p * 1024);
        }
        __syncthreads();
#pragma unroll
        for (int ks = 0; ks < 2; ++ks) {
            bf16x8 af[4], bfr[4];
#pragma unroll
            for (int i = 0; i < 4; ++i) {
                af[i]  = *(const bf16x8*)&As[(wr2 * 64 + i * 16 + r16) * 64 + ks * 32 + quad * 8];
                bfr[i] = *(const bf16x8*)&Bs[(wc2 * 64 + i * 16 + r16) * 64 + ks * 32 + quad * 8];
            }
#pragma unroll
            for (int mi = 0; mi < 4; ++mi)
#pragma unroll
                for (int ni = 0; ni < 4; ++ni)
                    acc[mi][ni] = __builtin_amdgcn_mfma_f32_16x16x32_bf16(
                        af[mi], bfr[ni], acc[mi][ni], 0, 0, 0);
        }
    }
    int odd = lane & 1;
#pragma unroll
    for (int mi = 0; mi < 4; ++mi)
#pragma unroll
        for (int ni = 0; ni < 4; ++ni) {
            int colE = col0 + wc2 * 64 + ni * 16 + r16;
#pragma unroll
            for (int rp = 0; rp < 2; ++rp) {
                int rowE = row0 + wr2 * 64 + mi * 16 + quad * 4 + rp * 2;
                int row  = rowE + odd;
                int colp = colE - odd;
                unsigned hh = (unsigned)f2bf(acc[mi][ni][rp*2]) |
                              ((unsigned)f2bf(acc[mi][ni][rp*2+1]) << 16);
                unsigned ph = __shfl_xor((int)hh, 1);
                unsigned u_even = (hh & 0xffffu) | (ph << 16);
                unsigned u_odd  = (ph >> 16) | (hh & 0xffff0000u);
                unsigned u = odd ? u_odd : u_even;
                *(unsigned*)&out2[(size_t)row * ldc + colp] = u;
            }
        }
}

// ---------------- bf16 MFMA GEMM: 128x128, 256 threads, BK=64 --------------
// mode 0: fp32 pair-packed if col<Ncols | mode 3: bf16 pair-packed
// mode 4: softplus(acc+aux[col]) -> bf16 pair-packed
__global__ __launch_bounds__(256)
void mfma_gemm(const unsigned short* __restrict__ A,
               const unsigned short* __restrict__ Wt,
               float* __restrict__ C, int ldc, int K, int kchunk,
               size_t zstride, int mode,
               const float* __restrict__ aux,
               int Ncols, unsigned short* __restrict__ out2) {
    __shared__ short As[128 * 64];
    __shared__ short Bs[128 * 64];
    int tid = threadIdx.x;
    int lane = tid & 63, w = tid >> 6;
    int wm = w & 1, wn = w >> 1;
    int row0 = blockIdx.y * 128, col0 = blockIdx.x * 128;
    int kb = blockIdx.z * kchunk, ke = kb + kchunk;
    C += (size_t)blockIdx.z * zstride;
    f32x4 acc[4][4] = {};
    const unsigned short* gA0 = A  + (size_t)row0 * K;
    const unsigned short* gB0 = Wt + (size_t)col0 * K;
    int r_in = lane >> 3;
    int e16  = (lane & 7) * 8;
    int quad = lane >> 4, r16 = lane & 15;
    for (int k0 = kb; k0 < ke; k0 += 64) {
        __syncthreads();
#pragma unroll
        for (int t = 0; t < 4; ++t) {
            int p = w * 4 + t;
            int row = p * 8 + r_in;
            GLD16(gA0 + (size_t)row * K + k0 + e16, (char*)As + p * 1024);
            GLD16(gB0 + (size_t)row * K + k0 + e16, (char*)Bs + p * 1024);
        }
        __syncthreads();
#pragma unroll
        for (int ks = 0; ks < 2; ++ks) {
            bf16x8 af[4], bfr[4];
#pragma unroll
            for (int i = 0; i < 4; ++i) {
                af[i]  = *(const bf16x8*)&As[(wm * 64 + i * 16 + r16) * 64 + ks * 32 + quad * 8];
                bfr[i] = *(const bf16x8*)&Bs[(wn * 64 + i * 16 + r16) * 64 + ks * 32 + quad * 8];
            }
#pragma unroll
            for (int mi = 0; mi < 4; ++mi)
#pragma unroll
                for (int ni = 0; ni < 4; ++ni)
                    acc[mi][ni] = __builtin_amdgcn_mfma_f32_16x16x32_bf16(
                        af[mi], bfr[ni], acc[mi][ni], 0, 0, 0);
        }
    }
    int odd = lane & 1;
#pragma unroll
    for (int mi = 0; mi < 4; ++mi)
#pragma unroll
        for (int ni = 0; ni < 4; ++ni) {
            int colE = col0 + wn * 64 + ni * 16 + r16;
            float v[4];
#pragma unroll
            for (int r = 0; r < 4; ++r) v[r] = acc[mi][ni][r];
            if (mode == 4) {
                float bv = aux[colE];
#pragma unroll
                for (int r = 0; r < 4; ++r) {
                    float tv = v[r] + bv;
                    // softplus via hw exp2/log2
                    v[r] = (tv > 20.0f) ? tv
                         : LN2 * __builtin_amdgcn_logf(1.0f + fexp2(tv * LOG2E));
                }
            }
#pragma unroll
            for (int rp = 0; rp < 2; ++rp) {
                int rowE = row0 + wm * 64 + mi * 16 + quad * 4 + rp * 2;
                int row  = rowE + odd;
                int colp = colE - odd;
                if (mode >= 3) {
                    unsigned hh = (unsigned)f2bf(v[rp*2]) | ((unsigned)f2bf(v[rp*2+1]) << 16);
                    unsigned ph = __shfl_xor((int)hh, 1);
                    unsigned u_even = (hh & 0xffffu) | (ph << 16);
                    unsigned u_odd  = (ph >> 16) | (hh & 0xffff0000u);
                    unsigned u = odd ? u_odd : u_even;
                    *(unsigned*)&out2[(size_t)row * ldc + colp] = u;
                } else {
                    float a0 = v[rp*2], a1 = v[rp*2+1];
                    float b0 = __shfl_xor(a0, 1), b1 = __shfl_xor(a1, 1);
                    float2 f2;
                    f2.x = odd ? b1 : a0;
                    f2.y = odd ? a1 : b0;
                    if (colp < Ncols)
                        *(float2*)&C[(size_t)row * ldc + colp] = f2;
                }
            }
        }
}

// ---- reduce 8 split-K partials of x_dbl; emit dt-rank bf16 + B|C fp32 ----
__global__ __launch_bounds__(256)
void xdbl_reduce(const float* __restrict__ P,
                 unsigned short* __restrict__ xdtr, float* __restrict__ xbc) {
    const int S1 = NROWS * 96;
    int t = blockIdx.x * 256 + threadIdx.x;
    float s = 0.0f;
#pragma unroll
    for (int k = 0; k < 8; ++k) s += P[t + k * S1];
    int row = t / 96, col = t - row * 96;
    if (col < DT_RANK) xdtr[(size_t)row * DT_RANK + col] = f2bf(s);
    else xbc[(size_t)row * 32 + col - DT_RANK] = s;
}

// ---- out = rs*(P0+P1) + residual ----
__global__ __launch_bounds__(256)
void out_final(const float* __restrict__ P0, const float* __restrict__ P1,
               const float* __restrict__ x, const float* __restrict__ rscale,
               float* __restrict__ out) {
    int t = blockIdx.x * 256 + threadIdx.x;
    float rs = rscale[0];
    float4 a = ((const float4*)P0)[t];
    float4 b = ((const float4*)P1)[t];
    float4 r = ((const float4*)x)[t];
    float4 o;
    o.x = rs * (a.x + b.x) + r.x;
    o.y = rs * (a.y + b.y) + r.y;
    o.z = rs * (a.z + b.z) + r.z;
    o.w = rs * (a.w + b.w) + r.w;
    ((float4*)out)[t] = o;
}

// ---- Causal depthwise conv (K=4) + bias + silu, bf16 in/out, vectorized ----
__global__ __launch_bounds__(256)
void conv_kernel(const unsigned short* __restrict__ xzb, const float* __restrict__ cw,
                 const float* __restrict__ cb, unsigned short* __restrict__ xs,
                 float* __restrict__ conv_state_out) {
    int loct = blockIdx.x & 255;
    int b    = blockIdx.x >> 8;
    int d0   = threadIdx.x * 8;
    float wgt[8][4];
#pragma unroll
    for (int j = 0; j < 8; ++j) {
        float4 w4 = *(const float4*)(cw + (size_t)(d0 + j) * 4);
        wgt[j][0] = w4.x; wgt[j][1] = w4.y; wgt[j][2] = w4.z; wgt[j][3] = w4.w;
    }
    float bias[8];
    *(float4*)&bias[0] = *(const float4*)(cb + d0);
    *(float4*)&bias[4] = *(const float4*)(cb + d0 + 4);
    float xr[11][8];
#pragma unroll
    for (int r = 0; r < 11; ++r) {
        int l = loct * 8 - 3 + r;
        if (l >= 0) {
            u16x8 v = *(const u16x8*)&xzb[((size_t)b * LL + l) * XZLD + d0];
#pragma unroll
            for (int j = 0; j < 8; ++j) xr[r][j] = bf2f(v[j]);
        } else {
#pragma unroll
            for (int j = 0; j < 8; ++j) xr[r][j] = 0.0f;
        }
    }
#pragma unroll
    for (int i = 0; i < 8; ++i) {
        unsigned short o[8];
#pragma unroll
        for (int j = 0; j < 8; ++j) {
            float a = bias[j];
#pragma unroll
            for (int k = 0; k < 4; ++k) a = fmaf(xr[i + k][j], wgt[j][k], a);
            o[j] = f2bf(fsilu(a));
        }
        *(u16x8*)&xs[((size_t)b * LL + loct * 8 + i) * D_INNER + d0] = *(u16x8*)o;
    }
    if (loct == 255) {
#pragma unroll
        for (int i = 8; i < 11; ++i)
#pragma unroll
            for (int j = 0; j < 8; ++j)
                conv_state_out[((size_t)b * D_INNER + d0 + j) * 3 + (i - 8)] = xr[i][j];
    }
}

// ---------------- Selective scan: thread-per-d, 16 n-states in regs --------
// Pass 1: chunk-local scan S[16] + Tsum (chunk dt sum). E never materialized.
__global__ __launch_bounds__(256)
void scan_part1(const unsigned short* __restrict__ dt, const float* __restrict__ xbc,
                const unsigned short* __restrict__ xs,
                const float* __restrict__ A_log,
                float* __restrict__ Sbuf, float* __restrict__ Tbuf) {
    __shared__ float Bs[CH][32];
    int d = blockIdx.x * 256 + threadIdx.x;
    int c = blockIdx.y, b = blockIdx.z;
    size_t rowbase = (size_t)b * LL + (size_t)c * CH;
    for (int e = threadIdx.x; e < CH * 32; e += 256) {
        int i = e >> 5, j = e & 31;
        Bs[i][j] = xbc[(rowbase + i) * 32 + j];
    }
    float al2[16];
    {
        const float4* ap = (const float4*)(A_log + (size_t)d * D_STATE);
#pragma unroll
        for (int q = 0; q < 4; ++q) {
            float4 a4 = ap[q];
            al2[q*4+0] = -fexp2(a4.x * LOG2E) * LOG2E;
            al2[q*4+1] = -fexp2(a4.y * LOG2E) * LOG2E;
            al2[q*4+2] = -fexp2(a4.z * LOG2E) * LOG2E;
            al2[q*4+3] = -fexp2(a4.w * LOG2E) * LOG2E;
        }
    }
    __syncthreads();
    float S[16];
#pragma unroll
    for (int n = 0; n < 16; ++n) S[n] = 0.0f;
    float Tsum = 0.0f;
    float dtv = bf2f(dt[rowbase * D_INNER + d]);
    float xv  = bf2f(xs[rowbase * D_INNER + d]);
    for (int i = 0; i < CH; ++i) {
        float dtn = 0.0f, xn2 = 0.0f;
        if (i + 1 < CH) {
            size_t r2 = (rowbase + i + 1) * D_INNER + d;
            dtn = bf2f(dt[r2]); xn2 = bf2f(xs[r2]);
        }
        Tsum += dtv;
        float dtx = dtv * xv;
#pragma unroll
        for (int q = 0; q < 4; ++q) {
            float4 Bv = *(const float4*)&Bs[i][q * 4];
            S[q*4+0] = fmaf(fexp2(al2[q*4+0] * dtv), S[q*4+0], dtx * Bv.x);
            S[q*4+1] = fmaf(fexp2(al2[q*4+1] * dtv), S[q*4+1], dtx * Bv.y);
            S[q*4+2] = fmaf(fexp2(al2[q*4+2] * dtv), S[q*4+2], dtx * Bv.z);
            S[q*4+3] = fmaf(fexp2(al2[q*4+3] * dtv), S[q*4+3], dtx * Bv.w);
        }
        dtv = dtn; xv = xn2;
    }
    size_t o = (((size_t)b * NC + c) * D_INNER + d) * D_STATE;
#pragma unroll
    for (int q = 0; q < 4; ++q) {
        float4 Sv;
        Sv.x = S[q*4+0]; Sv.y = S[q*4+1]; Sv.z = S[q*4+2]; Sv.w = S[q*4+3];
        *(float4*)(Sbuf + o + q * 4) = Sv;
    }
    Tbuf[((size_t)b * NC + c) * D_INNER + d] = Tsum;
}

// Pass 2: fold chunks; E recomputed from Tsum. Hin aliases Sbuf (load-then-store).
__global__ __launch_bounds__(256)
void scan_part2(const float* __restrict__ S, const float* __restrict__ Tbuf,
                const float* __restrict__ A_log, float* __restrict__ Hin) {
    int t = blockIdx.x * 256 + threadIdx.x;
    int b = t >> 15;
    int rem = t & 32767;          // d*16+n
    int d = rem >> 4;
    float al2 = -fexp2(A_log[rem] * LOG2E) * LOG2E;
    size_t sbase = (size_t)b * NC * (D_INNER * D_STATE) + rem;
    size_t tbase = (size_t)b * NC * D_INNER + d;
    float h = 0.0f;
    for (int c = 0; c < NC; ++c) {
        size_t sq = sbase + (size_t)c * (D_INNER * D_STATE);
        float s = S[sq];
        float T = Tbuf[tbase + (size_t)c * D_INNER];
        Hin[sq] = h;
        h = fmaf(fexp2(al2 * T), h, s);
    }
}

// Pass 3: local scan with h_in; emits y (bf16) and final ssm state.
__global__ __launch_bounds__(256)
void scan_part3(const unsigned short* __restrict__ dt, const float* __restrict__ xbc,
                const unsigned short* __restrict__ xs,
                const unsigned short* __restrict__ xzb,  // z at col 2048+, stride XZLD
                const float* __restrict__ A_log, const float* __restrict__ Dp,
                const float* __restrict__ Hin,
                unsigned short* __restrict__ y, float* __restrict__ ssm_out) {
    __shared__ float Bs[CH][32];
    int d = blockIdx.x * 256 + threadIdx.x;
    int c = blockIdx.y, b = blockIdx.z;
    size_t rowbase = (size_t)b * LL + (size_t)c * CH;
    for (int e = threadIdx.x; e < CH * 32; e += 256) {
        int i = e >> 5, j = e & 31;
        Bs[i][j] = xbc[(rowbase + i) * 32 + j];
    }
    float al2[16];
    {
        const float4* ap = (const float4*)(A_log + (size_t)d * D_STATE);
#pragma unroll
        for (int q = 0; q < 4; ++q) {
            float4 a4 = ap[q];
            al2[q*4+0] = -fexp2(a4.x * LOG2E) * LOG2E;
            al2[q*4+1] = -fexp2(a4.y * LOG2E) * LOG2E;
            al2[q*4+2] = -fexp2(a4.z * LOG2E) * LOG2E;
            al2[q*4+3] = -fexp2(a4.w * LOG2E) * LOG2E;
        }
    }
    float Dv = Dp[d];
    float h[16];
    {
        const float4* hp = (const float4*)(Hin + (((size_t)b * NC + c) * D_INNER + d) * D_STATE);
#pragma unroll
        for (int q = 0; q < 4; ++q) {
            float4 h4 = hp[q];
            h[q*4+0] = h4.x; h[q*4+1] = h4.y; h[q*4+2] = h4.z; h[q*4+3] = h4.w;
        }
    }
    __syncthreads();
    size_t r0 = rowbase * D_INNER + d;
    float dtv = bf2f(dt[r0]);
    float xv  = bf2f(xs[r0]);
    float zv  = bf2f(xzb[rowbase * XZLD + D_INNER + d]);
    for (int i = 0; i < CH; ++i) {
        float dtn = 0.0f, xn2 = 0.0f, zn2 = 0.0f;
        if (i + 1 < CH) {
            size_t r2 = (rowbase + i + 1) * D_INNER + d;
            dtn = bf2f(dt[r2]); xn2 = bf2f(xs[r2]);
            zn2 = bf2f(xzb[(rowbase + i + 1) * XZLD + D_INNER + d]);
        }
        float dtx = dtv * xv;
        float yv = 0.0f;
#pragma unroll
        for (int q = 0; q < 4; ++q) {
            float4 Bv = *(const float4*)&Bs[i][q * 4];
            float4 Cv = *(const float4*)&Bs[i][16 + q * 4];
            h[q*4+0] = fmaf(fexp2(al2[q*4+0] * dtv), h[q*4+0], dtx * Bv.x);
            h[q*4+1] = fmaf(fexp2(al2[q*4+1] * dtv), h[q*4+1], dtx * Bv.y);
            h[q*4+2] = fmaf(fexp2(al2[q*4+2] * dtv), h[q*4+2], dtx * Bv.z);
            h[q*4+3] = fmaf(fexp2(al2[q*4+3] * dtv), h[q*4+3], dtx * Bv.w);
            yv = fmaf(h[q*4+0], Cv.x, yv);
            yv = fmaf(h[q*4+1], Cv.y, yv);
            yv = fmaf(h[q*4+2], Cv.z, yv);
            yv = fmaf(h[q*4+3], Cv.w, yv);
        }
        yv = (yv + xv * Dv) * fsilu(zv);
        y[(rowbase + i) * D_INNER + d] = f2bf(yv);
        dtv = dtn; xv = xn2; zv = zn2;
    }
    if (c == NC - 1) {
        float* sp = ssm_out + ((size_t)b * D_INNER + d) * D_STATE;
#pragma unroll
        for (int q = 0; q < 4; ++q) {
            float4 h4;
            h4.x = h[q*4+0]; h4.y = h[q*4+1]; h4.z = h[q*4+2]; h4.w = h[q*4+3];
            *(float4*)(sp + q * 4) = h4;
        }
    }
}

// ---------------- launch ----------------
extern "C" void kernel_launch(void* const* d_in, const int* in_sizes, int n_in,
                              void* d_out, int out_size, void* d_ws, size_t ws_size,
                              hipStream_t stream) {
    (void)in_sizes; (void)n_in; (void)out_size; (void)ws_size;
    const float* x      = (const float*)d_in[0];
    const float* ln_w   = (const float*)d_in[1];
    const float* ln_b   = (const float*)d_in[2];
    const float* Win    = (const float*)d_in[3];   // [1024, 4096]
    const float* convw  = (const float*)d_in[4];   // [2048, 4]
    const float* convb  = (const float*)d_in[5];
    const float* Wx     = (const float*)d_in[6];   // [2048, 96]
    const float* Wdt    = (const float*)d_in[7];   // [64, 2048]
    const float* bdt    = (const float*)d_in[8];
    const float* A_log  = (const float*)d_in[9];   // [2048, 16]
    const float* Dp     = (const float*)d_in[10];
    const float* Wout   = (const float*)d_in[11];  // [2048, 1024]
    const float* rscale = (const float*)d_in[12];  // [1]

    float* out      = (float*)d_out;
    float* ssm_out  = out + (size_t)NROWS * D_MODEL;
    float* conv_out = ssm_out + (size_t)BB * D_INNER * D_STATE;

    // ---- workspace layout (~125.6 MB) ----
    float* ws = (float*)d_ws;
    unsigned short* xzb = (unsigned short*)ws;                     // 33.55 MB bf16
    unsigned short* xsb = xzb + (size_t)NROWS * XZLD;              // 16.78 MB bf16
    unsigned short* dtbb = xsb + (size_t)NROWS * D_INNER;          // 16.78 MB bf16
    float* xbc  = (float*)(dtbb + (size_t)NROWS * D_INNER);        // 0.52 MB
    unsigned short* xdtr = (unsigned short*)(xbc + (size_t)NROWS * 32);  // 0.52 MB
    unsigned short* xnb  = xdtr + (size_t)NROWS * DT_RANK;         // 8.39 MB
    unsigned short* wtin = xnb + (size_t)NROWS * D_MODEL;          // 8.39 MB
    unsigned short* wtout = wtin + (size_t)(2 * D_INNER) * D_MODEL; // 4.19 MB
    unsigned short* Wxt  = wtout + (size_t)D_MODEL * D_INNER;      // 0.52 MB
    unsigned short* Wdtt = Wxt + (size_t)128 * D_INNER;            // 0.26 MB
    float* Tbuf = (float*)(Wdtt + (size_t)D_INNER * DT_RANK);      // 2.10 MB
    float* Sbuf = Tbuf + (size_t)BB * NC * D_INNER;                // 33.55 MB
    // aliases (disjoint lifetimes within Sbuf region):
    float* Pxdbl = Sbuf;                         // 12.58 MB, dead before scan1
    float* Hin   = Sbuf;                         // pass2 out (load-before-store)
    float* P0 = Sbuf;                            // out_proj partials after scan3
    float* P1 = Sbuf + (size_t)NROWS * D_MODEL;
    unsigned short* ybuf = xnb;                  // y bf16 spans xnb+wtin (dead)

    // 1. LN + all weight transposes (one launch)
    prologue_kernel<<<NROWS + 228 * 64, 256, 0, stream>>>(
        x, ln_w, ln_b, xnb, Win, Wout, Wx, Wdt, wtin, wtout, Wxt, Wdtt);

    // 2. in_proj: big tile 256x128 -> bf16 fused xz
    mfma_gemm_big<<<dim3(2 * D_INNER / 128, NROWS / 256), 512, 0, stream>>>(
        xnb, wtin, XZLD, D_MODEL, xzb);

    // 3. conv + silu -> bf16 x_s (+ conv_state)
    conv_kernel<<<BB * (LL / 8), 256, 0, stream>>>(
        xzb, convw, convb, xsb, conv_out);

    // 4. x_dbl split-K x8 -> partials (MFMA), then reduce
    mfma_gemm<<<dim3(1, NROWS / 128, 8), 256, 0, stream>>>(
        xsb, Wxt, Pxdbl, 96, D_INNER, D_INNER / 8, (size_t)NROWS * 96, 0,
        nullptr, 96, nullptr);
    xdbl_reduce<<<(NROWS * 96) / 256, 256, 0, stream>>>(Pxdbl, xdtr, xbc);

    // 5. dt = softplus(xdtr @ Wdt + b) -> bf16  (MFMA, K=64)
    mfma_gemm<<<dim3(D_INNER / 128, NROWS / 128), 256, 0, stream>>>(
        xdtr, Wdtt, nullptr, D_INNER, DT_RANK, DT_RANK, 0, 4,
        bdt, D_INNER, dtbb);

    // 6-8. chunked selective scan (NC=128)
    scan_part1<<<dim3(D_INNER / 256, NC, BB), 256, 0, stream>>>(
        dtbb, xbc, xsb, A_log, Sbuf, Tbuf);
    scan_part2<<<(BB * D_INNER * D_STATE) / 256, 256, 0, stream>>>(
        Sbuf, Tbuf, A_log, Hin);
    scan_part3<<<dim3(D_INNER / 256, NC, BB), 256, 0, stream>>>(
        dtbb, xbc, xsb, xzb, A_log, Dp, Hin, ybuf, ssm_out);

    // 9. out_proj split-K x2 -> partials P0/P1 (Sbuf region dead after scan3)
    mfma_gemm<<<dim3(D_MODEL / 128, NROWS / 128, 2), 256, 0, stream>>>(
        ybuf, wtout, P0, D_MODEL, D_INNER, D_INNER / 2,
        (size_t)NROWS * D_MODEL, 0,
        nullptr, D_MODEL, nullptr);

    // 10. out = rs*(P0+P1) + residual
    out_final<<<(NROWS * D_MODEL) / (256 * 4), 256, 0, stream>>>(
        P0, P1, x, rscale, out);
}